// Round 10
// baseline (330.958 us; speedup 1.0000x reference)
//
#include <hip/hip_runtime.h>
#include <math.h>

// Problem dims
constexpr int T0n = 2048;   // tokens
constexpr int Dn  = 2048;   // hidden
constexpr int En  = 256;    // experts
constexpr int Gn  = 8;      // groups
constexpr int EGn = 32;     // experts per group
constexpr int Rn  = 64;     // tucker rank
constexpr int In  = 1408;   // intermediate

constexpr int NROWS = T0n * 8;    // 16384 dispatched rows
constexpr int SEGCAP = NROWS;     // per-group segment capacity in rseg
constexpr int KS_R = 4;           // router split-K (i32 accumulation is exact, any split OK)
constexpr int NTILE_MAX = NROWS / 128 + Gn;   // 136: upper bound on sum ceil(ng/128)
constexpr int CSPLIT = 4;         // I-chunk splits (8 regressed: write traffic doubles, R7)

typedef __attribute__((ext_vector_type(8))) short s8v;    // 8 bf16
typedef __attribute__((ext_vector_type(4))) float f4v;    // 4 fp32
typedef __attribute__((ext_vector_type(4))) int i4v;      // 16 i8 operand / 4 i32 acc
#define MFMA16(a, b, c) __builtin_amdgcn_mfma_f32_16x16x32_bf16(a, b, c, 0, 0, 0)
#define MFMAI8(a, b, c) __builtin_amdgcn_mfma_i32_16x16x64_i8(a, b, c, 0, 0, 0)

__device__ __forceinline__ unsigned short f2bf(float x) {
  unsigned int u = __float_as_uint(x);
  unsigned int r = (u + 0x7FFFu + ((u >> 16) & 1u)) >> 16;
  return (unsigned short)r;
}

// ---------------------------------------------------------------------------
// Fused batched transpose+convert for 9 weight tensors:
// src f32 [batch][rows][cols] -> dst bf16 [batch][cols][rows].
// ---------------------------------------------------------------------------
struct TD { const float* src; unsigned short* dst; int rows, cols, nbx, per_batch, base; };
struct TD9 { TD t[9]; };

__global__ __launch_bounds__(256) void k_tcvt9(TD9 D) {
  __shared__ float tbuf[32][33];
  int id = blockIdx.x;
  int ti = 0;
#pragma unroll
  for (int i = 1; i < 9; ++i) ti = (id >= D.t[i].base) ? i : ti;
  TD d = D.t[ti];
  int local = id - d.base;
  int bz = local / d.per_batch;
  int rem = local - bz * d.per_batch;
  int by = rem / d.nbx;
  int bx = rem - by * d.nbx;

  size_t boff = (size_t)bz * d.rows * d.cols;
  const float* src = d.src + boff;
  unsigned short* dst = d.dst + boff;
  int c0 = bx * 32, r0 = by * 32;
  int tx = threadIdx.x & 31, ty = threadIdx.x >> 5;   // ty 0..7
  for (int i = ty; i < 32; i += 8)
    tbuf[i][tx] = src[(size_t)(r0 + i) * d.cols + c0 + tx];
  __syncthreads();
  for (int i = ty; i < 32; i += 8)
    dst[(size_t)(c0 + i) * d.rows + r0 + tx] = f2bf(tbuf[tx][i]);
}

// ---------------------------------------------------------------------------
// ROUTER, exact fixed-point path (R8, HW-verified R2: absmax unchanged):
// logits = H @ W with H,W decomposed into 4 signed 8-bit limbs each;
// limb-pair products (k+l>=2) accumulated exactly in i32 MFMA.
// ---------------------------------------------------------------------------
__device__ __forceinline__ int4 limbs4(float v, double sc) {
  double d = (double)v * sc;           // exact in double
  d = fmin(fmax(d, -2.0e9), 2.0e9);    // clamp (unreachable for this data)
  int x = __double2int_rn(d);
  int l0 = (int)(signed char)(x & 0xff); x = (x - l0) >> 8;   // exact
  int l1 = (int)(signed char)(x & 0xff); x = (x - l1) >> 8;
  int l2 = (int)(signed char)(x & 0xff); x = (x - l2) >> 8;
  return make_int4(l0, l1, l2, x);     // x fits i8
}

// hidden [2048][2048] f32 -> hq planes [4][2048][2048] i8 (limb-major).
__global__ __launch_bounds__(256) void k_quant_h(
    const float* __restrict__ H, char* __restrict__ hq) {
  const size_t PL = (size_t)T0n * Dn;
  size_t i = (size_t)blockIdx.x * 256 + threadIdx.x;   // group of 4 elements
  float4 v = *(const float4*)&H[i * 4];
  int4 a = limbs4(v.x, 268435456.0);   // 2^28
  int4 b = limbs4(v.y, 268435456.0);
  int4 c = limbs4(v.z, 268435456.0);
  int4 d = limbs4(v.w, 268435456.0);
  unsigned int p0 = (a.x & 0xff) | ((b.x & 0xff) << 8) | ((c.x & 0xff) << 16) | ((unsigned)(d.x & 0xff) << 24);
  unsigned int p1 = (a.y & 0xff) | ((b.y & 0xff) << 8) | ((c.y & 0xff) << 16) | ((unsigned)(d.y & 0xff) << 24);
  unsigned int p2 = (a.z & 0xff) | ((b.z & 0xff) << 8) | ((c.z & 0xff) << 16) | ((unsigned)(d.z & 0xff) << 24);
  unsigned int p3 = (a.w & 0xff) | ((b.w & 0xff) << 8) | ((c.w & 0xff) << 16) | ((unsigned)(d.w & 0xff) << 24);
  *(unsigned int*)&hq[0 * PL + i * 4] = p0;
  *(unsigned int*)&hq[1 * PL + i * 4] = p1;
  *(unsigned int*)&hq[2 * PL + i * 4] = p2;
  *(unsigned int*)&hq[3 * PL + i * 4] = p3;
}

// w_gate [2048][256] f32 -> wqT planes [4][256][2048] i8 (transposed, limb-major).
__global__ __launch_bounds__(256) void k_quant_wT(
    const float* __restrict__ W, char* __restrict__ wqT) {
  __shared__ float tb[32][33];
  const size_t PL = (size_t)En * Dn;
  int kb = blockIdx.x * 32, nb = blockIdx.y * 32;
  int tx = threadIdx.x & 31, ty = threadIdx.x >> 5;
  for (int i = ty; i < 32; i += 8)
    tb[i][tx] = W[(size_t)(kb + i) * En + nb + tx];
  __syncthreads();
  for (int i = ty; i < 32; i += 8) {
    int4 l = limbs4(tb[tx][i], 8589934592.0);   // 2^33
    size_t off = (size_t)(nb + i) * Dn + kb + tx;
    wqT[0 * PL + off] = (char)l.x;
    wqT[1 * PL + off] = (char)l.y;
    wqT[2 * PL + off] = (char)l.z;
    wqT[3 * PL + off] = (char)l.w;
  }
}

// i8 MFMA router GEMM. grid (En/64, T0n/64, KS_R). HW-verified R2.
__global__ __launch_bounds__(256) void k_router_i8(
    const char* __restrict__ hq, const char* __restrict__ wqT,
    float* __restrict__ part) {
  __shared__ __align__(16) char Asl[4][64][80];   // [limb][m-row][k]
  __shared__ __align__(16) char Bsl[4][64][80];   // [limb][n-row][k]
  const int n0 = blockIdx.x * 64, m0 = blockIdx.y * 64;
  const int kc = blockIdx.z;
  const int tid = threadIdx.x;
  const int w = tid >> 6, ln = tid & 63;
  const int quad = ln >> 4, lane16 = ln & 15;

  const char* ha = hq + ((size_t)w * T0n + m0 + ln) * Dn;   // plane w, row m0+ln
  const char* ba = wqT + ((size_t)w * En + n0 + ln) * Dn;   // plane w, row n0+ln

  i4v acc[4][5] = {};   // [m-tile][s-group s=k+l-2]

  const int kbeg = kc * (Dn / KS_R);
  for (int k0 = kbeg; k0 < kbeg + Dn / KS_R; k0 += 64) {
#pragma unroll
    for (int q = 0; q < 4; ++q) {
      *(uint4*)&Asl[w][ln][q * 16] = *(const uint4*)&ha[k0 + q * 16];
      *(uint4*)&Bsl[w][ln][q * 16] = *(const uint4*)&ba[k0 + q * 16];
    }
    __syncthreads();
    i4v b0 = *(const i4v*)&Bsl[0][w * 16 + lane16][quad * 16];
    i4v b1 = *(const i4v*)&Bsl[1][w * 16 + lane16][quad * 16];
    i4v b2 = *(const i4v*)&Bsl[2][w * 16 + lane16][quad * 16];
    i4v b3 = *(const i4v*)&Bsl[3][w * 16 + lane16][quad * 16];
#pragma unroll
    for (int mt = 0; mt < 4; ++mt) {
      i4v a0 = *(const i4v*)&Asl[0][mt * 16 + lane16][quad * 16];
      i4v a1 = *(const i4v*)&Asl[1][mt * 16 + lane16][quad * 16];
      i4v a2 = *(const i4v*)&Asl[2][mt * 16 + lane16][quad * 16];
      i4v a3 = *(const i4v*)&Asl[3][mt * 16 + lane16][quad * 16];
      // s = 2
      acc[mt][0] = MFMAI8(a0, b2, acc[mt][0]);
      acc[mt][0] = MFMAI8(a1, b1, acc[mt][0]);
      acc[mt][0] = MFMAI8(a2, b0, acc[mt][0]);
      // s = 3
      acc[mt][1] = MFMAI8(a0, b3, acc[mt][1]);
      acc[mt][1] = MFMAI8(a1, b2, acc[mt][1]);
      acc[mt][1] = MFMAI8(a2, b1, acc[mt][1]);
      acc[mt][1] = MFMAI8(a3, b0, acc[mt][1]);
      // s = 4
      acc[mt][2] = MFMAI8(a1, b3, acc[mt][2]);
      acc[mt][2] = MFMAI8(a2, b2, acc[mt][2]);
      acc[mt][2] = MFMAI8(a3, b1, acc[mt][2]);
      // s = 5
      acc[mt][3] = MFMAI8(a2, b3, acc[mt][3]);
      acc[mt][3] = MFMAI8(a3, b2, acc[mt][3]);
      // s = 6
      acc[mt][4] = MFMAI8(a3, b3, acc[mt][4]);
    }
    __syncthreads();
  }

  float* prow = part + (size_t)kc * T0n * En;
#pragma unroll
  for (int mt = 0; mt < 4; ++mt)
#pragma unroll
    for (int r = 0; r < 4; ++r) {
      int row = m0 + mt * 16 + quad * 4 + r;
      int col = n0 + w * 16 + lane16;
      double v = (double)acc[mt][0][r] * 0x1p-45 +
                 (double)acc[mt][1][r] * 0x1p-37 +
                 (double)acc[mt][2][r] * 0x1p-29 +
                 (double)acc[mt][3][r] * 0x1p-21 +
                 (double)acc[mt][4][r] * 0x1p-13;
      prow[(size_t)row * En + col] = (float)v;
    }
}

// ---------------------------------------------------------------------------
// Top-8: one wave per token, shuffle butterfly. Sums KS_R fp32 partials in fp64.
// ---------------------------------------------------------------------------
__global__ __launch_bounds__(256) void k_topk(
    const float* __restrict__ part, int* __restrict__ sel,
    float* __restrict__ rw, int* __restrict__ cnt_e) {
  const int wid = threadIdx.x >> 6, ln = threadIdx.x & 63;
  const int t = blockIdx.x * 4 + wid;

  double v[4];
#pragma unroll
  for (int j = 0; j < 4; ++j) {
    double s = 0.0;
#pragma unroll
    for (int kc = 0; kc < KS_R; ++kc)
      s += (double)part[((size_t)kc * T0n + t) * En + ln + 64 * j];
    v[j] = s;
  }

  float topv[8];
  int topi[8];
#pragma unroll
  for (int k = 0; k < 8; ++k) {
    double bv = v[0]; int bi = ln;
#pragma unroll
    for (int j = 1; j < 4; ++j) {
      int cand = ln + 64 * j;
      if (v[j] > bv || (v[j] == bv && cand < bi)) { bv = v[j]; bi = cand; }
    }
#pragma unroll
    for (int off = 32; off > 0; off >>= 1) {
      double ov = __shfl_xor(bv, off);
      int oi = __shfl_xor(bi, off);
      if (ov > bv || (ov == bv && oi < bi)) { bv = ov; bi = oi; }
    }
    topv[k] = (float)bv; topi[k] = bi;
    if ((bi & 63) == ln) v[bi >> 6] = -1e300;
  }

  if (ln < 8) {
    float m = topv[0];
    float ssum = 0.f;
#pragma unroll
    for (int k = 0; k < 8; ++k) ssum += expf(topv[k] - m);
    rw[t * 8 + ln] = expf(topv[ln] - m) / ssum;
    sel[t * 8 + ln] = topi[ln];
    atomicAdd(&cnt_e[topi[ln]], 1);
  }
}

// Parallel per-group prefix over 256 experts.
__global__ __launch_bounds__(256) void k_scan(
    const int* __restrict__ cnt_e, int* __restrict__ off_e,
    int* __restrict__ cur_e, int* __restrict__ grp_n) {
  __shared__ int c[256];
  int tid = threadIdx.x;
  c[tid] = cnt_e[tid];
  __syncthreads();
  int g = tid >> 5, ei = tid & 31;
  int run = 0;
  for (int i = 0; i < ei; ++i) run += c[(g << 5) + i];
  off_e[tid] = g * SEGCAP + run;
  cur_e[tid] = g * SEGCAP + run;
  if (ei == 31) grp_n[g] = run + c[tid];
}

__global__ void k_scatter(const int* __restrict__ sel, int* __restrict__ cur_e,
                          int* __restrict__ rseg) {
  int i = blockIdx.x * 256 + threadIdx.x;
  int e = sel[i];
  int pos = atomicAdd(&cur_e[e], 1);
  rseg[pos] = i;
}

// ---------------------------------------------------------------------------
// h1 = H @ A_fac[g]. 512 threads: waves 0-3 gate, 4-7 up (H staged once,
// 8 waves/CU for latency hiding). Output bf16. grid (T0/64, G).
// ---------------------------------------------------------------------------
__global__ __launch_bounds__(512) void k_h1_mfma(
    const float* __restrict__ H,
    const unsigned short* __restrict__ AgT, const unsigned short* __restrict__ AuT,
    unsigned short* __restrict__ h1gb, unsigned short* __restrict__ h1ub) {
  const int t0 = blockIdx.x * 64;
  const int g = blockIdx.y;
  const unsigned short* Wg = AgT + (size_t)g * Rn * Dn;
  const unsigned short* Wu = AuT + (size_t)g * Rn * Dn;

  __shared__ unsigned short As[64 * 72];
  __shared__ unsigned short Bg_l[64 * 72];
  __shared__ unsigned short Bu_l[64 * 72];
  const int tid = threadIdx.x;
  const int w = tid >> 6, ln = tid & 63;
  const int path = w >> 2, ws = w & 3;
  const int quad = ln >> 4, lane16 = ln & 15;
  const int j = tid >> 3, q = (tid & 7) * 8;   // 64 rows x 8 chunks

  f4v S[4] = {};

  for (int k0 = 0; k0 < Dn; k0 += 64) {
    {
      float4 v0 = *(const float4*)&H[(size_t)(t0 + j) * Dn + k0 + q];
      float4 v1 = *(const float4*)&H[(size_t)(t0 + j) * Dn + k0 + q + 4];
      ushort4 o0, o1;
      o0.x = f2bf(v0.x); o0.y = f2bf(v0.y); o0.z = f2bf(v0.z); o0.w = f2bf(v0.w);
      o1.x = f2bf(v1.x); o1.y = f2bf(v1.y); o1.z = f2bf(v1.z); o1.w = f2bf(v1.w);
      *(ushort4*)&As[j * 72 + q] = o0;
      *(ushort4*)&As[j * 72 + q + 4] = o1;
      *(uint4*)&Bg_l[j * 72 + q] = *(const uint4*)&Wg[(size_t)j * Dn + k0 + q];
      *(uint4*)&Bu_l[j * 72 + q] = *(const uint4*)&Wu[(size_t)j * Dn + k0 + q];
    }
    __syncthreads();
    const unsigned short* Bl = path ? Bu_l : Bg_l;
#pragma unroll
    for (int kk = 0; kk < 2; ++kk) {
      s8v a = *(const s8v*)&As[(ws * 16 + lane16) * 72 + kk * 32 + quad * 8];
#pragma unroll
      for (int nt = 0; nt < 4; ++nt) {
        s8v b = *(const s8v*)&Bl[(nt * 16 + lane16) * 72 + kk * 32 + quad * 8];
        S[nt] = MFMA16(a, b, S[nt]);
      }
    }
    __syncthreads();
  }
  unsigned short* out = path ? h1ub : h1gb;
#pragma unroll
  for (int nt = 0; nt < 4; ++nt)
#pragma unroll
    for (int r = 0; r < 4; ++r) {
      int row = t0 + ws * 16 + quad * 4 + r;
      int col = g * 64 + nt * 16 + lane16;
      out[(size_t)row * (Gn * Rn) + col] = f2bf(S[nt][r]);
    }
}

// ---------------------------------------------------------------------------
// Per-expert core (gate/up) via MFMA. 512 threads: waves 0-3 gate, 4-7 up.
// ---------------------------------------------------------------------------
__global__ __launch_bounds__(512) void k_core_gu(
    const unsigned short* __restrict__ h1gb, const unsigned short* __restrict__ h1ub,
    const unsigned short* __restrict__ CgT, const unsigned short* __restrict__ CuT,
    const int* __restrict__ rseg, const int* __restrict__ off_e,
    const int* __restrict__ cnt_e,
    unsigned short* __restrict__ h2gb, unsigned short* __restrict__ h2ub) {
  const int e = blockIdx.x;
  const int ne = cnt_e[e];
  if (ne == 0) return;
  const int g = e >> 5;
  const int base = off_e[e];
  __shared__ unsigned short Cg_l[64 * 72];
  __shared__ unsigned short Cu_l[64 * 72];
  __shared__ unsigned short Ags[64 * 72];
  __shared__ unsigned short Aus[64 * 72];
  __shared__ int rids[64];
  const int tid = threadIdx.x;
  const int w = tid >> 6, ln = tid & 63;
  const int path = w >> 2, ws = w & 3;
  const int quad = ln >> 4, lane16 = ln & 15;
  const int j = tid >> 3, q = (tid & 7) * 8;
  {
    const unsigned short* cg = CgT + (size_t)e * (Rn * Rn);
    const unsigned short* cu = CuT + (size_t)e * (Rn * Rn);
    *(uint4*)&Cg_l[j * 72 + q] = *(const uint4*)&cg[j * 64 + q];
    *(uint4*)&Cu_l[j * 72 + q] = *(const uint4*)&cu[j * 64 + q];
  }
  const int ntile = (ne + 63) >> 6;
  for (int it = 0; it < ntile; ++it) {
    int mi = it * 64 + j;
    int rid = (mi < ne) ? rseg[base + mi] : -1;
    if ((tid & 7) == 0) rids[j] = rid;
    uint4 zg = {0, 0, 0, 0}, zu = {0, 0, 0, 0};
    if (rid >= 0) {
      zg = *(const uint4*)&h1gb[(size_t)(rid >> 3) * (Gn * Rn) + g * 64 + q];
      zu = *(const uint4*)&h1ub[(size_t)(rid >> 3) * (Gn * Rn) + g * 64 + q];
    }
    *(uint4*)&Ags[j * 72 + q] = zg;
    *(uint4*)&Aus[j * 72 + q] = zu;
    __syncthreads();
    const unsigned short* Al = path ? Aus : Ags;
    const unsigned short* Cl = path ? Cu_l : Cg_l;
    f4v S[4] = {};
#pragma unroll
    for (int kk = 0; kk < 2; ++kk) {
      s8v a = *(const s8v*)&Al[(ws * 16 + lane16) * 72 + kk * 32 + quad * 8];
#pragma unroll
      for (int nt = 0; nt < 4; ++nt) {
        s8v b = *(const s8v*)&Cl[(nt * 16 + lane16) * 72 + kk * 32 + quad * 8];
        S[nt] = MFMA16(a, b, S[nt]);
      }
    }
    unsigned short* out = path ? h2ub : h2gb;
#pragma unroll
    for (int nt = 0; nt < 4; ++nt)
#pragma unroll
      for (int r = 0; r < 4; ++r) {
        int rid2 = rids[ws * 16 + quad * 4 + r];
        if (rid2 >= 0)
          out[(size_t)rid2 * 64 + nt * 16 + lane16] = f2bf(S[nt][r]);
      }
    __syncthreads();
  }
}

// ---------------------------------------------------------------------------
// Fused expand + down-A via MFMA. R14: BARRIER-FREE — every wave fully
// independent. Rationale (R5-R13 data): all pipes idle (Mfma 5-6%, VALU 23-28%,
// HBM 9%) across 5 experiments; the invariant is 4 waves/block locked into
// lockstep by __syncthreads, so independent streams/CU = blocks (~2), not
// waves (~8). B/Ad tiles are group-shared and L1/L2-resident -> read
// fragments DIRECTLY from global (16B-aligned in the transposed layouts);
// rids reloaded per-lane from rseg (L2-hot). Zero barriers; LDS = per-wave
// inter only (18.4 KB). 2176 independent waves give the scheduler real TLP.
// grid (NTILE_MAX, CSPLIT). Epilogue: plain stores to per-split slices (R13).
// ---------------------------------------------------------------------------
__global__ __launch_bounds__(256) void k_expand_mfma(
    const unsigned short* __restrict__ h2gb, const unsigned short* __restrict__ h2ub,
    const unsigned short* __restrict__ BgT, const unsigned short* __restrict__ BuT,
    const unsigned short* __restrict__ AdT,
    const int* __restrict__ rseg, const int* __restrict__ grp_n,
    float* __restrict__ s0, float* __restrict__ s1,
    float* __restrict__ s2, float* __restrict__ s3) {
  // Decode flat tile id -> (g, m0) via prefix over per-group tile counts.
  int t = blockIdx.x;
  int g = -1, m0 = 0, ng = 0;
  {
    int pre = 0;
#pragma unroll
    for (int gg = 0; gg < Gn; ++gg) {
      int n = grp_n[gg];
      int nt = (n + 127) >> 7;
      if (g < 0 && t < pre + nt) { g = gg; m0 = (t - pre) << 7; ng = n; }
      pre += nt;
    }
  }
  if (g < 0) return;
  const int c_beg = (blockIdx.y * 22) / CSPLIT;
  const int c_end = ((blockIdx.y + 1) * 22) / CSPLIT;
  float* hs = (blockIdx.y == 0) ? s0 : (blockIdx.y == 1) ? s1
            : (blockIdx.y == 2) ? s2 : s3;

  __shared__ unsigned short inter_l[4][32 * 72];   // per-wave private only

  const int tid = threadIdx.x;
  const int w = tid >> 6, ln = tid & 63;
  const int quad = ln >> 4, lane16 = ln & 15;
  const int rbase = g * SEGCAP + m0 + w * 32;      // this wave's rseg base

  // H gate/up fragments in registers: wave w owns rows w*32..w*32+31.
  // rids loaded per-lane directly from rseg (L2-hot, no LDS, no barrier).
  s8v ag[2][2], au[2][2];
  int ridf[2];
#pragma unroll
  for (int mt = 0; mt < 2; ++mt) {
    int row = m0 + w * 32 + mt * 16 + lane16;
    int rid = (row < ng) ? rseg[rbase + mt * 16 + lane16] : -1;
    ridf[mt] = rid;
#pragma unroll
    for (int kk = 0; kk < 2; ++kk) {
      s8v zg = {}, zu = {};
      if (rid >= 0) {
        zg = *(const s8v*)&h2gb[(size_t)rid * 64 + kk * 32 + quad * 8];
        zu = *(const s8v*)&h2ub[(size_t)rid * 64 + kk * 32 + quad * 8];
      }
      ag[mt][kk] = zg;
      au[mt][kk] = zu;
    }
  }

  const unsigned short* Bg_base = BgT + (size_t)g * In * Rn;   // [In][Rn]
  const unsigned short* Bu_base = BuT + (size_t)g * In * Rn;   // [In][Rn]
  const unsigned short* Ad_base = AdT + (size_t)g * Rn * In;   // [Rn][In]

  unsigned short* ib = &inter_l[w][0];
  f4v P[2][4] = {};

  for (int c = c_beg; c < c_end; ++c) {
    const int i0 = c * 64;

    f4v Sg[2][4] = {}, Su[2][4] = {};
#pragma unroll
    for (int kk = 0; kk < 2; ++kk) {
      s8v bg[4], bu[4];
#pragma unroll
      for (int nt = 0; nt < 4; ++nt) {
        // B operand [n][k]: n = I-chunk row, k = R index. Direct 16B loads.
        bg[nt] = *(const s8v*)&Bg_base[(size_t)(i0 + nt * 16 + lane16) * Rn + kk * 32 + quad * 8];
        bu[nt] = *(const s8v*)&Bu_base[(size_t)(i0 + nt * 16 + lane16) * Rn + kk * 32 + quad * 8];
      }
#pragma unroll
      for (int mt = 0; mt < 2; ++mt)
#pragma unroll
        for (int nt = 0; nt < 4; ++nt) {
          Sg[mt][nt] = MFMA16(ag[mt][kk], bg[nt], Sg[mt][nt]);
          Su[mt][nt] = MFMA16(au[mt][kk], bu[nt], Su[mt][nt]);
        }
    }

    // silu(gate)*up -> per-wave inter region. Wave-local W->R only.
#pragma unroll
    for (int mt = 0; mt < 2; ++mt)
#pragma unroll
      for (int nt = 0; nt < 4; ++nt)
#pragma unroll
        for (int r = 0; r < 4; ++r) {
          float sg = Sg[mt][nt][r];
          float v = sg / (1.f + __expf(-sg)) * Su[mt][nt][r];
          ib[(mt * 16 + quad * 4 + r) * 72 + nt * 16 + lane16] = f2bf(v);
        }
    asm volatile("s_waitcnt lgkmcnt(0)" ::: "memory");   // wave-local W->R order

#pragma unroll
    for (int kk = 0; kk < 2; ++kk) {
      s8v ai[2], bd[4];
#pragma unroll
      for (int mt = 0; mt < 2; ++mt)
        ai[mt] = *(const s8v*)&ib[(mt * 16 + lane16) * 72 + kk * 32 + quad * 8];
#pragma unroll
      for (int nt = 0; nt < 4; ++nt)
        // Ad operand [n][k]: n = R index, k = I index within chunk.
        bd[nt] = *(const s8v*)&Ad_base[(size_t)(nt * 16 + lane16) * In + i0 + kk * 32 + quad * 8];
#pragma unroll
      for (int mt = 0; mt < 2; ++mt)
#pragma unroll
        for (int nt = 0; nt < 4; ++nt)
          P[mt][nt] = MFMA16(ai[mt], bd[nt], P[mt][nt]);
    }
  }

  // Plain stores: this (rid, split) is ours alone. rid2 reloaded per-lane.
#pragma unroll
  for (int mt = 0; mt < 2; ++mt)
#pragma unroll
    for (int r = 0; r < 4; ++r) {
      int lrow = mt * 16 + quad * 4 + r;
      int rid = (m0 + w * 32 + lrow < ng) ? rseg[rbase + lrow] : -1;
      if (rid >= 0) {
#pragma unroll
        for (int nt = 0; nt < 4; ++nt)
          hs[(size_t)rid * 64 + nt * 16 + lane16] = P[mt][nt][r];
      }
    }
}

// ---------------------------------------------------------------------------
// Per-expert down core via MFMA + routing weight, reduce to y[t,g,64].
// 512 threads: 128 rows/iter. R13: sums CSPLIT h1d slices while staging.
// ---------------------------------------------------------------------------
__global__ __launch_bounds__(512) void k_core_down(
    const float* __restrict__ s0, const float* __restrict__ s1,
    const float* __restrict__ s2, const float* __restrict__ s3,
    const unsigned short* __restrict__ CdT,
    const float* __restrict__ rw,
    const int* __restrict__ rseg, const int* __restrict__ off_e,
    const int* __restrict__ cnt_e,
    float* __restrict__ y) {
  const int e = blockIdx.x;
  const int ne = cnt_e[e];
  if (ne == 0) return;
  const int g = e >> 5;
  const int base = off_e[e];
  __shared__ unsigned short Bd_l[64 * 72];
  __shared__ unsigned short Ad_l[128 * 72];
  __shared__ int rids[128];
  const int tid = threadIdx.x;
  const int w = tid >> 6, ln = tid & 63;
  const int quad = ln >> 4, lane16 = ln & 15;
  {
    int j = tid >> 3, q = (tid & 7) * 8;
    const unsigned short* cd = CdT + (size_t)e * (Rn * Rn);
    *(uint4*)&Bd_l[j * 72 + q] = *(const uint4*)&cd[j * 64 + q];
  }
  const int gj = tid >> 2, gq = (tid & 3) * 16;   // 128 rows x 4 chunks of 16
  const int ntile = (ne + 127) >> 7;
  for (int it = 0; it < ntile; ++it) {
    int mi = it * 128 + gj;
    int rid = (mi < ne) ? rseg[base + mi] : -1;
    if ((tid & 3) == 0) rids[gj] = rid;
#pragma unroll
    for (int i = 0; i < 4; ++i) {
      int kb = gq + i * 4;
      float4 vd = {0.f, 0.f, 0.f, 0.f};
      if (rid >= 0) {
        size_t off = (size_t)rid * 64 + kb;
        float4 a0 = *(const float4*)&s0[off];
        float4 a1 = *(const float4*)&s1[off];
        float4 a2 = *(const float4*)&s2[off];
        float4 a3 = *(const float4*)&s3[off];
        vd.x = (a0.x + a1.x) + (a2.x + a3.x);
        vd.y = (a0.y + a1.y) + (a2.y + a3.y);
        vd.z = (a0.z + a1.z) + (a2.z + a3.z);
        vd.w = (a0.w + a1.w) + (a2.w + a3.w);
      }
      ushort4 od;
      od.x = f2bf(vd.x); od.y = f2bf(vd.y); od.z = f2bf(vd.z); od.w = f2bf(vd.w);
      *(ushort4*)&Ad_l[gj * 72 + kb] = od;
    }
    __syncthreads();
    f4v Sd[4] = {};
#pragma unroll
    for (int kk = 0; kk < 2; ++kk) {
      s8v ad = *(const s8v*)&Ad_l[(w * 16 + lane16) * 72 + kk * 32 + quad * 8];
#pragma unroll
      for (int nt = 0; nt < 4; ++nt) {
        s8v bd = *(const s8v*)&Bd_l[(nt * 16 + lane16) * 72 + kk * 32 + quad * 8];
        Sd[nt] = MFMA16(ad, bd, Sd[nt]);
      }
    }
#pragma unroll
    for (int nt = 0; nt < 4; ++nt)
#pragma unroll
      for (int r = 0; r < 4; ++r) {
        int rid2 = rids[w * 16 + quad * 4 + r];
        if (rid2 >= 0) {
          float wgt = rw[rid2];
          atomicAdd(&y[(size_t)(rid2 >> 3) * (Gn * Rn) + g * 64 + nt * 16 + lane16],
                    wgt * Sd[nt][r]);
        }
      }
    __syncthreads();
  }
}

// ---------------------------------------------------------------------------
// Combine: out[2048,2048] = y[2048,512] @ B_down-as-[512,2048], MFMA bf16.
// ---------------------------------------------------------------------------
__global__ __launch_bounds__(256) void k_combine(
    const float* __restrict__ y, const unsigned short* __restrict__ BdT,
    float* __restrict__ outp) {
  const int t0 = blockIdx.y * 128, n0 = blockIdx.x * 128;
  __shared__ unsigned short As[128 * 72];
  __shared__ unsigned short Bs[128 * 72];
  const int tid = threadIdx.x;
  const int w = tid >> 6, ln = tid & 63;
  const int quad = ln >> 4, lane16 = ln & 15;
  const int mbase = (w >> 1) * 64, nbase = (w & 1) * 64;

  f4v acc[4][4] = {};

  for (int k0 = 0; k0 < Gn * Rn; k0 += 64) {
#pragma unroll
    for (int i = 0; i < 8; ++i) {
      int c = tid + i * 256;
      int row = c >> 4, cc = (c & 15) * 4;
      float4 v = *(const float4*)&y[(size_t)(t0 + row) * (Gn * Rn) + k0 + cc];
      ushort4 o;
      o.x = f2bf(v.x); o.y = f2bf(v.y); o.z = f2bf(v.z); o.w = f2bf(v.w);
      *(ushort4*)&As[row * 72 + cc] = o;
    }
#pragma unroll
    for (int i = 0; i < 4; ++i) {
      int c = tid + i * 256;
      int row = c >> 3, cc = (c & 7) * 8;
      *(uint4*)&Bs[row * 72 + cc] = *(const uint4*)&BdT[(size_t)(n0 + row) * (Gn * Rn) + k0 + cc];
    }
    __syncthreads();
#pragma unroll
    for (int kk = 0; kk < 2; ++kk) {
      s8v a[4], b[4];
#pragma unroll
      for (int mt = 0; mt < 4; ++mt)
        a[mt] = *(const s8v*)&As[(mbase + mt * 16 + lane16) * 72 + kk * 32 + quad * 8];
#pragma unroll
      for (int nt = 0; nt < 4; ++nt)
        b[nt] = *(const s8v*)&Bs[(nbase + nt * 16 + lane16) * 72 + kk * 32 + quad * 8];
#pragma unroll
      for (int mt = 0; mt < 4; ++mt)
#pragma unroll
        for (int nt = 0; nt < 4; ++nt)
          acc[mt][nt] = MFMA16(a[mt], b[nt], acc[mt][nt]);
    }
    __syncthreads();
  }
#pragma unroll
  for (int mt = 0; mt < 4; ++mt)
#pragma unroll
    for (int nt = 0; nt < 4; ++nt)
#pragma unroll
      for (int r = 0; r < 4; ++r)
        outp[(size_t)(t0 + mbase + mt * 16 + quad * 4 + r) * Dn +
             n0 + nbase + nt * 16 + lane16] = acc[mt][nt][r];
}

// ---------------------------------------------------------------------------
extern "C" void kernel_launch(void* const* d_in, const int* in_sizes, int n_in,
                              void* d_out, int out_size, void* d_ws, size_t ws_size,
                              hipStream_t stream) {
  const float* hidden = (const float*)d_in[0];
  const float* w_gate = (const float*)d_in[1];
  const float* A_gate = (const float*)d_in[2];
  const float* C_gate = (const float*)d_in[3];
  const float* B_gate = (const float*)d_in[4];
  const float* A_up   = (const float*)d_in[5];
  const float* C_up   = (const float*)d_in[6];
  const float* B_up   = (const float*)d_in[7];
  const float* A_down = (const float*)d_in[8];
  const float* C_down = (const float*)d_in[9];
  const float* B_down = (const float*)d_in[10];
  float* out = (float*)d_out;

  // Workspace layout (peak unchanged, 34.34 MB). Router-stage {part, hq, wqT}
  // overlay [0, 27.3MB), dead after k_topk. h1d slices 1-3 alias buffers dead
  // at k_expand time: AgT+AuT (dead after k_h1_mfma), CgT+CuT and h1gb+h1ub
  // (dead after k_core_gu). CdT/BdT (still live later) untouched.
  char* base = (char*)d_ws;
  size_t o = 0;
  unsigned short* h2gb = (unsigned short*)(base + o); o += (size_t)NROWS * Rn * 2;
  unsigned short* h2ub = (unsigned short*)(base + o); o += (size_t)NROWS * Rn * 2;
  unsigned short* AgT  = (unsigned short*)(base + o); o += (size_t)Gn * Rn * Dn * 2;
  unsigned short* AuT  = (unsigned short*)(base + o); o += (size_t)Gn * Rn * Dn * 2;
  unsigned short* BgT  = (unsigned short*)(base + o); o += (size_t)Gn * In * Rn * 2;
  unsigned short* BuT  = (unsigned short*)(base + o); o += (size_t)Gn * In * Rn * 2;
  unsigned short* AdT  = (unsigned short*)(base + o); o += (size_t)Gn * Rn * In * 2;
  unsigned short* BdT  = (unsigned short*)(base + o); o += (size_t)Dn * Gn * Rn * 2;
  unsigned short* CgT  = (unsigned short*)(base + o); o += (size_t)En * Rn * Rn * 2;
  unsigned short* CuT  = (unsigned short*)(base + o); o += (size_t)En * Rn * Rn * 2;
  unsigned short* CdT  = (unsigned short*)(base + o); o += (size_t)En * Rn * Rn * 2;
  unsigned short* h1gb = (unsigned short*)(base + o); o += (size_t)T0n * Gn * Rn * 2;
  unsigned short* h1ub = (unsigned short*)(base + o); o += (size_t)T0n * Gn * Rn * 2;
  float* h1d = (float*)(base + o); o += (size_t)NROWS * Rn * 4;
  float* y   = (float*)(base + o); o += (size_t)T0n * Gn * Rn * 4;
  // ---- persistent smalls ----
  float* rwp = (float*)(base + o); o += (size_t)NROWS * 4;
  int* sel   = (int*)(base + o); o += (size_t)NROWS * 4;
  int* rseg  = (int*)(base + o); o += (size_t)Gn * SEGCAP * 4;
  int* cnt_e = (int*)(base + o); o += En * 4;
  int* off_e = (int*)(base + o); o += En * 4;
  int* cur_e = (int*)(base + o); o += En * 4;
  int* grp_n = (int*)(base + o); o += Gn * 4;
  // ---- router-stage aliases (dead after k_topk), inside [0, 27.3MB) ----
  float* part = (float*)base;                              // 8,388,608 B
  char* hq  = base + (size_t)KS_R * T0n * En * 4;          // +16,777,216 (4 i8 planes)
  char* wqT = hq + (size_t)4 * T0n * Dn;                   // +2,097,152  (4 i8 planes, T)
  // ---- h1d slices for atomic-free expand (each NROWS*64*4 = 4.19 MB) ----
  float* h1s0 = h1d;             // dedicated h1d buffer
  float* h1s1 = (float*)AgT;     // AgT+AuT   (4.19 MB, dead after k_h1_mfma)
  float* h1s2 = (float*)CgT;     // CgT+CuT   (4.19 MB, dead after k_core_gu)
  float* h1s3 = (float*)h1gb;    // h1gb+h1ub (4.19 MB, dead after k_core_gu)

  hipMemsetAsync(cnt_e, 0, En * sizeof(int), stream);

  // 1) quantize inputs to exact 4x-i8 fixed-point limbs
  k_quant_h<<<T0n * Dn / 1024, 256, 0, stream>>>(hidden, hq);
  k_quant_wT<<<dim3(Dn / 32, En / 32), 256, 0, stream>>>(w_gate, wqT);
  // 2) router logits via exact i32-MFMA limb GEMM (split-K=4, fp32 slice partials)
  k_router_i8<<<dim3(En / 64, T0n / 64, KS_R), 256, 0, stream>>>(hq, wqT, part);
  // 3) top-8 + renorm + expert counts
  k_topk<<<T0n / 4, 256, 0, stream>>>(part, sel, rwp, cnt_e);
  // 4) offsets (parallel prefix) + scatter rows by expert
  k_scan<<<1, 256, 0, stream>>>(cnt_e, off_e, cur_e, grp_n);
  k_scatter<<<NROWS / 256, 256, 0, stream>>>(sel, cur_e, rseg);

  // part/hq/wqT now dead; aliased buffers may be written.
  hipMemsetAsync(y, 0, (size_t)T0n * Gn * Rn * sizeof(float), stream);

  // 5) transpose+convert all 9 weight tensors to bf16 operand layouts
  {
    TD9 D;
    D.t[0] = {A_gate, AgT, Dn, Rn, Rn / 32, (Rn / 32) * (Dn / 32), 0};
    D.t[1] = {A_up,   AuT, Dn, Rn, Rn / 32, (Rn / 32) * (Dn / 32), 1024};
    D.t[2] = {B_gate, BgT, Rn, In, In / 32, (In / 32) * (Rn / 32), 2048};
    D.t[3] = {B_up,   BuT, Rn, In, In / 32, (In / 32) * (Rn / 32), 2752};
    D.t[4] = {A_down, AdT, In, Rn, Rn / 32, (Rn / 32) * (In / 32), 3456};
    D.t[5] = {B_down, BdT, Gn * Rn, Dn, Dn / 32, (Dn / 32) * (Gn * Rn / 32), 4160};
    D.t[6] = {C_gate, CgT, Rn, Rn, 2, 4, 5184};
    D.t[7] = {C_up,   CuT, Rn, Rn, 2, 4, 6208};
    D.t[8] = {C_down, CdT, Rn, Rn, 2, 4, 7232};
    k_tcvt9<<<8256, 256, 0, stream>>>(D);
  }

  // 6) dense in-factor projections (512 thr: gate waves + up waves)
  k_h1_mfma<<<dim3(T0n / 64, Gn), 512, 0, stream>>>(hidden, AgT, AuT, h1gb, h1ub);
  // 7) per-expert core (gate/up) via MFMA (512 thr path-split)
  k_core_gu<<<En, 512, 0, stream>>>(h1gb, h1ub, CgT, CuT,
                                    rseg, off_e, cnt_e, h2gb, h2ub);
  // 8) fused expand + down-A (R14: barrier-free, B-frags direct from L1/L2,
  //    plain stores to per-split slices)
  k_expand_mfma<<<dim3(NTILE_MAX, CSPLIT), 256, 0, stream>>>(
      h2gb, h2ub, BgT, BuT, AdT, rseg, grp_n, h1s0, h1s1, h1s2, h1s3);
  // 9) per-expert down core via MFMA + rw (sums 4 slices while staging)
  k_core_down<<<En, 512, 0, stream>>>(h1s0, h1s1, h1s2, h1s3, CdT, rwp,
                                      rseg, off_e, cnt_e, y);
  // 10) combine (MFMA bf16)
  k_combine<<<dim3(Dn / 128, T0n / 128), 256, 0, stream>>>(y, BdT, out);
}

// Round 11
// 320.690 us; speedup vs baseline: 1.0320x; 1.0320x over previous
//
#include <hip/hip_runtime.h>
#include <math.h>

// Problem dims
constexpr int T0n = 2048;   // tokens
constexpr int Dn  = 2048;   // hidden
constexpr int En  = 256;    // experts
constexpr int Gn  = 8;      // groups
constexpr int EGn = 32;     // experts per group
constexpr int Rn  = 64;     // tucker rank
constexpr int In  = 1408;   // intermediate

constexpr int NROWS = T0n * 8;    // 16384 dispatched rows
constexpr int SEGCAP = NROWS;     // per-group segment capacity in rseg
constexpr int KS_R = 4;           // router split-K (i32 accumulation is exact, any split OK)
constexpr int NTILE_MAX = NROWS / 128 + Gn;   // 136: upper bound on sum ceil(ng/128)

typedef __attribute__((ext_vector_type(8))) short s8v;    // 8 bf16
typedef __attribute__((ext_vector_type(4))) float f4v;    // 4 fp32
typedef __attribute__((ext_vector_type(4))) int i4v;      // 16 i8 operand / 4 i32 acc
#define MFMA16(a, b, c) __builtin_amdgcn_mfma_f32_16x16x32_bf16(a, b, c, 0, 0, 0)
#define MFMAI8(a, b, c) __builtin_amdgcn_mfma_i32_16x16x64_i8(a, b, c, 0, 0, 0)

__device__ __forceinline__ unsigned short f2bf(float x) {
  unsigned int u = __float_as_uint(x);
  unsigned int r = (u + 0x7FFFu + ((u >> 16) & 1u)) >> 16;
  return (unsigned short)r;
}

// ---------------------------------------------------------------------------
// Fused batched transpose+convert for 9 weight tensors:
// src f32 [batch][rows][cols] -> dst bf16 [batch][cols][rows].
// ---------------------------------------------------------------------------
struct TD { const float* src; unsigned short* dst; int rows, cols, nbx, per_batch, base; };
struct TD9 { TD t[9]; };

__global__ __launch_bounds__(256) void k_tcvt9(TD9 D) {
  __shared__ float tbuf[32][33];
  int id = blockIdx.x;
  int ti = 0;
#pragma unroll
  for (int i = 1; i < 9; ++i) ti = (id >= D.t[i].base) ? i : ti;
  TD d = D.t[ti];
  int local = id - d.base;
  int bz = local / d.per_batch;
  int rem = local - bz * d.per_batch;
  int by = rem / d.nbx;
  int bx = rem - by * d.nbx;

  size_t boff = (size_t)bz * d.rows * d.cols;
  const float* src = d.src + boff;
  unsigned short* dst = d.dst + boff;
  int c0 = bx * 32, r0 = by * 32;
  int tx = threadIdx.x & 31, ty = threadIdx.x >> 5;   // ty 0..7
  for (int i = ty; i < 32; i += 8)
    tbuf[i][tx] = src[(size_t)(r0 + i) * d.cols + c0 + tx];
  __syncthreads();
  for (int i = ty; i < 32; i += 8)
    dst[(size_t)(c0 + i) * d.rows + r0 + tx] = f2bf(tbuf[tx][i]);
}

// ---------------------------------------------------------------------------
// H f32 -> bf16 once (R15). Removes the 8x redundant H load+convert in
// k_h1_mfma (grid (32,8): same H element was read+converted once PER GROUP).
// ---------------------------------------------------------------------------
__global__ __launch_bounds__(256) void k_hcvt(
    const float* __restrict__ H, unsigned short* __restrict__ Hbf) {
  size_t i = ((size_t)blockIdx.x * 256 + threadIdx.x) * 8;
  float4 v0 = *(const float4*)&H[i];
  float4 v1 = *(const float4*)&H[i + 4];
  ushort4 o0, o1;
  o0.x = f2bf(v0.x); o0.y = f2bf(v0.y); o0.z = f2bf(v0.z); o0.w = f2bf(v0.w);
  o1.x = f2bf(v1.x); o1.y = f2bf(v1.y); o1.z = f2bf(v1.z); o1.w = f2bf(v1.w);
  *(ushort4*)&Hbf[i] = o0;
  *(ushort4*)&Hbf[i + 4] = o1;
}

// ---------------------------------------------------------------------------
// ROUTER, exact fixed-point path (R8, HW-verified R2: absmax unchanged):
// logits = H @ W with H,W decomposed into 4 signed 8-bit limbs each;
// limb-pair products (k+l>=2) accumulated exactly in i32 MFMA.
// ---------------------------------------------------------------------------
__device__ __forceinline__ int4 limbs4(float v, double sc) {
  double d = (double)v * sc;           // exact in double
  d = fmin(fmax(d, -2.0e9), 2.0e9);    // clamp (unreachable for this data)
  int x = __double2int_rn(d);
  int l0 = (int)(signed char)(x & 0xff); x = (x - l0) >> 8;   // exact
  int l1 = (int)(signed char)(x & 0xff); x = (x - l1) >> 8;
  int l2 = (int)(signed char)(x & 0xff); x = (x - l2) >> 8;
  return make_int4(l0, l1, l2, x);     // x fits i8
}

// hidden [2048][2048] f32 -> hq planes [4][2048][2048] i8 (limb-major).
__global__ __launch_bounds__(256) void k_quant_h(
    const float* __restrict__ H, char* __restrict__ hq) {
  const size_t PL = (size_t)T0n * Dn;
  size_t i = (size_t)blockIdx.x * 256 + threadIdx.x;   // group of 4 elements
  float4 v = *(const float4*)&H[i * 4];
  int4 a = limbs4(v.x, 268435456.0);   // 2^28
  int4 b = limbs4(v.y, 268435456.0);
  int4 c = limbs4(v.z, 268435456.0);
  int4 d = limbs4(v.w, 268435456.0);
  unsigned int p0 = (a.x & 0xff) | ((b.x & 0xff) << 8) | ((c.x & 0xff) << 16) | ((unsigned)(d.x & 0xff) << 24);
  unsigned int p1 = (a.y & 0xff) | ((b.y & 0xff) << 8) | ((c.y & 0xff) << 16) | ((unsigned)(d.y & 0xff) << 24);
  unsigned int p2 = (a.z & 0xff) | ((b.z & 0xff) << 8) | ((c.z & 0xff) << 16) | ((unsigned)(d.z & 0xff) << 24);
  unsigned int p3 = (a.w & 0xff) | ((b.w & 0xff) << 8) | ((c.w & 0xff) << 16) | ((unsigned)(d.w & 0xff) << 24);
  *(unsigned int*)&hq[0 * PL + i * 4] = p0;
  *(unsigned int*)&hq[1 * PL + i * 4] = p1;
  *(unsigned int*)&hq[2 * PL + i * 4] = p2;
  *(unsigned int*)&hq[3 * PL + i * 4] = p3;
}

// w_gate [2048][256] f32 -> wqT planes [4][256][2048] i8 (transposed, limb-major).
__global__ __launch_bounds__(256) void k_quant_wT(
    const float* __restrict__ W, char* __restrict__ wqT) {
  __shared__ float tb[32][33];
  const size_t PL = (size_t)En * Dn;
  int kb = blockIdx.x * 32, nb = blockIdx.y * 32;
  int tx = threadIdx.x & 31, ty = threadIdx.x >> 5;
  for (int i = ty; i < 32; i += 8)
    tb[i][tx] = W[(size_t)(kb + i) * En + nb + tx];
  __syncthreads();
  for (int i = ty; i < 32; i += 8) {
    int4 l = limbs4(tb[tx][i], 8589934592.0);   // 2^33
    size_t off = (size_t)(nb + i) * Dn + kb + tx;
    wqT[0 * PL + off] = (char)l.x;
    wqT[1 * PL + off] = (char)l.y;
    wqT[2 * PL + off] = (char)l.z;
    wqT[3 * PL + off] = (char)l.w;
  }
}

// i8 MFMA router GEMM. grid (En/64, T0n/64, KS_R). HW-verified R2.
__global__ __launch_bounds__(256) void k_router_i8(
    const char* __restrict__ hq, const char* __restrict__ wqT,
    float* __restrict__ part) {
  __shared__ __align__(16) char Asl[4][64][80];   // [limb][m-row][k]
  __shared__ __align__(16) char Bsl[4][64][80];   // [limb][n-row][k]
  const int n0 = blockIdx.x * 64, m0 = blockIdx.y * 64;
  const int kc = blockIdx.z;
  const int tid = threadIdx.x;
  const int w = tid >> 6, ln = tid & 63;
  const int quad = ln >> 4, lane16 = ln & 15;

  const char* ha = hq + ((size_t)w * T0n + m0 + ln) * Dn;   // plane w, row m0+ln
  const char* ba = wqT + ((size_t)w * En + n0 + ln) * Dn;   // plane w, row n0+ln

  i4v acc[4][5] = {};   // [m-tile][s-group s=k+l-2]

  const int kbeg = kc * (Dn / KS_R);
  for (int k0 = kbeg; k0 < kbeg + Dn / KS_R; k0 += 64) {
#pragma unroll
    for (int q = 0; q < 4; ++q) {
      *(uint4*)&Asl[w][ln][q * 16] = *(const uint4*)&ha[k0 + q * 16];
      *(uint4*)&Bsl[w][ln][q * 16] = *(const uint4*)&ba[k0 + q * 16];
    }
    __syncthreads();
    i4v b0 = *(const i4v*)&Bsl[0][w * 16 + lane16][quad * 16];
    i4v b1 = *(const i4v*)&Bsl[1][w * 16 + lane16][quad * 16];
    i4v b2 = *(const i4v*)&Bsl[2][w * 16 + lane16][quad * 16];
    i4v b3 = *(const i4v*)&Bsl[3][w * 16 + lane16][quad * 16];
#pragma unroll
    for (int mt = 0; mt < 4; ++mt) {
      i4v a0 = *(const i4v*)&Asl[0][mt * 16 + lane16][quad * 16];
      i4v a1 = *(const i4v*)&Asl[1][mt * 16 + lane16][quad * 16];
      i4v a2 = *(const i4v*)&Asl[2][mt * 16 + lane16][quad * 16];
      i4v a3 = *(const i4v*)&Asl[3][mt * 16 + lane16][quad * 16];
      // s = 2
      acc[mt][0] = MFMAI8(a0, b2, acc[mt][0]);
      acc[mt][0] = MFMAI8(a1, b1, acc[mt][0]);
      acc[mt][0] = MFMAI8(a2, b0, acc[mt][0]);
      // s = 3
      acc[mt][1] = MFMAI8(a0, b3, acc[mt][1]);
      acc[mt][1] = MFMAI8(a1, b2, acc[mt][1]);
      acc[mt][1] = MFMAI8(a2, b1, acc[mt][1]);
      acc[mt][1] = MFMAI8(a3, b0, acc[mt][1]);
      // s = 4
      acc[mt][2] = MFMAI8(a1, b3, acc[mt][2]);
      acc[mt][2] = MFMAI8(a2, b2, acc[mt][2]);
      acc[mt][2] = MFMAI8(a3, b1, acc[mt][2]);
      // s = 5
      acc[mt][3] = MFMAI8(a2, b3, acc[mt][3]);
      acc[mt][3] = MFMAI8(a3, b2, acc[mt][3]);
      // s = 6
      acc[mt][4] = MFMAI8(a3, b3, acc[mt][4]);
    }
    __syncthreads();
  }

  float* prow = part + (size_t)kc * T0n * En;
#pragma unroll
  for (int mt = 0; mt < 4; ++mt)
#pragma unroll
    for (int r = 0; r < 4; ++r) {
      int row = m0 + mt * 16 + quad * 4 + r;
      int col = n0 + w * 16 + lane16;
      double v = (double)acc[mt][0][r] * 0x1p-45 +
                 (double)acc[mt][1][r] * 0x1p-37 +
                 (double)acc[mt][2][r] * 0x1p-29 +
                 (double)acc[mt][3][r] * 0x1p-21 +
                 (double)acc[mt][4][r] * 0x1p-13;
      prow[(size_t)row * En + col] = (float)v;
    }
}

// ---------------------------------------------------------------------------
// Top-8: one wave per token, shuffle butterfly. Sums KS_R fp32 partials in fp64.
// ---------------------------------------------------------------------------
__global__ __launch_bounds__(256) void k_topk(
    const float* __restrict__ part, int* __restrict__ sel,
    float* __restrict__ rw, int* __restrict__ cnt_e) {
  const int wid = threadIdx.x >> 6, ln = threadIdx.x & 63;
  const int t = blockIdx.x * 4 + wid;

  double v[4];
#pragma unroll
  for (int j = 0; j < 4; ++j) {
    double s = 0.0;
#pragma unroll
    for (int kc = 0; kc < KS_R; ++kc)
      s += (double)part[((size_t)kc * T0n + t) * En + ln + 64 * j];
    v[j] = s;
  }

  float topv[8];
  int topi[8];
#pragma unroll
  for (int k = 0; k < 8; ++k) {
    double bv = v[0]; int bi = ln;
#pragma unroll
    for (int j = 1; j < 4; ++j) {
      int cand = ln + 64 * j;
      if (v[j] > bv || (v[j] == bv && cand < bi)) { bv = v[j]; bi = cand; }
    }
#pragma unroll
    for (int off = 32; off > 0; off >>= 1) {
      double ov = __shfl_xor(bv, off);
      int oi = __shfl_xor(bi, off);
      if (ov > bv || (ov == bv && oi < bi)) { bv = ov; bi = oi; }
    }
    topv[k] = (float)bv; topi[k] = bi;
    if ((bi & 63) == ln) v[bi >> 6] = -1e300;
  }

  if (ln < 8) {
    float m = topv[0];
    float ssum = 0.f;
#pragma unroll
    for (int k = 0; k < 8; ++k) ssum += expf(topv[k] - m);
    rw[t * 8 + ln] = expf(topv[ln] - m) / ssum;
    sel[t * 8 + ln] = topi[ln];
    atomicAdd(&cnt_e[topi[ln]], 1);
  }
}

// Parallel per-group prefix over 256 experts.
__global__ __launch_bounds__(256) void k_scan(
    const int* __restrict__ cnt_e, int* __restrict__ off_e,
    int* __restrict__ cur_e, int* __restrict__ grp_n) {
  __shared__ int c[256];
  int tid = threadIdx.x;
  c[tid] = cnt_e[tid];
  __syncthreads();
  int g = tid >> 5, ei = tid & 31;
  int run = 0;
  for (int i = 0; i < ei; ++i) run += c[(g << 5) + i];
  off_e[tid] = g * SEGCAP + run;
  cur_e[tid] = g * SEGCAP + run;
  if (ei == 31) grp_n[g] = run + c[tid];
}

__global__ void k_scatter(const int* __restrict__ sel, int* __restrict__ cur_e,
                          int* __restrict__ rseg) {
  int i = blockIdx.x * 256 + threadIdx.x;
  int e = sel[i];
  int pos = atomicAdd(&cur_e[e], 1);
  rseg[pos] = i;
}

// ---------------------------------------------------------------------------
// h1 = H @ A_fac[g]. R15: H pre-converted to bf16 (k_hcvt) -> single uint4
// staging load per thread (was 2x float4 + 8x f2bf, redundant per group).
// 512 threads: waves 0-3 gate, 4-7 up. grid (T0/64, G).
// ---------------------------------------------------------------------------
__global__ __launch_bounds__(512) void k_h1_mfma(
    const unsigned short* __restrict__ Hbf,
    const unsigned short* __restrict__ AgT, const unsigned short* __restrict__ AuT,
    unsigned short* __restrict__ h1gb, unsigned short* __restrict__ h1ub) {
  const int t0 = blockIdx.x * 64;
  const int g = blockIdx.y;
  const unsigned short* Wg = AgT + (size_t)g * Rn * Dn;
  const unsigned short* Wu = AuT + (size_t)g * Rn * Dn;

  __shared__ unsigned short As[64 * 72];
  __shared__ unsigned short Bg_l[64 * 72];
  __shared__ unsigned short Bu_l[64 * 72];
  const int tid = threadIdx.x;
  const int w = tid >> 6, ln = tid & 63;
  const int path = w >> 2, ws = w & 3;
  const int quad = ln >> 4, lane16 = ln & 15;
  const int j = tid >> 3, q = (tid & 7) * 8;   // 64 rows x 8 chunks

  f4v S[4] = {};

  for (int k0 = 0; k0 < Dn; k0 += 64) {
    {
      *(uint4*)&As[j * 72 + q] = *(const uint4*)&Hbf[(size_t)(t0 + j) * Dn + k0 + q];
      *(uint4*)&Bg_l[j * 72 + q] = *(const uint4*)&Wg[(size_t)j * Dn + k0 + q];
      *(uint4*)&Bu_l[j * 72 + q] = *(const uint4*)&Wu[(size_t)j * Dn + k0 + q];
    }
    __syncthreads();
    const unsigned short* Bl = path ? Bu_l : Bg_l;
#pragma unroll
    for (int kk = 0; kk < 2; ++kk) {
      s8v a = *(const s8v*)&As[(ws * 16 + lane16) * 72 + kk * 32 + quad * 8];
#pragma unroll
      for (int nt = 0; nt < 4; ++nt) {
        s8v b = *(const s8v*)&Bl[(nt * 16 + lane16) * 72 + kk * 32 + quad * 8];
        S[nt] = MFMA16(a, b, S[nt]);
      }
    }
    __syncthreads();
  }
  unsigned short* out = path ? h1ub : h1gb;
#pragma unroll
  for (int nt = 0; nt < 4; ++nt)
#pragma unroll
    for (int r = 0; r < 4; ++r) {
      int row = t0 + ws * 16 + quad * 4 + r;
      int col = g * 64 + nt * 16 + lane16;
      out[(size_t)row * (Gn * Rn) + col] = f2bf(S[nt][r]);
    }
}

// ---------------------------------------------------------------------------
// Per-expert core (gate/up) via MFMA. 512 threads: waves 0-3 gate, 4-7 up.
// ---------------------------------------------------------------------------
__global__ __launch_bounds__(512) void k_core_gu(
    const unsigned short* __restrict__ h1gb, const unsigned short* __restrict__ h1ub,
    const unsigned short* __restrict__ CgT, const unsigned short* __restrict__ CuT,
    const int* __restrict__ rseg, const int* __restrict__ off_e,
    const int* __restrict__ cnt_e,
    unsigned short* __restrict__ h2gb, unsigned short* __restrict__ h2ub) {
  const int e = blockIdx.x;
  const int ne = cnt_e[e];
  if (ne == 0) return;
  const int g = e >> 5;
  const int base = off_e[e];
  __shared__ unsigned short Cg_l[64 * 72];
  __shared__ unsigned short Cu_l[64 * 72];
  __shared__ unsigned short Ags[64 * 72];
  __shared__ unsigned short Aus[64 * 72];
  __shared__ int rids[64];
  const int tid = threadIdx.x;
  const int w = tid >> 6, ln = tid & 63;
  const int path = w >> 2, ws = w & 3;
  const int quad = ln >> 4, lane16 = ln & 15;
  const int j = tid >> 3, q = (tid & 7) * 8;
  {
    const unsigned short* cg = CgT + (size_t)e * (Rn * Rn);
    const unsigned short* cu = CuT + (size_t)e * (Rn * Rn);
    *(uint4*)&Cg_l[j * 72 + q] = *(const uint4*)&cg[j * 64 + q];
    *(uint4*)&Cu_l[j * 72 + q] = *(const uint4*)&cu[j * 64 + q];
  }
  const int ntile = (ne + 63) >> 6;
  for (int it = 0; it < ntile; ++it) {
    int mi = it * 64 + j;
    int rid = (mi < ne) ? rseg[base + mi] : -1;
    if ((tid & 7) == 0) rids[j] = rid;
    uint4 zg = {0, 0, 0, 0}, zu = {0, 0, 0, 0};
    if (rid >= 0) {
      zg = *(const uint4*)&h1gb[(size_t)(rid >> 3) * (Gn * Rn) + g * 64 + q];
      zu = *(const uint4*)&h1ub[(size_t)(rid >> 3) * (Gn * Rn) + g * 64 + q];
    }
    *(uint4*)&Ags[j * 72 + q] = zg;
    *(uint4*)&Aus[j * 72 + q] = zu;
    __syncthreads();
    const unsigned short* Al = path ? Aus : Ags;
    const unsigned short* Cl = path ? Cu_l : Cg_l;
    f4v S[4] = {};
#pragma unroll
    for (int kk = 0; kk < 2; ++kk) {
      s8v a = *(const s8v*)&Al[(ws * 16 + lane16) * 72 + kk * 32 + quad * 8];
#pragma unroll
      for (int nt = 0; nt < 4; ++nt) {
        s8v b = *(const s8v*)&Cl[(nt * 16 + lane16) * 72 + kk * 32 + quad * 8];
        S[nt] = MFMA16(a, b, S[nt]);
      }
    }
    unsigned short* out = path ? h2ub : h2gb;
#pragma unroll
    for (int nt = 0; nt < 4; ++nt)
#pragma unroll
      for (int r = 0; r < 4; ++r) {
        int rid2 = rids[ws * 16 + quad * 4 + r];
        if (rid2 >= 0)
          out[(size_t)rid2 * 64 + nt * 16 + lane16] = f2bf(S[nt][r]);
      }
    __syncthreads();
  }
}

// ---------------------------------------------------------------------------
// Fused expand + down-A via MFMA. REVERTED to the measured-best R5/R10 form
// (49.7us): LDS-staged B tiles, reg H-frags, per-wave inter, atomicAdd
// epilogue, compacted flat-tile grid, CSPLIT=4. Expand-structure ledger
// (R9-R14): LDS down=null, reg-prefetch=-5%, CSPLIT8=-30% (write traffic),
// atomic-free=null, barrier-free=-37% (per-wave vmem 4x). This is the floor
// for this structure; further expand-only surgery has negative EV.
// ---------------------------------------------------------------------------
__global__ __launch_bounds__(256) void k_expand_mfma(
    const unsigned short* __restrict__ h2gb, const unsigned short* __restrict__ h2ub,
    const unsigned short* __restrict__ BgT, const unsigned short* __restrict__ BuT,
    const unsigned short* __restrict__ AdT,
    const int* __restrict__ rseg, const int* __restrict__ grp_n,
    float* __restrict__ h1d) {
  // Decode flat tile id -> (g, m0) via prefix over per-group tile counts.
  int t = blockIdx.x;
  int g = -1, m0 = 0, ng = 0;
  {
    int pre = 0;
#pragma unroll
    for (int gg = 0; gg < Gn; ++gg) {
      int n = grp_n[gg];
      int nt = (n + 127) >> 7;
      if (g < 0 && t < pre + nt) { g = gg; m0 = (t - pre) << 7; ng = n; }
      pre += nt;
    }
  }
  if (g < 0) return;
  const int c_beg = blockIdx.y * 6;
  const int c_end = min(22, c_beg + 6);

  __shared__ unsigned short Bg_l[64 * 72];
  __shared__ unsigned short Bu_l[64 * 72];
  __shared__ unsigned short Ad_l[64 * 72];
  __shared__ unsigned short inter_l[4][32 * 72];   // per-wave private
  __shared__ int rids[128];

  const int tid = threadIdx.x;
  const int w = tid >> 6, ln = tid & 63;
  const int quad = ln >> 4, lane16 = ln & 15;

  if (tid < 128) rids[tid] = (m0 + tid < ng) ? rseg[g * SEGCAP + m0 + tid] : -1;
  __syncthreads();

  // H gate/up fragments in registers: wave w owns rows w*32..w*32+31.
  s8v ag[2][2], au[2][2];
#pragma unroll
  for (int mt = 0; mt < 2; ++mt) {
    int rid = rids[w * 32 + mt * 16 + lane16];
#pragma unroll
    for (int kk = 0; kk < 2; ++kk) {
      s8v zg = {}, zu = {};
      if (rid >= 0) {
        zg = *(const s8v*)&h2gb[(size_t)rid * 64 + kk * 32 + quad * 8];
        zu = *(const s8v*)&h2ub[(size_t)rid * 64 + kk * 32 + quad * 8];
      }
      ag[mt][kk] = zg;
      au[mt][kk] = zu;
    }
  }

  const unsigned short* Bg_base = BgT + (size_t)g * In * Rn;
  const unsigned short* Bu_base = BuT + (size_t)g * In * Rn;
  const unsigned short* Ad_base = AdT + (size_t)g * Rn * In;

  unsigned short* ib = &inter_l[w][0];
  f4v P[2][4] = {};

  for (int c = c_beg; c < c_end; ++c) {
    const int i0 = c * 64;
#pragma unroll
    for (int i = 0; i < 2; ++i) {
      int cq = tid + i * 256;
      int row = cq >> 3, co = (cq & 7) * 8;
      *(uint4*)&Bg_l[row * 72 + co] = *(const uint4*)&Bg_base[(size_t)(i0 + row) * Rn + co];
      *(uint4*)&Bu_l[row * 72 + co] = *(const uint4*)&Bu_base[(size_t)(i0 + row) * Rn + co];
      *(uint4*)&Ad_l[row * 72 + co] = *(const uint4*)&Ad_base[(size_t)row * In + i0 + co];
    }
    __syncthreads();   // B tiles ready

    f4v Sg[2][4] = {}, Su[2][4] = {};
#pragma unroll
    for (int kk = 0; kk < 2; ++kk) {
      s8v bg[4], bu[4];
#pragma unroll
      for (int nt = 0; nt < 4; ++nt) {
        bg[nt] = *(const s8v*)&Bg_l[(nt * 16 + lane16) * 72 + kk * 32 + quad * 8];
        bu[nt] = *(const s8v*)&Bu_l[(nt * 16 + lane16) * 72 + kk * 32 + quad * 8];
      }
#pragma unroll
      for (int mt = 0; mt < 2; ++mt)
#pragma unroll
        for (int nt = 0; nt < 4; ++nt) {
          Sg[mt][nt] = MFMA16(ag[mt][kk], bg[nt], Sg[mt][nt]);
          Su[mt][nt] = MFMA16(au[mt][kk], bu[nt], Su[mt][nt]);
        }
    }

    // silu(gate)*up -> per-wave inter region. No barrier: wave-local W->R.
#pragma unroll
    for (int mt = 0; mt < 2; ++mt)
#pragma unroll
      for (int nt = 0; nt < 4; ++nt)
#pragma unroll
        for (int r = 0; r < 4; ++r) {
          float sg = Sg[mt][nt][r];
          float v = sg / (1.f + __expf(-sg)) * Su[mt][nt][r];
          ib[(mt * 16 + quad * 4 + r) * 72 + nt * 16 + lane16] = f2bf(v);
        }
    asm volatile("s_waitcnt lgkmcnt(0)" ::: "memory");   // wave-local W->R order

#pragma unroll
    for (int kk = 0; kk < 2; ++kk) {
      s8v ai[2], bd[4];
#pragma unroll
      for (int mt = 0; mt < 2; ++mt)
        ai[mt] = *(const s8v*)&ib[(mt * 16 + lane16) * 72 + kk * 32 + quad * 8];
#pragma unroll
      for (int nt = 0; nt < 4; ++nt)
        bd[nt] = *(const s8v*)&Ad_l[(nt * 16 + lane16) * 72 + kk * 32 + quad * 8];
#pragma unroll
      for (int mt = 0; mt < 2; ++mt)
#pragma unroll
        for (int nt = 0; nt < 4; ++nt)
          P[mt][nt] = MFMA16(ai[mt], bd[nt], P[mt][nt]);
    }
    __syncthreads();   // protect Bg/Bu/Ad before next chunk's load
  }

#pragma unroll
  for (int mt = 0; mt < 2; ++mt)
#pragma unroll
    for (int nt = 0; nt < 4; ++nt)
#pragma unroll
      for (int r = 0; r < 4; ++r) {
        int lrow = w * 32 + mt * 16 + quad * 4 + r;
        int rid = rids[lrow];
        if (rid >= 0)
          atomicAdd(&h1d[(size_t)rid * 64 + nt * 16 + lane16], P[mt][nt][r]);
      }
}

// ---------------------------------------------------------------------------
// Per-expert down core via MFMA + routing weight, reduce to y[t,g,64].
// 512 threads: 128 rows/iter.
// ---------------------------------------------------------------------------
__global__ __launch_bounds__(512) void k_core_down(
    const float* __restrict__ h1d, const unsigned short* __restrict__ CdT,
    const float* __restrict__ rw,
    const int* __restrict__ rseg, const int* __restrict__ off_e,
    const int* __restrict__ cnt_e,
    float* __restrict__ y) {
  const int e = blockIdx.x;
  const int ne = cnt_e[e];
  if (ne == 0) return;
  const int g = e >> 5;
  const int base = off_e[e];
  __shared__ unsigned short Bd_l[64 * 72];
  __shared__ unsigned short Ad_l[128 * 72];
  __shared__ int rids[128];
  const int tid = threadIdx.x;
  const int w = tid >> 6, ln = tid & 63;
  const int quad = ln >> 4, lane16 = ln & 15;
  {
    int j = tid >> 3, q = (tid & 7) * 8;
    const unsigned short* cd = CdT + (size_t)e * (Rn * Rn);
    *(uint4*)&Bd_l[j * 72 + q] = *(const uint4*)&cd[j * 64 + q];
  }
  const int gj = tid >> 2, gq = (tid & 3) * 16;   // 128 rows x 4 chunks of 16
  const int ntile = (ne + 127) >> 7;
  for (int it = 0; it < ntile; ++it) {
    int mi = it * 128 + gj;
    int rid = (mi < ne) ? rseg[base + mi] : -1;
    if ((tid & 3) == 0) rids[gj] = rid;
#pragma unroll
    for (int i = 0; i < 4; ++i) {
      int kb = gq + i * 4;
      float4 vd = {0.f, 0.f, 0.f, 0.f};
      if (rid >= 0) vd = *(const float4*)&h1d[(size_t)rid * 64 + kb];
      ushort4 od;
      od.x = f2bf(vd.x); od.y = f2bf(vd.y); od.z = f2bf(vd.z); od.w = f2bf(vd.w);
      *(ushort4*)&Ad_l[gj * 72 + kb] = od;
    }
    __syncthreads();
    f4v Sd[4] = {};
#pragma unroll
    for (int kk = 0; kk < 2; ++kk) {
      s8v ad = *(const s8v*)&Ad_l[(w * 16 + lane16) * 72 + kk * 32 + quad * 8];
#pragma unroll
      for (int nt = 0; nt < 4; ++nt) {
        s8v bd = *(const s8v*)&Bd_l[(nt * 16 + lane16) * 72 + kk * 32 + quad * 8];
        Sd[nt] = MFMA16(ad, bd, Sd[nt]);
      }
    }
#pragma unroll
    for (int nt = 0; nt < 4; ++nt)
#pragma unroll
      for (int r = 0; r < 4; ++r) {
        int rid2 = rids[w * 16 + quad * 4 + r];
        if (rid2 >= 0) {
          float wgt = rw[rid2];
          atomicAdd(&y[(size_t)(rid2 >> 3) * (Gn * Rn) + g * 64 + nt * 16 + lane16],
                    wgt * Sd[nt][r]);
        }
      }
    __syncthreads();
  }
}

// ---------------------------------------------------------------------------
// Combine: out[2048,2048] = y[2048,512] @ B_down-as-[512,2048], MFMA bf16.
// ---------------------------------------------------------------------------
__global__ __launch_bounds__(256) void k_combine(
    const float* __restrict__ y, const unsigned short* __restrict__ BdT,
    float* __restrict__ outp) {
  const int t0 = blockIdx.y * 128, n0 = blockIdx.x * 128;
  __shared__ unsigned short As[128 * 72];
  __shared__ unsigned short Bs[128 * 72];
  const int tid = threadIdx.x;
  const int w = tid >> 6, ln = tid & 63;
  const int quad = ln >> 4, lane16 = ln & 15;
  const int mbase = (w >> 1) * 64, nbase = (w & 1) * 64;

  f4v acc[4][4] = {};

  for (int k0 = 0; k0 < Gn * Rn; k0 += 64) {
#pragma unroll
    for (int i = 0; i < 8; ++i) {
      int c = tid + i * 256;
      int row = c >> 4, cc = (c & 15) * 4;
      float4 v = *(const float4*)&y[(size_t)(t0 + row) * (Gn * Rn) + k0 + cc];
      ushort4 o;
      o.x = f2bf(v.x); o.y = f2bf(v.y); o.z = f2bf(v.z); o.w = f2bf(v.w);
      *(ushort4*)&As[row * 72 + cc] = o;
    }
#pragma unroll
    for (int i = 0; i < 4; ++i) {
      int c = tid + i * 256;
      int row = c >> 3, cc = (c & 7) * 8;
      *(uint4*)&Bs[row * 72 + cc] = *(const uint4*)&BdT[(size_t)(n0 + row) * (Gn * Rn) + k0 + cc];
    }
    __syncthreads();
#pragma unroll
    for (int kk = 0; kk < 2; ++kk) {
      s8v a[4], b[4];
#pragma unroll
      for (int mt = 0; mt < 4; ++mt)
        a[mt] = *(const s8v*)&As[(mbase + mt * 16 + lane16) * 72 + kk * 32 + quad * 8];
#pragma unroll
      for (int nt = 0; nt < 4; ++nt)
        b[nt] = *(const s8v*)&Bs[(nbase + nt * 16 + lane16) * 72 + kk * 32 + quad * 8];
#pragma unroll
      for (int mt = 0; mt < 4; ++mt)
#pragma unroll
        for (int nt = 0; nt < 4; ++nt)
          acc[mt][nt] = MFMA16(a[mt], b[nt], acc[mt][nt]);
    }
    __syncthreads();
  }
#pragma unroll
  for (int mt = 0; mt < 4; ++mt)
#pragma unroll
    for (int nt = 0; nt < 4; ++nt)
#pragma unroll
      for (int r = 0; r < 4; ++r)
        outp[(size_t)(t0 + mbase + mt * 16 + quad * 4 + r) * Dn +
             n0 + nbase + nt * 16 + lane16] = acc[mt][nt][r];
}

// ---------------------------------------------------------------------------
extern "C" void kernel_launch(void* const* d_in, const int* in_sizes, int n_in,
                              void* d_out, int out_size, void* d_ws, size_t ws_size,
                              hipStream_t stream) {
  const float* hidden = (const float*)d_in[0];
  const float* w_gate = (const float*)d_in[1];
  const float* A_gate = (const float*)d_in[2];
  const float* C_gate = (const float*)d_in[3];
  const float* B_gate = (const float*)d_in[4];
  const float* A_up   = (const float*)d_in[5];
  const float* C_up   = (const float*)d_in[6];
  const float* B_up   = (const float*)d_in[7];
  const float* A_down = (const float*)d_in[8];
  const float* C_down = (const float*)d_in[9];
  const float* B_down = (const float*)d_in[10];
  float* out = (float*)d_out;

  // Workspace layout (peak unchanged, 34.34 MB). Router-stage {part, hq, wqT}
  // overlay [0, 27.3MB), dead after k_topk (wqT dead after k_router_i8).
  // R15: Hbf (bf16 H, 8.39MB) aliases h1d+y exactly [25.3MB, 33.7MB) —
  // written by k_hcvt AFTER the router stage (stream-ordered past wqT's last
  // read), read by k_h1_mfma, dead before the h1d/y memsets (moved after
  // k_h1_mfma) and k_expand's h1d writes.
  char* base = (char*)d_ws;
  size_t o = 0;
  unsigned short* h2gb = (unsigned short*)(base + o); o += (size_t)NROWS * Rn * 2;
  unsigned short* h2ub = (unsigned short*)(base + o); o += (size_t)NROWS * Rn * 2;
  unsigned short* AgT  = (unsigned short*)(base + o); o += (size_t)Gn * Rn * Dn * 2;
  unsigned short* AuT  = (unsigned short*)(base + o); o += (size_t)Gn * Rn * Dn * 2;
  unsigned short* BgT  = (unsigned short*)(base + o); o += (size_t)Gn * In * Rn * 2;
  unsigned short* BuT  = (unsigned short*)(base + o); o += (size_t)Gn * In * Rn * 2;
  unsigned short* AdT  = (unsigned short*)(base + o); o += (size_t)Gn * Rn * In * 2;
  unsigned short* BdT  = (unsigned short*)(base + o); o += (size_t)Dn * Gn * Rn * 2;
  unsigned short* CgT  = (unsigned short*)(base + o); o += (size_t)En * Rn * Rn * 2;
  unsigned short* CuT  = (unsigned short*)(base + o); o += (size_t)En * Rn * Rn * 2;
  unsigned short* CdT  = (unsigned short*)(base + o); o += (size_t)En * Rn * Rn * 2;
  unsigned short* h1gb = (unsigned short*)(base + o); o += (size_t)T0n * Gn * Rn * 2;
  unsigned short* h1ub = (unsigned short*)(base + o); o += (size_t)T0n * Gn * Rn * 2;
  float* h1d = (float*)(base + o); o += (size_t)NROWS * Rn * 4;
  float* y   = (float*)(base + o); o += (size_t)T0n * Gn * Rn * 4;
  // ---- persistent smalls ----
  float* rwp = (float*)(base + o); o += (size_t)NROWS * 4;
  int* sel   = (int*)(base + o); o += (size_t)NROWS * 4;
  int* rseg  = (int*)(base + o); o += (size_t)Gn * SEGCAP * 4;
  int* cnt_e = (int*)(base + o); o += En * 4;
  int* off_e = (int*)(base + o); o += En * 4;
  int* cur_e = (int*)(base + o); o += En * 4;
  int* grp_n = (int*)(base + o); o += Gn * 4;
  // ---- router-stage aliases (dead after k_topk), inside [0, 27.3MB) ----
  float* part = (float*)base;                              // 8,388,608 B
  char* hq  = base + (size_t)KS_R * T0n * En * 4;          // +16,777,216 (4 i8 planes)
  char* wqT = hq + (size_t)4 * T0n * Dn;                   // +2,097,152  (4 i8 planes, T)
  // ---- Hbf alias: h1d (4.19MB) + y (4.19MB) = exactly T0n*Dn*2 bytes ----
  unsigned short* Hbf = (unsigned short*)h1d;

  hipMemsetAsync(cnt_e, 0, En * sizeof(int), stream);

  // 1) quantize inputs to exact 4x-i8 fixed-point limbs
  k_quant_h<<<T0n * Dn / 1024, 256, 0, stream>>>(hidden, hq);
  k_quant_wT<<<dim3(Dn / 32, En / 32), 256, 0, stream>>>(w_gate, wqT);
  // 2) router logits via exact i32-MFMA limb GEMM (split-K=4, fp32 slice partials)
  k_router_i8<<<dim3(En / 64, T0n / 64, KS_R), 256, 0, stream>>>(hq, wqT, part);
  // 3) top-8 + renorm + expert counts
  k_topk<<<T0n / 4, 256, 0, stream>>>(part, sel, rwp, cnt_e);
  // 4) offsets (parallel prefix) + scatter rows by expert
  k_scan<<<1, 256, 0, stream>>>(cnt_e, off_e, cur_e, grp_n);
  k_scatter<<<NROWS / 256, 256, 0, stream>>>(sel, cur_e, rseg);

  // part/hq/wqT now dead. Convert H to bf16 once (into the h1d+y alias).
  k_hcvt<<<T0n * Dn / 2048, 256, 0, stream>>>(hidden, Hbf);

  // 5) transpose+convert all 9 weight tensors to bf16 operand layouts
  {
    TD9 D;
    D.t[0] = {A_gate, AgT, Dn, Rn, Rn / 32, (Rn / 32) * (Dn / 32), 0};
    D.t[1] = {A_up,   AuT, Dn, Rn, Rn / 32, (Rn / 32) * (Dn / 32), 1024};
    D.t[2] = {B_gate, BgT, Rn, In, In / 32, (In / 32) * (Rn / 32), 2048};
    D.t[3] = {B_up,   BuT, Rn, In, In / 32, (In / 32) * (Rn / 32), 2752};
    D.t[4] = {A_down, AdT, In, Rn, Rn / 32, (Rn / 32) * (In / 32), 3456};
    D.t[5] = {B_down, BdT, Gn * Rn, Dn, Dn / 32, (Dn / 32) * (Gn * Rn / 32), 4160};
    D.t[6] = {C_gate, CgT, Rn, Rn, 2, 4, 5184};
    D.t[7] = {C_up,   CuT, Rn, Rn, 2, 4, 6208};
    D.t[8] = {C_down, CdT, Rn, Rn, 2, 4, 7232};
    k_tcvt9<<<8256, 256, 0, stream>>>(D);
  }

  // 6) dense in-factor projections (bf16 H from Hbf; single uint4 staging)
  k_h1_mfma<<<dim3(T0n / 64, Gn), 512, 0, stream>>>(Hbf, AgT, AuT, h1gb, h1ub);

  // Hbf dead; reclaim h1d + y.
  hipMemsetAsync(h1d, 0, (size_t)NROWS * Rn * sizeof(float), stream);
  hipMemsetAsync(y,   0, (size_t)T0n * Gn * Rn * sizeof(float), stream);

  // 7) per-expert core (gate/up) via MFMA (512 thr path-split)
  k_core_gu<<<En, 512, 0, stream>>>(h1gb, h1ub, CgT, CuT,
                                    rseg, off_e, cnt_e, h2gb, h2ub);
  // 8) fused expand + down-A (measured-best R5 form: LDS-staged, atomics)
  k_expand_mfma<<<dim3(NTILE_MAX, 4), 256, 0, stream>>>(
      h2gb, h2ub, BgT, BuT, AdT, rseg, grp_n, h1d);
  // 9) per-expert down core via MFMA + rw (512 thr, 128 rows/iter)
  k_core_down<<<En, 512, 0, stream>>>(h1d, CdT, rwp,
                                      rseg, off_e, cnt_e, y);
  // 10) combine (MFMA bf16)
  k_combine<<<dim3(Dn / 128, T0n / 128), 256, 0, stream>>>(y, BdT, out);
}

// Round 12
// 305.671 us; speedup vs baseline: 1.0827x; 1.0491x over previous
//
#include <hip/hip_runtime.h>
#include <math.h>

// Problem dims
constexpr int T0n = 2048;   // tokens
constexpr int Dn  = 2048;   // hidden
constexpr int En  = 256;    // experts
constexpr int Gn  = 8;      // groups
constexpr int EGn = 32;     // experts per group
constexpr int Rn  = 64;     // tucker rank
constexpr int In  = 1408;   // intermediate

constexpr int NROWS = T0n * 8;    // 16384 dispatched rows
constexpr int SEGCAP = NROWS;     // per-group segment capacity in rseg
constexpr int KS_R = 6;           // router split-K (R16: 4->6; i32 exact, uneven split OK)
constexpr int NTILE_MAX = NROWS / 128 + Gn;   // 136: upper bound on sum ceil(ng/128)

typedef __attribute__((ext_vector_type(8))) short s8v;    // 8 bf16
typedef __attribute__((ext_vector_type(4))) float f4v;    // 4 fp32
typedef __attribute__((ext_vector_type(4))) int i4v;      // 16 i8 operand / 4 i32 acc
#define MFMA16(a, b, c) __builtin_amdgcn_mfma_f32_16x16x32_bf16(a, b, c, 0, 0, 0)
#define MFMAI8(a, b, c) __builtin_amdgcn_mfma_i32_16x16x64_i8(a, b, c, 0, 0, 0)

__device__ __forceinline__ unsigned short f2bf(float x) {
  unsigned int u = __float_as_uint(x);
  unsigned int r = (u + 0x7FFFu + ((u >> 16) & 1u)) >> 16;
  return (unsigned short)r;
}

// ---------------------------------------------------------------------------
// Fused batched transpose+convert for 9 weight tensors:
// src f32 [batch][rows][cols] -> dst bf16 [batch][cols][rows].
// ---------------------------------------------------------------------------
struct TD { const float* src; unsigned short* dst; int rows, cols, nbx, per_batch, base; };
struct TD9 { TD t[9]; };

__global__ __launch_bounds__(256) void k_tcvt9(TD9 D) {
  __shared__ float tbuf[32][33];
  int id = blockIdx.x;
  int ti = 0;
#pragma unroll
  for (int i = 1; i < 9; ++i) ti = (id >= D.t[i].base) ? i : ti;
  TD d = D.t[ti];
  int local = id - d.base;
  int bz = local / d.per_batch;
  int rem = local - bz * d.per_batch;
  int by = rem / d.nbx;
  int bx = rem - by * d.nbx;

  size_t boff = (size_t)bz * d.rows * d.cols;
  const float* src = d.src + boff;
  unsigned short* dst = d.dst + boff;
  int c0 = bx * 32, r0 = by * 32;
  int tx = threadIdx.x & 31, ty = threadIdx.x >> 5;   // ty 0..7
  for (int i = ty; i < 32; i += 8)
    tbuf[i][tx] = src[(size_t)(r0 + i) * d.cols + c0 + tx];
  __syncthreads();
  for (int i = ty; i < 32; i += 8)
    dst[(size_t)(c0 + i) * d.rows + r0 + tx] = f2bf(tbuf[tx][i]);
}

// ---------------------------------------------------------------------------
// H f32 -> bf16 once (R15). Halves H traffic in k_h1_mfma.
// ---------------------------------------------------------------------------
__global__ __launch_bounds__(256) void k_hcvt(
    const float* __restrict__ H, unsigned short* __restrict__ Hbf) {
  size_t i = ((size_t)blockIdx.x * 256 + threadIdx.x) * 8;
  float4 v0 = *(const float4*)&H[i];
  float4 v1 = *(const float4*)&H[i + 4];
  ushort4 o0, o1;
  o0.x = f2bf(v0.x); o0.y = f2bf(v0.y); o0.z = f2bf(v0.z); o0.w = f2bf(v0.w);
  o1.x = f2bf(v1.x); o1.y = f2bf(v1.y); o1.z = f2bf(v1.z); o1.w = f2bf(v1.w);
  *(ushort4*)&Hbf[i] = o0;
  *(ushort4*)&Hbf[i + 4] = o1;
}

// ---------------------------------------------------------------------------
// ROUTER, fixed-point limb path (R8; R16: drop s=2 group).
// logits = H @ W, H/W in 4 signed 8-bit limbs; pairs k+l>=3 kept (10 MFMA,
// was 13). Dropped s=2 contribution: low-order limbs ~uniform +-128, random
// walk over K=2048 -> ~7e-9 rms/pair x 3 pairs, <=~1e-7 at 6 sigma; the
// dataset's ref-logit gap floor is >=~1e-6 (exact logits passed R2-R11).
// i32 accumulation exact -> any K-split valid.
// ---------------------------------------------------------------------------
__device__ __forceinline__ int4 limbs4(float v, double sc) {
  double d = (double)v * sc;           // exact in double
  d = fmin(fmax(d, -2.0e9), 2.0e9);    // clamp (unreachable for this data)
  int x = __double2int_rn(d);
  int l0 = (int)(signed char)(x & 0xff); x = (x - l0) >> 8;   // exact
  int l1 = (int)(signed char)(x & 0xff); x = (x - l1) >> 8;
  int l2 = (int)(signed char)(x & 0xff); x = (x - l2) >> 8;
  return make_int4(l0, l1, l2, x);     // x fits i8
}

// hidden [2048][2048] f32 -> hq planes [4][2048][2048] i8 (limb-major).
__global__ __launch_bounds__(256) void k_quant_h(
    const float* __restrict__ H, char* __restrict__ hq) {
  const size_t PL = (size_t)T0n * Dn;
  size_t i = (size_t)blockIdx.x * 256 + threadIdx.x;   // group of 4 elements
  float4 v = *(const float4*)&H[i * 4];
  int4 a = limbs4(v.x, 268435456.0);   // 2^28
  int4 b = limbs4(v.y, 268435456.0);
  int4 c = limbs4(v.z, 268435456.0);
  int4 d = limbs4(v.w, 268435456.0);
  unsigned int p0 = (a.x & 0xff) | ((b.x & 0xff) << 8) | ((c.x & 0xff) << 16) | ((unsigned)(d.x & 0xff) << 24);
  unsigned int p1 = (a.y & 0xff) | ((b.y & 0xff) << 8) | ((c.y & 0xff) << 16) | ((unsigned)(d.y & 0xff) << 24);
  unsigned int p2 = (a.z & 0xff) | ((b.z & 0xff) << 8) | ((c.z & 0xff) << 16) | ((unsigned)(d.z & 0xff) << 24);
  unsigned int p3 = (a.w & 0xff) | ((b.w & 0xff) << 8) | ((c.w & 0xff) << 16) | ((unsigned)(d.w & 0xff) << 24);
  *(unsigned int*)&hq[0 * PL + i * 4] = p0;
  *(unsigned int*)&hq[1 * PL + i * 4] = p1;
  *(unsigned int*)&hq[2 * PL + i * 4] = p2;
  *(unsigned int*)&hq[3 * PL + i * 4] = p3;
}

// w_gate [2048][256] f32 -> wqT planes [4][256][2048] i8 (transposed, limb-major).
__global__ __launch_bounds__(256) void k_quant_wT(
    const float* __restrict__ W, char* __restrict__ wqT) {
  __shared__ float tb[32][33];
  const size_t PL = (size_t)En * Dn;
  int kb = blockIdx.x * 32, nb = blockIdx.y * 32;
  int tx = threadIdx.x & 31, ty = threadIdx.x >> 5;
  for (int i = ty; i < 32; i += 8)
    tb[i][tx] = W[(size_t)(kb + i) * En + nb + tx];
  __syncthreads();
  for (int i = ty; i < 32; i += 8) {
    int4 l = limbs4(tb[tx][i], 8589934592.0);   // 2^33
    size_t off = (size_t)(nb + i) * Dn + kb + tx;
    wqT[0 * PL + off] = (char)l.x;
    wqT[1 * PL + off] = (char)l.y;
    wqT[2 * PL + off] = (char)l.z;
    wqT[3 * PL + off] = (char)l.w;
  }
}

// i8 MFMA router GEMM. R16: 10 MFMA/step (s>=3 only), KS_R=6 (uneven split).
// grid (En/64, T0n/64, KS_R).
__global__ __launch_bounds__(256) void k_router_i8(
    const char* __restrict__ hq, const char* __restrict__ wqT,
    float* __restrict__ part) {
  __shared__ __align__(16) char Asl[4][64][80];   // [limb][m-row][k]
  __shared__ __align__(16) char Bsl[4][64][80];   // [limb][n-row][k]
  const int n0 = blockIdx.x * 64, m0 = blockIdx.y * 64;
  const int kc = blockIdx.z;
  const int tid = threadIdx.x;
  const int w = tid >> 6, ln = tid & 63;
  const int quad = ln >> 4, lane16 = ln & 15;

  const char* ha = hq + ((size_t)w * T0n + m0 + ln) * Dn;   // plane w, row m0+ln
  const char* ba = wqT + ((size_t)w * En + n0 + ln) * Dn;   // plane w, row n0+ln

  i4v acc[4][4] = {};   // [m-tile][s-group s=k+l-3, s in 3..6]

  // Uneven K-split over 32 steps of 64: kc gets steps [kc*32/6,(kc+1)*32/6).
  const int kbeg = ((kc * 32) / KS_R) * 64;
  const int kend = (((kc + 1) * 32) / KS_R) * 64;
  for (int k0 = kbeg; k0 < kend; k0 += 64) {
#pragma unroll
    for (int q = 0; q < 4; ++q) {
      *(uint4*)&Asl[w][ln][q * 16] = *(const uint4*)&ha[k0 + q * 16];
      *(uint4*)&Bsl[w][ln][q * 16] = *(const uint4*)&ba[k0 + q * 16];
    }
    __syncthreads();
    i4v b0 = *(const i4v*)&Bsl[0][w * 16 + lane16][quad * 16];
    i4v b1 = *(const i4v*)&Bsl[1][w * 16 + lane16][quad * 16];
    i4v b2 = *(const i4v*)&Bsl[2][w * 16 + lane16][quad * 16];
    i4v b3 = *(const i4v*)&Bsl[3][w * 16 + lane16][quad * 16];
#pragma unroll
    for (int mt = 0; mt < 4; ++mt) {
      i4v a0 = *(const i4v*)&Asl[0][mt * 16 + lane16][quad * 16];
      i4v a1 = *(const i4v*)&Asl[1][mt * 16 + lane16][quad * 16];
      i4v a2 = *(const i4v*)&Asl[2][mt * 16 + lane16][quad * 16];
      i4v a3 = *(const i4v*)&Asl[3][mt * 16 + lane16][quad * 16];
      // s = 3
      acc[mt][0] = MFMAI8(a0, b3, acc[mt][0]);
      acc[mt][0] = MFMAI8(a1, b2, acc[mt][0]);
      acc[mt][0] = MFMAI8(a2, b1, acc[mt][0]);
      acc[mt][0] = MFMAI8(a3, b0, acc[mt][0]);
      // s = 4
      acc[mt][1] = MFMAI8(a1, b3, acc[mt][1]);
      acc[mt][1] = MFMAI8(a2, b2, acc[mt][1]);
      acc[mt][1] = MFMAI8(a3, b1, acc[mt][1]);
      // s = 5
      acc[mt][2] = MFMAI8(a2, b3, acc[mt][2]);
      acc[mt][2] = MFMAI8(a3, b2, acc[mt][2]);
      // s = 6
      acc[mt][3] = MFMAI8(a3, b3, acc[mt][3]);
    }
    __syncthreads();
  }

  // Combine 4 exact i32 sums at scales 2^(8s-61), s=3..6.
  float* prow = part + (size_t)kc * T0n * En;
#pragma unroll
  for (int mt = 0; mt < 4; ++mt)
#pragma unroll
    for (int r = 0; r < 4; ++r) {
      int row = m0 + mt * 16 + quad * 4 + r;
      int col = n0 + w * 16 + lane16;
      double v = (double)acc[mt][0][r] * 0x1p-37 +
                 (double)acc[mt][1][r] * 0x1p-29 +
                 (double)acc[mt][2][r] * 0x1p-21 +
                 (double)acc[mt][3][r] * 0x1p-13;
      prow[(size_t)row * En + col] = (float)v;
    }
}

// ---------------------------------------------------------------------------
// Top-8: one wave per token, shuffle butterfly. Sums KS_R fp32 partials in fp64.
// ---------------------------------------------------------------------------
__global__ __launch_bounds__(256) void k_topk(
    const float* __restrict__ part, int* __restrict__ sel,
    float* __restrict__ rw, int* __restrict__ cnt_e) {
  const int wid = threadIdx.x >> 6, ln = threadIdx.x & 63;
  const int t = blockIdx.x * 4 + wid;

  double v[4];
#pragma unroll
  for (int j = 0; j < 4; ++j) {
    double s = 0.0;
#pragma unroll
    for (int kc = 0; kc < KS_R; ++kc)
      s += (double)part[((size_t)kc * T0n + t) * En + ln + 64 * j];
    v[j] = s;
  }

  float topv[8];
  int topi[8];
#pragma unroll
  for (int k = 0; k < 8; ++k) {
    double bv = v[0]; int bi = ln;
#pragma unroll
    for (int j = 1; j < 4; ++j) {
      int cand = ln + 64 * j;
      if (v[j] > bv || (v[j] == bv && cand < bi)) { bv = v[j]; bi = cand; }
    }
#pragma unroll
    for (int off = 32; off > 0; off >>= 1) {
      double ov = __shfl_xor(bv, off);
      int oi = __shfl_xor(bi, off);
      if (ov > bv || (ov == bv && oi < bi)) { bv = ov; bi = oi; }
    }
    topv[k] = (float)bv; topi[k] = bi;
    if ((bi & 63) == ln) v[bi >> 6] = -1e300;
  }

  if (ln < 8) {
    float m = topv[0];
    float ssum = 0.f;
#pragma unroll
    for (int k = 0; k < 8; ++k) ssum += expf(topv[k] - m);
    rw[t * 8 + ln] = expf(topv[ln] - m) / ssum;
    sel[t * 8 + ln] = topi[ln];
    atomicAdd(&cnt_e[topi[ln]], 1);
  }
}

// Parallel per-group prefix over 256 experts.
__global__ __launch_bounds__(256) void k_scan(
    const int* __restrict__ cnt_e, int* __restrict__ off_e,
    int* __restrict__ cur_e, int* __restrict__ grp_n) {
  __shared__ int c[256];
  int tid = threadIdx.x;
  c[tid] = cnt_e[tid];
  __syncthreads();
  int g = tid >> 5, ei = tid & 31;
  int run = 0;
  for (int i = 0; i < ei; ++i) run += c[(g << 5) + i];
  off_e[tid] = g * SEGCAP + run;
  cur_e[tid] = g * SEGCAP + run;
  if (ei == 31) grp_n[g] = run + c[tid];
}

__global__ void k_scatter(const int* __restrict__ sel, int* __restrict__ cur_e,
                          int* __restrict__ rseg) {
  int i = blockIdx.x * 256 + threadIdx.x;
  int e = sel[i];
  int pos = atomicAdd(&cur_e[e], 1);
  rseg[pos] = i;
}

// ---------------------------------------------------------------------------
// h1 = H @ A_fac[g]. bf16 H (k_hcvt); single uint4 staging load per thread.
// 512 threads: waves 0-3 gate, 4-7 up. grid (T0/64, G).
// ---------------------------------------------------------------------------
__global__ __launch_bounds__(512) void k_h1_mfma(
    const unsigned short* __restrict__ Hbf,
    const unsigned short* __restrict__ AgT, const unsigned short* __restrict__ AuT,
    unsigned short* __restrict__ h1gb, unsigned short* __restrict__ h1ub) {
  const int t0 = blockIdx.x * 64;
  const int g = blockIdx.y;
  const unsigned short* Wg = AgT + (size_t)g * Rn * Dn;
  const unsigned short* Wu = AuT + (size_t)g * Rn * Dn;

  __shared__ unsigned short As[64 * 72];
  __shared__ unsigned short Bg_l[64 * 72];
  __shared__ unsigned short Bu_l[64 * 72];
  const int tid = threadIdx.x;
  const int w = tid >> 6, ln = tid & 63;
  const int path = w >> 2, ws = w & 3;
  const int quad = ln >> 4, lane16 = ln & 15;
  const int j = tid >> 3, q = (tid & 7) * 8;   // 64 rows x 8 chunks

  f4v S[4] = {};

  for (int k0 = 0; k0 < Dn; k0 += 64) {
    {
      *(uint4*)&As[j * 72 + q] = *(const uint4*)&Hbf[(size_t)(t0 + j) * Dn + k0 + q];
      *(uint4*)&Bg_l[j * 72 + q] = *(const uint4*)&Wg[(size_t)j * Dn + k0 + q];
      *(uint4*)&Bu_l[j * 72 + q] = *(const uint4*)&Wu[(size_t)j * Dn + k0 + q];
    }
    __syncthreads();
    const unsigned short* Bl = path ? Bu_l : Bg_l;
#pragma unroll
    for (int kk = 0; kk < 2; ++kk) {
      s8v a = *(const s8v*)&As[(ws * 16 + lane16) * 72 + kk * 32 + quad * 8];
#pragma unroll
      for (int nt = 0; nt < 4; ++nt) {
        s8v b = *(const s8v*)&Bl[(nt * 16 + lane16) * 72 + kk * 32 + quad * 8];
        S[nt] = MFMA16(a, b, S[nt]);
      }
    }
    __syncthreads();
  }
  unsigned short* out = path ? h1ub : h1gb;
#pragma unroll
  for (int nt = 0; nt < 4; ++nt)
#pragma unroll
    for (int r = 0; r < 4; ++r) {
      int row = t0 + ws * 16 + quad * 4 + r;
      int col = g * 64 + nt * 16 + lane16;
      out[(size_t)row * (Gn * Rn) + col] = f2bf(S[nt][r]);
    }
}

// ---------------------------------------------------------------------------
// Per-expert core (gate/up) via MFMA. 512 threads: waves 0-3 gate, 4-7 up.
// ---------------------------------------------------------------------------
__global__ __launch_bounds__(512) void k_core_gu(
    const unsigned short* __restrict__ h1gb, const unsigned short* __restrict__ h1ub,
    const unsigned short* __restrict__ CgT, const unsigned short* __restrict__ CuT,
    const int* __restrict__ rseg, const int* __restrict__ off_e,
    const int* __restrict__ cnt_e,
    unsigned short* __restrict__ h2gb, unsigned short* __restrict__ h2ub) {
  const int e = blockIdx.x;
  const int ne = cnt_e[e];
  if (ne == 0) return;
  const int g = e >> 5;
  const int base = off_e[e];
  __shared__ unsigned short Cg_l[64 * 72];
  __shared__ unsigned short Cu_l[64 * 72];
  __shared__ unsigned short Ags[64 * 72];
  __shared__ unsigned short Aus[64 * 72];
  __shared__ int rids[64];
  const int tid = threadIdx.x;
  const int w = tid >> 6, ln = tid & 63;
  const int path = w >> 2, ws = w & 3;
  const int quad = ln >> 4, lane16 = ln & 15;
  const int j = tid >> 3, q = (tid & 7) * 8;
  {
    const unsigned short* cg = CgT + (size_t)e * (Rn * Rn);
    const unsigned short* cu = CuT + (size_t)e * (Rn * Rn);
    *(uint4*)&Cg_l[j * 72 + q] = *(const uint4*)&cg[j * 64 + q];
    *(uint4*)&Cu_l[j * 72 + q] = *(const uint4*)&cu[j * 64 + q];
  }
  const int ntile = (ne + 63) >> 6;
  for (int it = 0; it < ntile; ++it) {
    int mi = it * 64 + j;
    int rid = (mi < ne) ? rseg[base + mi] : -1;
    if ((tid & 7) == 0) rids[j] = rid;
    uint4 zg = {0, 0, 0, 0}, zu = {0, 0, 0, 0};
    if (rid >= 0) {
      zg = *(const uint4*)&h1gb[(size_t)(rid >> 3) * (Gn * Rn) + g * 64 + q];
      zu = *(const uint4*)&h1ub[(size_t)(rid >> 3) * (Gn * Rn) + g * 64 + q];
    }
    *(uint4*)&Ags[j * 72 + q] = zg;
    *(uint4*)&Aus[j * 72 + q] = zu;
    __syncthreads();
    const unsigned short* Al = path ? Aus : Ags;
    const unsigned short* Cl = path ? Cu_l : Cg_l;
    f4v S[4] = {};
#pragma unroll
    for (int kk = 0; kk < 2; ++kk) {
      s8v a = *(const s8v*)&Al[(ws * 16 + lane16) * 72 + kk * 32 + quad * 8];
#pragma unroll
      for (int nt = 0; nt < 4; ++nt) {
        s8v b = *(const s8v*)&Cl[(nt * 16 + lane16) * 72 + kk * 32 + quad * 8];
        S[nt] = MFMA16(a, b, S[nt]);
      }
    }
    unsigned short* out = path ? h2ub : h2gb;
#pragma unroll
    for (int nt = 0; nt < 4; ++nt)
#pragma unroll
      for (int r = 0; r < 4; ++r) {
        int rid2 = rids[ws * 16 + quad * 4 + r];
        if (rid2 >= 0)
          out[(size_t)rid2 * 64 + nt * 16 + lane16] = f2bf(S[nt][r]);
      }
    __syncthreads();
  }
}

// ---------------------------------------------------------------------------
// Fused expand + down-A via MFMA. Measured-best R5/R10 form (49us): LDS-staged
// B tiles, reg H-frags, per-wave inter, atomicAdd epilogue, compacted grid,
// CSPLIT=4. Ledger (R9-R14): all structural variants null or worse.
// ---------------------------------------------------------------------------
__global__ __launch_bounds__(256) void k_expand_mfma(
    const unsigned short* __restrict__ h2gb, const unsigned short* __restrict__ h2ub,
    const unsigned short* __restrict__ BgT, const unsigned short* __restrict__ BuT,
    const unsigned short* __restrict__ AdT,
    const int* __restrict__ rseg, const int* __restrict__ grp_n,
    float* __restrict__ h1d) {
  // Decode flat tile id -> (g, m0) via prefix over per-group tile counts.
  int t = blockIdx.x;
  int g = -1, m0 = 0, ng = 0;
  {
    int pre = 0;
#pragma unroll
    for (int gg = 0; gg < Gn; ++gg) {
      int n = grp_n[gg];
      int nt = (n + 127) >> 7;
      if (g < 0 && t < pre + nt) { g = gg; m0 = (t - pre) << 7; ng = n; }
      pre += nt;
    }
  }
  if (g < 0) return;
  const int c_beg = blockIdx.y * 6;
  const int c_end = min(22, c_beg + 6);

  __shared__ unsigned short Bg_l[64 * 72];
  __shared__ unsigned short Bu_l[64 * 72];
  __shared__ unsigned short Ad_l[64 * 72];
  __shared__ unsigned short inter_l[4][32 * 72];   // per-wave private
  __shared__ int rids[128];

  const int tid = threadIdx.x;
  const int w = tid >> 6, ln = tid & 63;
  const int quad = ln >> 4, lane16 = ln & 15;

  if (tid < 128) rids[tid] = (m0 + tid < ng) ? rseg[g * SEGCAP + m0 + tid] : -1;
  __syncthreads();

  // H gate/up fragments in registers: wave w owns rows w*32..w*32+31.
  s8v ag[2][2], au[2][2];
#pragma unroll
  for (int mt = 0; mt < 2; ++mt) {
    int rid = rids[w * 32 + mt * 16 + lane16];
#pragma unroll
    for (int kk = 0; kk < 2; ++kk) {
      s8v zg = {}, zu = {};
      if (rid >= 0) {
        zg = *(const s8v*)&h2gb[(size_t)rid * 64 + kk * 32 + quad * 8];
        zu = *(const s8v*)&h2ub[(size_t)rid * 64 + kk * 32 + quad * 8];
      }
      ag[mt][kk] = zg;
      au[mt][kk] = zu;
    }
  }

  const unsigned short* Bg_base = BgT + (size_t)g * In * Rn;
  const unsigned short* Bu_base = BuT + (size_t)g * In * Rn;
  const unsigned short* Ad_base = AdT + (size_t)g * Rn * In;

  unsigned short* ib = &inter_l[w][0];
  f4v P[2][4] = {};

  for (int c = c_beg; c < c_end; ++c) {
    const int i0 = c * 64;
#pragma unroll
    for (int i = 0; i < 2; ++i) {
      int cq = tid + i * 256;
      int row = cq >> 3, co = (cq & 7) * 8;
      *(uint4*)&Bg_l[row * 72 + co] = *(const uint4*)&Bg_base[(size_t)(i0 + row) * Rn + co];
      *(uint4*)&Bu_l[row * 72 + co] = *(const uint4*)&Bu_base[(size_t)(i0 + row) * Rn + co];
      *(uint4*)&Ad_l[row * 72 + co] = *(const uint4*)&Ad_base[(size_t)row * In + i0 + co];
    }
    __syncthreads();   // B tiles ready

    f4v Sg[2][4] = {}, Su[2][4] = {};
#pragma unroll
    for (int kk = 0; kk < 2; ++kk) {
      s8v bg[4], bu[4];
#pragma unroll
      for (int nt = 0; nt < 4; ++nt) {
        bg[nt] = *(const s8v*)&Bg_l[(nt * 16 + lane16) * 72 + kk * 32 + quad * 8];
        bu[nt] = *(const s8v*)&Bu_l[(nt * 16 + lane16) * 72 + kk * 32 + quad * 8];
      }
#pragma unroll
      for (int mt = 0; mt < 2; ++mt)
#pragma unroll
        for (int nt = 0; nt < 4; ++nt) {
          Sg[mt][nt] = MFMA16(ag[mt][kk], bg[nt], Sg[mt][nt]);
          Su[mt][nt] = MFMA16(au[mt][kk], bu[nt], Su[mt][nt]);
        }
    }

    // silu(gate)*up -> per-wave inter region. No barrier: wave-local W->R.
#pragma unroll
    for (int mt = 0; mt < 2; ++mt)
#pragma unroll
      for (int nt = 0; nt < 4; ++nt)
#pragma unroll
        for (int r = 0; r < 4; ++r) {
          float sg = Sg[mt][nt][r];
          float v = sg / (1.f + __expf(-sg)) * Su[mt][nt][r];
          ib[(mt * 16 + quad * 4 + r) * 72 + nt * 16 + lane16] = f2bf(v);
        }
    asm volatile("s_waitcnt lgkmcnt(0)" ::: "memory");   // wave-local W->R order

#pragma unroll
    for (int kk = 0; kk < 2; ++kk) {
      s8v ai[2], bd[4];
#pragma unroll
      for (int mt = 0; mt < 2; ++mt)
        ai[mt] = *(const s8v*)&ib[(mt * 16 + lane16) * 72 + kk * 32 + quad * 8];
#pragma unroll
      for (int nt = 0; nt < 4; ++nt)
        bd[nt] = *(const s8v*)&Ad_l[(nt * 16 + lane16) * 72 + kk * 32 + quad * 8];
#pragma unroll
      for (int mt = 0; mt < 2; ++mt)
#pragma unroll
        for (int nt = 0; nt < 4; ++nt)
          P[mt][nt] = MFMA16(ai[mt], bd[nt], P[mt][nt]);
    }
    __syncthreads();   // protect Bg/Bu/Ad before next chunk's load
  }

#pragma unroll
  for (int mt = 0; mt < 2; ++mt)
#pragma unroll
    for (int nt = 0; nt < 4; ++nt)
#pragma unroll
      for (int r = 0; r < 4; ++r) {
        int lrow = w * 32 + mt * 16 + quad * 4 + r;
        int rid = rids[lrow];
        if (rid >= 0)
          atomicAdd(&h1d[(size_t)rid * 64 + nt * 16 + lane16], P[mt][nt][r]);
      }
}

// ---------------------------------------------------------------------------
// Per-expert down core via MFMA + routing weight, reduce to y[t,g,64].
// 512 threads: 128 rows/iter.
// ---------------------------------------------------------------------------
__global__ __launch_bounds__(512) void k_core_down(
    const float* __restrict__ h1d, const unsigned short* __restrict__ CdT,
    const float* __restrict__ rw,
    const int* __restrict__ rseg, const int* __restrict__ off_e,
    const int* __restrict__ cnt_e,
    float* __restrict__ y) {
  const int e = blockIdx.x;
  const int ne = cnt_e[e];
  if (ne == 0) return;
  const int g = e >> 5;
  const int base = off_e[e];
  __shared__ unsigned short Bd_l[64 * 72];
  __shared__ unsigned short Ad_l[128 * 72];
  __shared__ int rids[128];
  const int tid = threadIdx.x;
  const int w = tid >> 6, ln = tid & 63;
  const int quad = ln >> 4, lane16 = ln & 15;
  {
    int j = tid >> 3, q = (tid & 7) * 8;
    const unsigned short* cd = CdT + (size_t)e * (Rn * Rn);
    *(uint4*)&Bd_l[j * 72 + q] = *(const uint4*)&cd[j * 64 + q];
  }
  const int gj = tid >> 2, gq = (tid & 3) * 16;   // 128 rows x 4 chunks of 16
  const int ntile = (ne + 127) >> 7;
  for (int it = 0; it < ntile; ++it) {
    int mi = it * 128 + gj;
    int rid = (mi < ne) ? rseg[base + mi] : -1;
    if ((tid & 3) == 0) rids[gj] = rid;
#pragma unroll
    for (int i = 0; i < 4; ++i) {
      int kb = gq + i * 4;
      float4 vd = {0.f, 0.f, 0.f, 0.f};
      if (rid >= 0) vd = *(const float4*)&h1d[(size_t)rid * 64 + kb];
      ushort4 od;
      od.x = f2bf(vd.x); od.y = f2bf(vd.y); od.z = f2bf(vd.z); od.w = f2bf(vd.w);
      *(ushort4*)&Ad_l[gj * 72 + kb] = od;
    }
    __syncthreads();
    f4v Sd[4] = {};
#pragma unroll
    for (int kk = 0; kk < 2; ++kk) {
      s8v ad = *(const s8v*)&Ad_l[(w * 16 + lane16) * 72 + kk * 32 + quad * 8];
#pragma unroll
      for (int nt = 0; nt < 4; ++nt) {
        s8v bd = *(const s8v*)&Bd_l[(nt * 16 + lane16) * 72 + kk * 32 + quad * 8];
        Sd[nt] = MFMA16(ad, bd, Sd[nt]);
      }
    }
#pragma unroll
    for (int nt = 0; nt < 4; ++nt)
#pragma unroll
      for (int r = 0; r < 4; ++r) {
        int rid2 = rids[w * 16 + quad * 4 + r];
        if (rid2 >= 0) {
          float wgt = rw[rid2];
          atomicAdd(&y[(size_t)(rid2 >> 3) * (Gn * Rn) + g * 64 + nt * 16 + lane16],
                    wgt * Sd[nt][r]);
        }
      }
    __syncthreads();
  }
}

// ---------------------------------------------------------------------------
// Combine: out[2048,2048] = y[2048,512] @ B_down-as-[512,2048], MFMA bf16.
// ---------------------------------------------------------------------------
__global__ __launch_bounds__(256) void k_combine(
    const float* __restrict__ y, const unsigned short* __restrict__ BdT,
    float* __restrict__ outp) {
  const int t0 = blockIdx.y * 128, n0 = blockIdx.x * 128;
  __shared__ unsigned short As[128 * 72];
  __shared__ unsigned short Bs[128 * 72];
  const int tid = threadIdx.x;
  const int w = tid >> 6, ln = tid & 63;
  const int quad = ln >> 4, lane16 = ln & 15;
  const int mbase = (w >> 1) * 64, nbase = (w & 1) * 64;

  f4v acc[4][4] = {};

  for (int k0 = 0; k0 < Gn * Rn; k0 += 64) {
#pragma unroll
    for (int i = 0; i < 8; ++i) {
      int c = tid + i * 256;
      int row = c >> 4, cc = (c & 15) * 4;
      float4 v = *(const float4*)&y[(size_t)(t0 + row) * (Gn * Rn) + k0 + cc];
      ushort4 o;
      o.x = f2bf(v.x); o.y = f2bf(v.y); o.z = f2bf(v.z); o.w = f2bf(v.w);
      *(ushort4*)&As[row * 72 + cc] = o;
    }
#pragma unroll
    for (int i = 0; i < 4; ++i) {
      int c = tid + i * 256;
      int row = c >> 3, cc = (c & 7) * 8;
      *(uint4*)&Bs[row * 72 + cc] = *(const uint4*)&BdT[(size_t)(n0 + row) * (Gn * Rn) + k0 + cc];
    }
    __syncthreads();
#pragma unroll
    for (int kk = 0; kk < 2; ++kk) {
      s8v a[4], b[4];
#pragma unroll
      for (int mt = 0; mt < 4; ++mt)
        a[mt] = *(const s8v*)&As[(mbase + mt * 16 + lane16) * 72 + kk * 32 + quad * 8];
#pragma unroll
      for (int nt = 0; nt < 4; ++nt)
        b[nt] = *(const s8v*)&Bs[(nbase + nt * 16 + lane16) * 72 + kk * 32 + quad * 8];
#pragma unroll
      for (int mt = 0; mt < 4; ++mt)
#pragma unroll
        for (int nt = 0; nt < 4; ++nt)
          acc[mt][nt] = MFMA16(a[mt], b[nt], acc[mt][nt]);
    }
    __syncthreads();
  }
#pragma unroll
  for (int mt = 0; mt < 4; ++mt)
#pragma unroll
    for (int nt = 0; nt < 4; ++nt)
#pragma unroll
      for (int r = 0; r < 4; ++r)
        outp[(size_t)(t0 + mbase + mt * 16 + quad * 4 + r) * Dn +
             n0 + nbase + nt * 16 + lane16] = acc[mt][nt][r];
}

// ---------------------------------------------------------------------------
extern "C" void kernel_launch(void* const* d_in, const int* in_sizes, int n_in,
                              void* d_out, int out_size, void* d_ws, size_t ws_size,
                              hipStream_t stream) {
  const float* hidden = (const float*)d_in[0];
  const float* w_gate = (const float*)d_in[1];
  const float* A_gate = (const float*)d_in[2];
  const float* C_gate = (const float*)d_in[3];
  const float* B_gate = (const float*)d_in[4];
  const float* A_up   = (const float*)d_in[5];
  const float* C_up   = (const float*)d_in[6];
  const float* B_up   = (const float*)d_in[7];
  const float* A_down = (const float*)d_in[8];
  const float* C_down = (const float*)d_in[9];
  const float* B_down = (const float*)d_in[10];
  float* out = (float*)d_out;

  // Workspace layout (peak unchanged, 34.34 MB). Router-stage {part 12.6MB
  // (KS_R=6), hq 16.8MB, wqT 2.1MB} = 31.5MB overlay [0, 31.5MB), all dead
  // after k_topk and below the persistent smalls at 33.69MB. Hbf aliases
  // h1d+y (written after router stage, dead before h1d/y memsets).
  char* base = (char*)d_ws;
  size_t o = 0;
  unsigned short* h2gb = (unsigned short*)(base + o); o += (size_t)NROWS * Rn * 2;
  unsigned short* h2ub = (unsigned short*)(base + o); o += (size_t)NROWS * Rn * 2;
  unsigned short* AgT  = (unsigned short*)(base + o); o += (size_t)Gn * Rn * Dn * 2;
  unsigned short* AuT  = (unsigned short*)(base + o); o += (size_t)Gn * Rn * Dn * 2;
  unsigned short* BgT  = (unsigned short*)(base + o); o += (size_t)Gn * In * Rn * 2;
  unsigned short* BuT  = (unsigned short*)(base + o); o += (size_t)Gn * In * Rn * 2;
  unsigned short* AdT  = (unsigned short*)(base + o); o += (size_t)Gn * Rn * In * 2;
  unsigned short* BdT  = (unsigned short*)(base + o); o += (size_t)Dn * Gn * Rn * 2;
  unsigned short* CgT  = (unsigned short*)(base + o); o += (size_t)En * Rn * Rn * 2;
  unsigned short* CuT  = (unsigned short*)(base + o); o += (size_t)En * Rn * Rn * 2;
  unsigned short* CdT  = (unsigned short*)(base + o); o += (size_t)En * Rn * Rn * 2;
  unsigned short* h1gb = (unsigned short*)(base + o); o += (size_t)T0n * Gn * Rn * 2;
  unsigned short* h1ub = (unsigned short*)(base + o); o += (size_t)T0n * Gn * Rn * 2;
  float* h1d = (float*)(base + o); o += (size_t)NROWS * Rn * 4;
  float* y   = (float*)(base + o); o += (size_t)T0n * Gn * Rn * 4;
  // ---- persistent smalls ----
  float* rwp = (float*)(base + o); o += (size_t)NROWS * 4;
  int* sel   = (int*)(base + o); o += (size_t)NROWS * 4;
  int* rseg  = (int*)(base + o); o += (size_t)Gn * SEGCAP * 4;
  int* cnt_e = (int*)(base + o); o += En * 4;
  int* off_e = (int*)(base + o); o += En * 4;
  int* cur_e = (int*)(base + o); o += En * 4;
  int* grp_n = (int*)(base + o); o += Gn * 4;
  // ---- router-stage aliases (dead after k_topk), inside [0, 31.5MB) ----
  float* part = (float*)base;                              // 6*2048*256*4 = 12,582,912
  char* hq  = base + (size_t)KS_R * T0n * En * 4;          // +16,777,216 (4 i8 planes)
  char* wqT = hq + (size_t)4 * T0n * Dn;                   // +2,097,152  (4 i8 planes, T)
  // ---- Hbf alias: h1d (4.19MB) + y (4.19MB) = exactly T0n*Dn*2 bytes ----
  unsigned short* Hbf = (unsigned short*)h1d;

  hipMemsetAsync(cnt_e, 0, En * sizeof(int), stream);

  // 1) quantize inputs to exact 4x-i8 fixed-point limbs
  k_quant_h<<<T0n * Dn / 1024, 256, 0, stream>>>(hidden, hq);
  k_quant_wT<<<dim3(Dn / 32, En / 32), 256, 0, stream>>>(w_gate, wqT);
  // 2) router logits via i32-MFMA limb GEMM (s>=3 pairs, split-K=6)
  k_router_i8<<<dim3(En / 64, T0n / 64, KS_R), 256, 0, stream>>>(hq, wqT, part);
  // 3) top-8 + renorm + expert counts
  k_topk<<<T0n / 4, 256, 0, stream>>>(part, sel, rwp, cnt_e);
  // 4) offsets (parallel prefix) + scatter rows by expert
  k_scan<<<1, 256, 0, stream>>>(cnt_e, off_e, cur_e, grp_n);
  k_scatter<<<NROWS / 256, 256, 0, stream>>>(sel, cur_e, rseg);

  // part/hq/wqT now dead. Convert H to bf16 once (into the h1d+y alias).
  k_hcvt<<<T0n * Dn / 2048, 256, 0, stream>>>(hidden, Hbf);

  // 5) transpose+convert all 9 weight tensors to bf16 operand layouts
  {
    TD9 D;
    D.t[0] = {A_gate, AgT, Dn, Rn, Rn / 32, (Rn / 32) * (Dn / 32), 0};
    D.t[1] = {A_up,   AuT, Dn, Rn, Rn / 32, (Rn / 32) * (Dn / 32), 1024};
    D.t[2] = {B_gate, BgT, Rn, In, In / 32, (In / 32) * (Rn / 32), 2048};
    D.t[3] = {B_up,   BuT, Rn, In, In / 32, (In / 32) * (Rn / 32), 2752};
    D.t[4] = {A_down, AdT, In, Rn, Rn / 32, (Rn / 32) * (In / 32), 3456};
    D.t[5] = {B_down, BdT, Gn * Rn, Dn, Dn / 32, (Dn / 32) * (Gn * Rn / 32), 4160};
    D.t[6] = {C_gate, CgT, Rn, Rn, 2, 4, 5184};
    D.t[7] = {C_up,   CuT, Rn, Rn, 2, 4, 6208};
    D.t[8] = {C_down, CdT, Rn, Rn, 2, 4, 7232};
    k_tcvt9<<<8256, 256, 0, stream>>>(D);
  }

  // 6) dense in-factor projections (bf16 H from Hbf)
  k_h1_mfma<<<dim3(T0n / 64, Gn), 512, 0, stream>>>(Hbf, AgT, AuT, h1gb, h1ub);

  // Hbf dead; reclaim h1d + y.
  hipMemsetAsync(h1d, 0, (size_t)NROWS * Rn * sizeof(float), stream);
  hipMemsetAsync(y,   0, (size_t)T0n * Gn * Rn * sizeof(float), stream);

  // 7) per-expert core (gate/up) via MFMA (512 thr path-split)
  k_core_gu<<<En, 512, 0, stream>>>(h1gb, h1ub, CgT, CuT,
                                    rseg, off_e, cnt_e, h2gb, h2ub);
  // 8) fused expand + down-A (measured-best form)
  k_expand_mfma<<<dim3(NTILE_MAX, 4), 256, 0, stream>>>(
      h2gb, h2ub, BgT, BuT, AdT, rseg, grp_n, h1d);
  // 9) per-expert down core via MFMA + rw (512 thr, 128 rows/iter)
  k_core_down<<<En, 512, 0, stream>>>(h1d, CdT, rwp,
                                      rseg, off_e, cnt_e, y);
  // 10) combine (MFMA bf16)
  k_combine<<<dim3(Dn / 128, T0n / 128), 256, 0, stream>>>(y, BdT, out);
}

// Round 13
// 301.549 us; speedup vs baseline: 1.0975x; 1.0137x over previous
//
#include <hip/hip_runtime.h>
#include <math.h>

// Problem dims
constexpr int T0n = 2048;   // tokens
constexpr int Dn  = 2048;   // hidden
constexpr int En  = 256;    // experts
constexpr int Gn  = 8;      // groups
constexpr int EGn = 32;     // experts per group
constexpr int Rn  = 64;     // tucker rank
constexpr int In  = 1408;   // intermediate

constexpr int NROWS = T0n * 8;    // 16384 dispatched rows
constexpr int SEGCAP = NROWS;     // per-group segment capacity in rseg
constexpr int KS_R = 6;           // router split-K (i32 exact, uneven split OK)
constexpr int NTILE2_MAX = NROWS / 256 + Gn;   // 72: bound on sum ceil(ng/256)

typedef __attribute__((ext_vector_type(8))) short s8v;    // 8 bf16
typedef __attribute__((ext_vector_type(4))) float f4v;    // 4 fp32
typedef __attribute__((ext_vector_type(4))) int i4v;      // 16 i8 operand / 4 i32 acc
#define MFMA16(a, b, c) __builtin_amdgcn_mfma_f32_16x16x32_bf16(a, b, c, 0, 0, 0)
#define MFMAI8(a, b, c) __builtin_amdgcn_mfma_i32_16x16x64_i8(a, b, c, 0, 0, 0)

__device__ __forceinline__ unsigned short f2bf(float x) {
  unsigned int u = __float_as_uint(x);
  unsigned int r = (u + 0x7FFFu + ((u >> 16) & 1u)) >> 16;
  return (unsigned short)r;
}

// ---------------------------------------------------------------------------
// Fused batched transpose+convert for 9 weight tensors:
// src f32 [batch][rows][cols] -> dst bf16 [batch][cols][rows].
// ---------------------------------------------------------------------------
struct TD { const float* src; unsigned short* dst; int rows, cols, nbx, per_batch, base; };
struct TD9 { TD t[9]; };

__global__ __launch_bounds__(256) void k_tcvt9(TD9 D) {
  __shared__ float tbuf[32][33];
  int id = blockIdx.x;
  int ti = 0;
#pragma unroll
  for (int i = 1; i < 9; ++i) ti = (id >= D.t[i].base) ? i : ti;
  TD d = D.t[ti];
  int local = id - d.base;
  int bz = local / d.per_batch;
  int rem = local - bz * d.per_batch;
  int by = rem / d.nbx;
  int bx = rem - by * d.nbx;

  size_t boff = (size_t)bz * d.rows * d.cols;
  const float* src = d.src + boff;
  unsigned short* dst = d.dst + boff;
  int c0 = bx * 32, r0 = by * 32;
  int tx = threadIdx.x & 31, ty = threadIdx.x >> 5;   // ty 0..7
  for (int i = ty; i < 32; i += 8)
    tbuf[i][tx] = src[(size_t)(r0 + i) * d.cols + c0 + tx];
  __syncthreads();
  for (int i = ty; i < 32; i += 8)
    dst[(size_t)(c0 + i) * d.rows + r0 + tx] = f2bf(tbuf[tx][i]);
}

// ---------------------------------------------------------------------------
// H f32 -> bf16 once. Halves H traffic in k_h1_mfma.
// ---------------------------------------------------------------------------
__global__ __launch_bounds__(256) void k_hcvt(
    const float* __restrict__ H, unsigned short* __restrict__ Hbf) {
  size_t i = ((size_t)blockIdx.x * 256 + threadIdx.x) * 8;
  float4 v0 = *(const float4*)&H[i];
  float4 v1 = *(const float4*)&H[i + 4];
  ushort4 o0, o1;
  o0.x = f2bf(v0.x); o0.y = f2bf(v0.y); o0.z = f2bf(v0.z); o0.w = f2bf(v0.w);
  o1.x = f2bf(v1.x); o1.y = f2bf(v1.y); o1.z = f2bf(v1.z); o1.w = f2bf(v1.w);
  *(ushort4*)&Hbf[i] = o0;
  *(ushort4*)&Hbf[i + 4] = o1;
}

// ---------------------------------------------------------------------------
// ROUTER, fixed-point limb path. Pairs k+l>=3 (10 MFMA). NOTE (R17): s=3 is
// NOT droppable — with actual limb distributions (top limbs rms ~10-16, low
// limbs ~74) s=3 contributes ~2.6e-6 rms, comparable to the token-min top-8
// gap (~1.5e-5). s=2 drop (R16) is ~1e-8, verified byte-identical absmax.
// ---------------------------------------------------------------------------
__device__ __forceinline__ int4 limbs4(float v, double sc) {
  double d = (double)v * sc;           // exact in double
  d = fmin(fmax(d, -2.0e9), 2.0e9);    // clamp (unreachable for this data)
  int x = __double2int_rn(d);
  int l0 = (int)(signed char)(x & 0xff); x = (x - l0) >> 8;   // exact
  int l1 = (int)(signed char)(x & 0xff); x = (x - l1) >> 8;
  int l2 = (int)(signed char)(x & 0xff); x = (x - l2) >> 8;
  return make_int4(l0, l1, l2, x);     // x fits i8
}

// hidden [2048][2048] f32 -> hq planes [4][2048][2048] i8 (limb-major).
__global__ __launch_bounds__(256) void k_quant_h(
    const float* __restrict__ H, char* __restrict__ hq) {
  const size_t PL = (size_t)T0n * Dn;
  size_t i = (size_t)blockIdx.x * 256 + threadIdx.x;   // group of 4 elements
  float4 v = *(const float4*)&H[i * 4];
  int4 a = limbs4(v.x, 268435456.0);   // 2^28
  int4 b = limbs4(v.y, 268435456.0);
  int4 c = limbs4(v.z, 268435456.0);
  int4 d = limbs4(v.w, 268435456.0);
  unsigned int p0 = (a.x & 0xff) | ((b.x & 0xff) << 8) | ((c.x & 0xff) << 16) | ((unsigned)(d.x & 0xff) << 24);
  unsigned int p1 = (a.y & 0xff) | ((b.y & 0xff) << 8) | ((c.y & 0xff) << 16) | ((unsigned)(d.y & 0xff) << 24);
  unsigned int p2 = (a.z & 0xff) | ((b.z & 0xff) << 8) | ((c.z & 0xff) << 16) | ((unsigned)(d.z & 0xff) << 24);
  unsigned int p3 = (a.w & 0xff) | ((b.w & 0xff) << 8) | ((c.w & 0xff) << 16) | ((unsigned)(d.w & 0xff) << 24);
  *(unsigned int*)&hq[0 * PL + i * 4] = p0;
  *(unsigned int*)&hq[1 * PL + i * 4] = p1;
  *(unsigned int*)&hq[2 * PL + i * 4] = p2;
  *(unsigned int*)&hq[3 * PL + i * 4] = p3;
}

// w_gate [2048][256] f32 -> wqT planes [4][256][2048] i8 (transposed, limb-major).
__global__ __launch_bounds__(256) void k_quant_wT(
    const float* __restrict__ W, char* __restrict__ wqT) {
  __shared__ float tb[32][33];
  const size_t PL = (size_t)En * Dn;
  int kb = blockIdx.x * 32, nb = blockIdx.y * 32;
  int tx = threadIdx.x & 31, ty = threadIdx.x >> 5;
  for (int i = ty; i < 32; i += 8)
    tb[i][tx] = W[(size_t)(kb + i) * En + nb + tx];
  __syncthreads();
  for (int i = ty; i < 32; i += 8) {
    int4 l = limbs4(tb[tx][i], 8589934592.0);   // 2^33
    size_t off = (size_t)(nb + i) * Dn + kb + tx;
    wqT[0 * PL + off] = (char)l.x;
    wqT[1 * PL + off] = (char)l.y;
    wqT[2 * PL + off] = (char)l.z;
    wqT[3 * PL + off] = (char)l.w;
  }
}

// i8 MFMA router GEMM. 10 MFMA/step (s>=3), KS_R=6 (uneven split).
// grid (En/64, T0n/64, KS_R).
__global__ __launch_bounds__(256) void k_router_i8(
    const char* __restrict__ hq, const char* __restrict__ wqT,
    float* __restrict__ part) {
  __shared__ __align__(16) char Asl[4][64][80];   // [limb][m-row][k]
  __shared__ __align__(16) char Bsl[4][64][80];   // [limb][n-row][k]
  const int n0 = blockIdx.x * 64, m0 = blockIdx.y * 64;
  const int kc = blockIdx.z;
  const int tid = threadIdx.x;
  const int w = tid >> 6, ln = tid & 63;
  const int quad = ln >> 4, lane16 = ln & 15;

  const char* ha = hq + ((size_t)w * T0n + m0 + ln) * Dn;   // plane w, row m0+ln
  const char* ba = wqT + ((size_t)w * En + n0 + ln) * Dn;   // plane w, row n0+ln

  i4v acc[4][4] = {};   // [m-tile][s-group s=k+l-3, s in 3..6]

  // Uneven K-split over 32 steps of 64: kc gets steps [kc*32/6,(kc+1)*32/6).
  const int kbeg = ((kc * 32) / KS_R) * 64;
  const int kend = (((kc + 1) * 32) / KS_R) * 64;
  for (int k0 = kbeg; k0 < kend; k0 += 64) {
#pragma unroll
    for (int q = 0; q < 4; ++q) {
      *(uint4*)&Asl[w][ln][q * 16] = *(const uint4*)&ha[k0 + q * 16];
      *(uint4*)&Bsl[w][ln][q * 16] = *(const uint4*)&ba[k0 + q * 16];
    }
    __syncthreads();
    i4v b0 = *(const i4v*)&Bsl[0][w * 16 + lane16][quad * 16];
    i4v b1 = *(const i4v*)&Bsl[1][w * 16 + lane16][quad * 16];
    i4v b2 = *(const i4v*)&Bsl[2][w * 16 + lane16][quad * 16];
    i4v b3 = *(const i4v*)&Bsl[3][w * 16 + lane16][quad * 16];
#pragma unroll
    for (int mt = 0; mt < 4; ++mt) {
      i4v a0 = *(const i4v*)&Asl[0][mt * 16 + lane16][quad * 16];
      i4v a1 = *(const i4v*)&Asl[1][mt * 16 + lane16][quad * 16];
      i4v a2 = *(const i4v*)&Asl[2][mt * 16 + lane16][quad * 16];
      i4v a3 = *(const i4v*)&Asl[3][mt * 16 + lane16][quad * 16];
      // s = 3
      acc[mt][0] = MFMAI8(a0, b3, acc[mt][0]);
      acc[mt][0] = MFMAI8(a1, b2, acc[mt][0]);
      acc[mt][0] = MFMAI8(a2, b1, acc[mt][0]);
      acc[mt][0] = MFMAI8(a3, b0, acc[mt][0]);
      // s = 4
      acc[mt][1] = MFMAI8(a1, b3, acc[mt][1]);
      acc[mt][1] = MFMAI8(a2, b2, acc[mt][1]);
      acc[mt][1] = MFMAI8(a3, b1, acc[mt][1]);
      // s = 5
      acc[mt][2] = MFMAI8(a2, b3, acc[mt][2]);
      acc[mt][2] = MFMAI8(a3, b2, acc[mt][2]);
      // s = 6
      acc[mt][3] = MFMAI8(a3, b3, acc[mt][3]);
    }
    __syncthreads();
  }

  // Combine 4 exact i32 sums at scales 2^(8s-61), s=3..6.
  float* prow = part + (size_t)kc * T0n * En;
#pragma unroll
  for (int mt = 0; mt < 4; ++mt)
#pragma unroll
    for (int r = 0; r < 4; ++r) {
      int row = m0 + mt * 16 + quad * 4 + r;
      int col = n0 + w * 16 + lane16;
      double v = (double)acc[mt][0][r] * 0x1p-37 +
                 (double)acc[mt][1][r] * 0x1p-29 +
                 (double)acc[mt][2][r] * 0x1p-21 +
                 (double)acc[mt][3][r] * 0x1p-13;
      prow[(size_t)row * En + col] = (float)v;
    }
}

// ---------------------------------------------------------------------------
// Top-8: one wave per token, shuffle butterfly. Sums KS_R fp32 partials in fp64.
// ---------------------------------------------------------------------------
__global__ __launch_bounds__(256) void k_topk(
    const float* __restrict__ part, int* __restrict__ sel,
    float* __restrict__ rw, int* __restrict__ cnt_e) {
  const int wid = threadIdx.x >> 6, ln = threadIdx.x & 63;
  const int t = blockIdx.x * 4 + wid;

  double v[4];
#pragma unroll
  for (int j = 0; j < 4; ++j) {
    double s = 0.0;
#pragma unroll
    for (int kc = 0; kc < KS_R; ++kc)
      s += (double)part[((size_t)kc * T0n + t) * En + ln + 64 * j];
    v[j] = s;
  }

  float topv[8];
  int topi[8];
#pragma unroll
  for (int k = 0; k < 8; ++k) {
    double bv = v[0]; int bi = ln;
#pragma unroll
    for (int j = 1; j < 4; ++j) {
      int cand = ln + 64 * j;
      if (v[j] > bv || (v[j] == bv && cand < bi)) { bv = v[j]; bi = cand; }
    }
#pragma unroll
    for (int off = 32; off > 0; off >>= 1) {
      double ov = __shfl_xor(bv, off);
      int oi = __shfl_xor(bi, off);
      if (ov > bv || (ov == bv && oi < bi)) { bv = ov; bi = oi; }
    }
    topv[k] = (float)bv; topi[k] = bi;
    if ((bi & 63) == ln) v[bi >> 6] = -1e300;
  }

  if (ln < 8) {
    float m = topv[0];
    float ssum = 0.f;
#pragma unroll
    for (int k = 0; k < 8; ++k) ssum += expf(topv[k] - m);
    rw[t * 8 + ln] = expf(topv[ln] - m) / ssum;
    sel[t * 8 + ln] = topi[ln];
    atomicAdd(&cnt_e[topi[ln]], 1);
  }
}

// Parallel per-group prefix over 256 experts.
__global__ __launch_bounds__(256) void k_scan(
    const int* __restrict__ cnt_e, int* __restrict__ off_e,
    int* __restrict__ cur_e, int* __restrict__ grp_n) {
  __shared__ int c[256];
  int tid = threadIdx.x;
  c[tid] = cnt_e[tid];
  __syncthreads();
  int g = tid >> 5, ei = tid & 31;
  int run = 0;
  for (int i = 0; i < ei; ++i) run += c[(g << 5) + i];
  off_e[tid] = g * SEGCAP + run;
  cur_e[tid] = g * SEGCAP + run;
  if (ei == 31) grp_n[g] = run + c[tid];
}

__global__ void k_scatter(const int* __restrict__ sel, int* __restrict__ cur_e,
                          int* __restrict__ rseg) {
  int i = blockIdx.x * 256 + threadIdx.x;
  int e = sel[i];
  int pos = atomicAdd(&cur_e[e], 1);
  rseg[pos] = i;
}

// ---------------------------------------------------------------------------
// h1 = H @ A_fac[g]. bf16 H (k_hcvt); single uint4 staging load per thread.
// 512 threads: waves 0-3 gate, 4-7 up. grid (T0/64, G).
// ---------------------------------------------------------------------------
__global__ __launch_bounds__(512) void k_h1_mfma(
    const unsigned short* __restrict__ Hbf,
    const unsigned short* __restrict__ AgT, const unsigned short* __restrict__ AuT,
    unsigned short* __restrict__ h1gb, unsigned short* __restrict__ h1ub) {
  const int t0 = blockIdx.x * 64;
  const int g = blockIdx.y;
  const unsigned short* Wg = AgT + (size_t)g * Rn * Dn;
  const unsigned short* Wu = AuT + (size_t)g * Rn * Dn;

  __shared__ unsigned short As[64 * 72];
  __shared__ unsigned short Bg_l[64 * 72];
  __shared__ unsigned short Bu_l[64 * 72];
  const int tid = threadIdx.x;
  const int w = tid >> 6, ln = tid & 63;
  const int path = w >> 2, ws = w & 3;
  const int quad = ln >> 4, lane16 = ln & 15;
  const int j = tid >> 3, q = (tid & 7) * 8;   // 64 rows x 8 chunks

  f4v S[4] = {};

  for (int k0 = 0; k0 < Dn; k0 += 64) {
    {
      *(uint4*)&As[j * 72 + q] = *(const uint4*)&Hbf[(size_t)(t0 + j) * Dn + k0 + q];
      *(uint4*)&Bg_l[j * 72 + q] = *(const uint4*)&Wg[(size_t)j * Dn + k0 + q];
      *(uint4*)&Bu_l[j * 72 + q] = *(const uint4*)&Wu[(size_t)j * Dn + k0 + q];
    }
    __syncthreads();
    const unsigned short* Bl = path ? Bu_l : Bg_l;
#pragma unroll
    for (int kk = 0; kk < 2; ++kk) {
      s8v a = *(const s8v*)&As[(ws * 16 + lane16) * 72 + kk * 32 + quad * 8];
#pragma unroll
      for (int nt = 0; nt < 4; ++nt) {
        s8v b = *(const s8v*)&Bl[(nt * 16 + lane16) * 72 + kk * 32 + quad * 8];
        S[nt] = MFMA16(a, b, S[nt]);
      }
    }
    __syncthreads();
  }
  unsigned short* out = path ? h1ub : h1gb;
#pragma unroll
  for (int nt = 0; nt < 4; ++nt)
#pragma unroll
    for (int r = 0; r < 4; ++r) {
      int row = t0 + ws * 16 + quad * 4 + r;
      int col = g * 64 + nt * 16 + lane16;
      out[(size_t)row * (Gn * Rn) + col] = f2bf(S[nt][r]);
    }
}

// ---------------------------------------------------------------------------
// Per-expert core (gate/up) via MFMA. 512 threads: waves 0-3 gate, 4-7 up.
// ---------------------------------------------------------------------------
__global__ __launch_bounds__(512) void k_core_gu(
    const unsigned short* __restrict__ h1gb, const unsigned short* __restrict__ h1ub,
    const unsigned short* __restrict__ CgT, const unsigned short* __restrict__ CuT,
    const int* __restrict__ rseg, const int* __restrict__ off_e,
    const int* __restrict__ cnt_e,
    unsigned short* __restrict__ h2gb, unsigned short* __restrict__ h2ub) {
  const int e = blockIdx.x;
  const int ne = cnt_e[e];
  if (ne == 0) return;
  const int g = e >> 5;
  const int base = off_e[e];
  __shared__ unsigned short Cg_l[64 * 72];
  __shared__ unsigned short Cu_l[64 * 72];
  __shared__ unsigned short Ags[64 * 72];
  __shared__ unsigned short Aus[64 * 72];
  __shared__ int rids[64];
  const int tid = threadIdx.x;
  const int w = tid >> 6, ln = tid & 63;
  const int path = w >> 2, ws = w & 3;
  const int quad = ln >> 4, lane16 = ln & 15;
  const int j = tid >> 3, q = (tid & 7) * 8;
  {
    const unsigned short* cg = CgT + (size_t)e * (Rn * Rn);
    const unsigned short* cu = CuT + (size_t)e * (Rn * Rn);
    *(uint4*)&Cg_l[j * 72 + q] = *(const uint4*)&cg[j * 64 + q];
    *(uint4*)&Cu_l[j * 72 + q] = *(const uint4*)&cu[j * 64 + q];
  }
  const int ntile = (ne + 63) >> 6;
  for (int it = 0; it < ntile; ++it) {
    int mi = it * 64 + j;
    int rid = (mi < ne) ? rseg[base + mi] : -1;
    if ((tid & 7) == 0) rids[j] = rid;
    uint4 zg = {0, 0, 0, 0}, zu = {0, 0, 0, 0};
    if (rid >= 0) {
      zg = *(const uint4*)&h1gb[(size_t)(rid >> 3) * (Gn * Rn) + g * 64 + q];
      zu = *(const uint4*)&h1ub[(size_t)(rid >> 3) * (Gn * Rn) + g * 64 + q];
    }
    *(uint4*)&Ags[j * 72 + q] = zg;
    *(uint4*)&Aus[j * 72 + q] = zu;
    __syncthreads();
    const unsigned short* Al = path ? Aus : Ags;
    const unsigned short* Cl = path ? Cu_l : Cg_l;
    f4v S[4] = {};
#pragma unroll
    for (int kk = 0; kk < 2; ++kk) {
      s8v a = *(const s8v*)&Al[(ws * 16 + lane16) * 72 + kk * 32 + quad * 8];
#pragma unroll
      for (int nt = 0; nt < 4; ++nt) {
        s8v b = *(const s8v*)&Cl[(nt * 16 + lane16) * 72 + kk * 32 + quad * 8];
        S[nt] = MFMA16(a, b, S[nt]);
      }
    }
    unsigned short* out = path ? h2ub : h2gb;
#pragma unroll
    for (int nt = 0; nt < 4; ++nt)
#pragma unroll
      for (int r = 0; r < 4; ++r) {
        int rid2 = rids[ws * 16 + quad * 4 + r];
        if (rid2 >= 0)
          out[(size_t)rid2 * 64 + nt * 16 + lane16] = f2bf(S[nt][r]);
      }
    __syncthreads();
  }
}

// ---------------------------------------------------------------------------
// Fused expand + down-A via MFMA. R17: 8 WAVES / 256-ROW TILES — same
// per-wave work and inner loop as the measured-best R5 form, but 512 thr:
// waves/CU 12 -> 16 (LDS = 27.6KB shared B + 8x4.6KB inter + 1KB rids =
// 65536 B -> 2 blocks/CU; VGPR 112 -> 4 waves/SIMD), block staging amortized
// over 8 waves instead of 4. grid (NTILE2_MAX=72, CSPLIT=4), ~264 live
// blocks, all co-resident.
// ---------------------------------------------------------------------------
__global__ __launch_bounds__(512) void k_expand_mfma(
    const unsigned short* __restrict__ h2gb, const unsigned short* __restrict__ h2ub,
    const unsigned short* __restrict__ BgT, const unsigned short* __restrict__ BuT,
    const unsigned short* __restrict__ AdT,
    const int* __restrict__ rseg, const int* __restrict__ grp_n,
    float* __restrict__ h1d) {
  // Decode flat 256-row tile id -> (g, m0) via prefix over per-group counts.
  int t = blockIdx.x;
  int g = -1, m0 = 0, ng = 0;
  {
    int pre = 0;
#pragma unroll
    for (int gg = 0; gg < Gn; ++gg) {
      int n = grp_n[gg];
      int nt = (n + 255) >> 8;
      if (g < 0 && t < pre + nt) { g = gg; m0 = (t - pre) << 8; ng = n; }
      pre += nt;
    }
  }
  if (g < 0) return;
  const int c_beg = blockIdx.y * 6;
  const int c_end = min(22, c_beg + 6);

  __shared__ unsigned short Bg_l[64 * 72];
  __shared__ unsigned short Bu_l[64 * 72];
  __shared__ unsigned short Ad_l[64 * 72];
  __shared__ unsigned short inter_l[8][32 * 72];   // per-wave private
  __shared__ int rids[256];

  const int tid = threadIdx.x;
  const int w = tid >> 6, ln = tid & 63;   // w in 0..7
  const int quad = ln >> 4, lane16 = ln & 15;

  if (tid < 256) rids[tid] = (m0 + tid < ng) ? rseg[g * SEGCAP + m0 + tid] : -1;
  __syncthreads();

  // H gate/up fragments in registers: wave w owns rows w*32..w*32+31.
  s8v ag[2][2], au[2][2];
#pragma unroll
  for (int mt = 0; mt < 2; ++mt) {
    int rid = rids[w * 32 + mt * 16 + lane16];
#pragma unroll
    for (int kk = 0; kk < 2; ++kk) {
      s8v zg = {}, zu = {};
      if (rid >= 0) {
        zg = *(const s8v*)&h2gb[(size_t)rid * 64 + kk * 32 + quad * 8];
        zu = *(const s8v*)&h2ub[(size_t)rid * 64 + kk * 32 + quad * 8];
      }
      ag[mt][kk] = zg;
      au[mt][kk] = zu;
    }
  }

  const unsigned short* Bg_base = BgT + (size_t)g * In * Rn;
  const unsigned short* Bu_base = BuT + (size_t)g * In * Rn;
  const unsigned short* Ad_base = AdT + (size_t)g * Rn * In;

  unsigned short* ib = &inter_l[w][0];
  f4v P[2][4] = {};
  const int srow = tid >> 3, sco = (tid & 7) * 8;   // 512 thr: 64 rows x 8 cols

  for (int c = c_beg; c < c_end; ++c) {
    const int i0 = c * 64;
    *(uint4*)&Bg_l[srow * 72 + sco] = *(const uint4*)&Bg_base[(size_t)(i0 + srow) * Rn + sco];
    *(uint4*)&Bu_l[srow * 72 + sco] = *(const uint4*)&Bu_base[(size_t)(i0 + srow) * Rn + sco];
    *(uint4*)&Ad_l[srow * 72 + sco] = *(const uint4*)&Ad_base[(size_t)srow * In + i0 + sco];
    __syncthreads();   // B tiles ready

    f4v Sg[2][4] = {}, Su[2][4] = {};
#pragma unroll
    for (int kk = 0; kk < 2; ++kk) {
      s8v bg[4], bu[4];
#pragma unroll
      for (int nt = 0; nt < 4; ++nt) {
        bg[nt] = *(const s8v*)&Bg_l[(nt * 16 + lane16) * 72 + kk * 32 + quad * 8];
        bu[nt] = *(const s8v*)&Bu_l[(nt * 16 + lane16) * 72 + kk * 32 + quad * 8];
      }
#pragma unroll
      for (int mt = 0; mt < 2; ++mt)
#pragma unroll
        for (int nt = 0; nt < 4; ++nt) {
          Sg[mt][nt] = MFMA16(ag[mt][kk], bg[nt], Sg[mt][nt]);
          Su[mt][nt] = MFMA16(au[mt][kk], bu[nt], Su[mt][nt]);
        }
    }

    // silu(gate)*up -> per-wave inter region. No barrier: wave-local W->R.
#pragma unroll
    for (int mt = 0; mt < 2; ++mt)
#pragma unroll
      for (int nt = 0; nt < 4; ++nt)
#pragma unroll
        for (int r = 0; r < 4; ++r) {
          float sg = Sg[mt][nt][r];
          float v = sg / (1.f + __expf(-sg)) * Su[mt][nt][r];
          ib[(mt * 16 + quad * 4 + r) * 72 + nt * 16 + lane16] = f2bf(v);
        }
    asm volatile("s_waitcnt lgkmcnt(0)" ::: "memory");   // wave-local W->R order

#pragma unroll
    for (int kk = 0; kk < 2; ++kk) {
      s8v ai[2], bd[4];
#pragma unroll
      for (int mt = 0; mt < 2; ++mt)
        ai[mt] = *(const s8v*)&ib[(mt * 16 + lane16) * 72 + kk * 32 + quad * 8];
#pragma unroll
      for (int nt = 0; nt < 4; ++nt)
        bd[nt] = *(const s8v*)&Ad_l[(nt * 16 + lane16) * 72 + kk * 32 + quad * 8];
#pragma unroll
      for (int mt = 0; mt < 2; ++mt)
#pragma unroll
        for (int nt = 0; nt < 4; ++nt)
          P[mt][nt] = MFMA16(ai[mt], bd[nt], P[mt][nt]);
    }
    __syncthreads();   // protect Bg/Bu/Ad before next chunk's load
  }

#pragma unroll
  for (int mt = 0; mt < 2; ++mt)
#pragma unroll
    for (int nt = 0; nt < 4; ++nt)
#pragma unroll
      for (int r = 0; r < 4; ++r) {
        int lrow = w * 32 + mt * 16 + quad * 4 + r;
        int rid = rids[lrow];
        if (rid >= 0)
          atomicAdd(&h1d[(size_t)rid * 64 + nt * 16 + lane16], P[mt][nt][r]);
      }
}

// ---------------------------------------------------------------------------
// Per-expert down core via MFMA + routing weight, reduce to y[t,g,64].
// 512 threads: 128 rows/iter.
// ---------------------------------------------------------------------------
__global__ __launch_bounds__(512) void k_core_down(
    const float* __restrict__ h1d, const unsigned short* __restrict__ CdT,
    const float* __restrict__ rw,
    const int* __restrict__ rseg, const int* __restrict__ off_e,
    const int* __restrict__ cnt_e,
    float* __restrict__ y) {
  const int e = blockIdx.x;
  const int ne = cnt_e[e];
  if (ne == 0) return;
  const int g = e >> 5;
  const int base = off_e[e];
  __shared__ unsigned short Bd_l[64 * 72];
  __shared__ unsigned short Ad_l[128 * 72];
  __shared__ int rids[128];
  const int tid = threadIdx.x;
  const int w = tid >> 6, ln = tid & 63;
  const int quad = ln >> 4, lane16 = ln & 15;
  {
    int j = tid >> 3, q = (tid & 7) * 8;
    const unsigned short* cd = CdT + (size_t)e * (Rn * Rn);
    *(uint4*)&Bd_l[j * 72 + q] = *(const uint4*)&cd[j * 64 + q];
  }
  const int gj = tid >> 2, gq = (tid & 3) * 16;   // 128 rows x 4 chunks of 16
  const int ntile = (ne + 127) >> 7;
  for (int it = 0; it < ntile; ++it) {
    int mi = it * 128 + gj;
    int rid = (mi < ne) ? rseg[base + mi] : -1;
    if ((tid & 3) == 0) rids[gj] = rid;
#pragma unroll
    for (int i = 0; i < 4; ++i) {
      int kb = gq + i * 4;
      float4 vd = {0.f, 0.f, 0.f, 0.f};
      if (rid >= 0) vd = *(const float4*)&h1d[(size_t)rid * 64 + kb];
      ushort4 od;
      od.x = f2bf(vd.x); od.y = f2bf(vd.y); od.z = f2bf(vd.z); od.w = f2bf(vd.w);
      *(ushort4*)&Ad_l[gj * 72 + kb] = od;
    }
    __syncthreads();
    f4v Sd[4] = {};
#pragma unroll
    for (int kk = 0; kk < 2; ++kk) {
      s8v ad = *(const s8v*)&Ad_l[(w * 16 + lane16) * 72 + kk * 32 + quad * 8];
#pragma unroll
      for (int nt = 0; nt < 4; ++nt) {
        s8v bd = *(const s8v*)&Bd_l[(nt * 16 + lane16) * 72 + kk * 32 + quad * 8];
        Sd[nt] = MFMA16(ad, bd, Sd[nt]);
      }
    }
#pragma unroll
    for (int nt = 0; nt < 4; ++nt)
#pragma unroll
      for (int r = 0; r < 4; ++r) {
        int rid2 = rids[w * 16 + quad * 4 + r];
        if (rid2 >= 0) {
          float wgt = rw[rid2];
          atomicAdd(&y[(size_t)(rid2 >> 3) * (Gn * Rn) + g * 64 + nt * 16 + lane16],
                    wgt * Sd[nt][r]);
        }
      }
    __syncthreads();
  }
}

// ---------------------------------------------------------------------------
// Combine: out[2048,2048] = y[2048,512] @ B_down-as-[512,2048], MFMA bf16.
// ---------------------------------------------------------------------------
__global__ __launch_bounds__(256) void k_combine(
    const float* __restrict__ y, const unsigned short* __restrict__ BdT,
    float* __restrict__ outp) {
  const int t0 = blockIdx.y * 128, n0 = blockIdx.x * 128;
  __shared__ unsigned short As[128 * 72];
  __shared__ unsigned short Bs[128 * 72];
  const int tid = threadIdx.x;
  const int w = tid >> 6, ln = tid & 63;
  const int quad = ln >> 4, lane16 = ln & 15;
  const int mbase = (w >> 1) * 64, nbase = (w & 1) * 64;

  f4v acc[4][4] = {};

  for (int k0 = 0; k0 < Gn * Rn; k0 += 64) {
#pragma unroll
    for (int i = 0; i < 8; ++i) {
      int c = tid + i * 256;
      int row = c >> 4, cc = (c & 15) * 4;
      float4 v = *(const float4*)&y[(size_t)(t0 + row) * (Gn * Rn) + k0 + cc];
      ushort4 o;
      o.x = f2bf(v.x); o.y = f2bf(v.y); o.z = f2bf(v.z); o.w = f2bf(v.w);
      *(ushort4*)&As[row * 72 + cc] = o;
    }
#pragma unroll
    for (int i = 0; i < 4; ++i) {
      int c = tid + i * 256;
      int row = c >> 3, cc = (c & 7) * 8;
      *(uint4*)&Bs[row * 72 + cc] = *(const uint4*)&BdT[(size_t)(n0 + row) * (Gn * Rn) + k0 + cc];
    }
    __syncthreads();
#pragma unroll
    for (int kk = 0; kk < 2; ++kk) {
      s8v a[4], b[4];
#pragma unroll
      for (int mt = 0; mt < 4; ++mt)
        a[mt] = *(const s8v*)&As[(mbase + mt * 16 + lane16) * 72 + kk * 32 + quad * 8];
#pragma unroll
      for (int nt = 0; nt < 4; ++nt)
        b[nt] = *(const s8v*)&Bs[(nbase + nt * 16 + lane16) * 72 + kk * 32 + quad * 8];
#pragma unroll
      for (int mt = 0; mt < 4; ++mt)
#pragma unroll
        for (int nt = 0; nt < 4; ++nt)
          acc[mt][nt] = MFMA16(a[mt], b[nt], acc[mt][nt]);
    }
    __syncthreads();
  }
#pragma unroll
  for (int mt = 0; mt < 4; ++mt)
#pragma unroll
    for (int nt = 0; nt < 4; ++nt)
#pragma unroll
      for (int r = 0; r < 4; ++r)
        outp[(size_t)(t0 + mbase + mt * 16 + quad * 4 + r) * Dn +
             n0 + nbase + nt * 16 + lane16] = acc[mt][nt][r];
}

// ---------------------------------------------------------------------------
extern "C" void kernel_launch(void* const* d_in, const int* in_sizes, int n_in,
                              void* d_out, int out_size, void* d_ws, size_t ws_size,
                              hipStream_t stream) {
  const float* hidden = (const float*)d_in[0];
  const float* w_gate = (const float*)d_in[1];
  const float* A_gate = (const float*)d_in[2];
  const float* C_gate = (const float*)d_in[3];
  const float* B_gate = (const float*)d_in[4];
  const float* A_up   = (const float*)d_in[5];
  const float* C_up   = (const float*)d_in[6];
  const float* B_up   = (const float*)d_in[7];
  const float* A_down = (const float*)d_in[8];
  const float* C_down = (const float*)d_in[9];
  const float* B_down = (const float*)d_in[10];
  float* out = (float*)d_out;

  // Workspace layout (peak unchanged, 34.34 MB). Router-stage {part 12.6MB
  // (KS_R=6), hq 16.8MB, wqT 2.1MB} = 31.5MB overlay [0, 31.5MB), all dead
  // after k_topk and below the persistent smalls at 33.69MB. Hbf aliases
  // h1d+y (written after router stage, dead before h1d/y memsets).
  char* base = (char*)d_ws;
  size_t o = 0;
  unsigned short* h2gb = (unsigned short*)(base + o); o += (size_t)NROWS * Rn * 2;
  unsigned short* h2ub = (unsigned short*)(base + o); o += (size_t)NROWS * Rn * 2;
  unsigned short* AgT  = (unsigned short*)(base + o); o += (size_t)Gn * Rn * Dn * 2;
  unsigned short* AuT  = (unsigned short*)(base + o); o += (size_t)Gn * Rn * Dn * 2;
  unsigned short* BgT  = (unsigned short*)(base + o); o += (size_t)Gn * In * Rn * 2;
  unsigned short* BuT  = (unsigned short*)(base + o); o += (size_t)Gn * In * Rn * 2;
  unsigned short* AdT  = (unsigned short*)(base + o); o += (size_t)Gn * Rn * In * 2;
  unsigned short* BdT  = (unsigned short*)(base + o); o += (size_t)Dn * Gn * Rn * 2;
  unsigned short* CgT  = (unsigned short*)(base + o); o += (size_t)En * Rn * Rn * 2;
  unsigned short* CuT  = (unsigned short*)(base + o); o += (size_t)En * Rn * Rn * 2;
  unsigned short* CdT  = (unsigned short*)(base + o); o += (size_t)En * Rn * Rn * 2;
  unsigned short* h1gb = (unsigned short*)(base + o); o += (size_t)T0n * Gn * Rn * 2;
  unsigned short* h1ub = (unsigned short*)(base + o); o += (size_t)T0n * Gn * Rn * 2;
  float* h1d = (float*)(base + o); o += (size_t)NROWS * Rn * 4;
  float* y   = (float*)(base + o); o += (size_t)T0n * Gn * Rn * 4;
  // ---- persistent smalls ----
  float* rwp = (float*)(base + o); o += (size_t)NROWS * 4;
  int* sel   = (int*)(base + o); o += (size_t)NROWS * 4;
  int* rseg  = (int*)(base + o); o += (size_t)Gn * SEGCAP * 4;
  int* cnt_e = (int*)(base + o); o += En * 4;
  int* off_e = (int*)(base + o); o += En * 4;
  int* cur_e = (int*)(base + o); o += En * 4;
  int* grp_n = (int*)(base + o); o += Gn * 4;
  // ---- router-stage aliases (dead after k_topk), inside [0, 31.5MB) ----
  float* part = (float*)base;                              // 6*2048*256*4 = 12,582,912
  char* hq  = base + (size_t)KS_R * T0n * En * 4;          // +16,777,216 (4 i8 planes)
  char* wqT = hq + (size_t)4 * T0n * Dn;                   // +2,097,152  (4 i8 planes, T)
  // ---- Hbf alias: h1d (4.19MB) + y (4.19MB) = exactly T0n*Dn*2 bytes ----
  unsigned short* Hbf = (unsigned short*)h1d;

  hipMemsetAsync(cnt_e, 0, En * sizeof(int), stream);

  // 1) quantize inputs to exact 4x-i8 fixed-point limbs
  k_quant_h<<<T0n * Dn / 1024, 256, 0, stream>>>(hidden, hq);
  k_quant_wT<<<dim3(Dn / 32, En / 32), 256, 0, stream>>>(w_gate, wqT);
  // 2) router logits via i32-MFMA limb GEMM (s>=3 pairs, split-K=6)
  k_router_i8<<<dim3(En / 64, T0n / 64, KS_R), 256, 0, stream>>>(hq, wqT, part);
  // 3) top-8 + renorm + expert counts
  k_topk<<<T0n / 4, 256, 0, stream>>>(part, sel, rwp, cnt_e);
  // 4) offsets (parallel prefix) + scatter rows by expert
  k_scan<<<1, 256, 0, stream>>>(cnt_e, off_e, cur_e, grp_n);
  k_scatter<<<NROWS / 256, 256, 0, stream>>>(sel, cur_e, rseg);

  // part/hq/wqT now dead. Convert H to bf16 once (into the h1d+y alias).
  k_hcvt<<<T0n * Dn / 2048, 256, 0, stream>>>(hidden, Hbf);

  // 5) transpose+convert all 9 weight tensors to bf16 operand layouts
  {
    TD9 D;
    D.t[0] = {A_gate, AgT, Dn, Rn, Rn / 32, (Rn / 32) * (Dn / 32), 0};
    D.t[1] = {A_up,   AuT, Dn, Rn, Rn / 32, (Rn / 32) * (Dn / 32), 1024};
    D.t[2] = {B_gate, BgT, Rn, In, In / 32, (In / 32) * (Rn / 32), 2048};
    D.t[3] = {B_up,   BuT, Rn, In, In / 32, (In / 32) * (Rn / 32), 2752};
    D.t[4] = {A_down, AdT, In, Rn, Rn / 32, (Rn / 32) * (In / 32), 3456};
    D.t[5] = {B_down, BdT, Gn * Rn, Dn, Dn / 32, (Dn / 32) * (Gn * Rn / 32), 4160};
    D.t[6] = {C_gate, CgT, Rn, Rn, 2, 4, 5184};
    D.t[7] = {C_up,   CuT, Rn, Rn, 2, 4, 6208};
    D.t[8] = {C_down, CdT, Rn, Rn, 2, 4, 7232};
    k_tcvt9<<<8256, 256, 0, stream>>>(D);
  }

  // 6) dense in-factor projections (bf16 H from Hbf)
  k_h1_mfma<<<dim3(T0n / 64, Gn), 512, 0, stream>>>(Hbf, AgT, AuT, h1gb, h1ub);

  // Hbf dead; reclaim h1d + y.
  hipMemsetAsync(h1d, 0, (size_t)NROWS * Rn * sizeof(float), stream);
  hipMemsetAsync(y,   0, (size_t)T0n * Gn * Rn * sizeof(float), stream);

  // 7) per-expert core (gate/up) via MFMA (512 thr path-split)
  k_core_gu<<<En, 512, 0, stream>>>(h1gb, h1ub, CgT, CuT,
                                    rseg, off_e, cnt_e, h2gb, h2ub);
  // 8) fused expand + down-A (R17: 8-wave / 256-row tiles)
  k_expand_mfma<<<dim3(NTILE2_MAX, 4), 512, 0, stream>>>(
      h2gb, h2ub, BgT, BuT, AdT, rseg, grp_n, h1d);
  // 9) per-expert down core via MFMA + rw (512 thr, 128 rows/iter)
  k_core_down<<<En, 512, 0, stream>>>(h1d, CdT, rwp,
                                      rseg, off_e, cnt_e, y);
  // 10) combine (MFMA bf16)
  k_combine<<<dim3(Dn / 128, T0n / 128), 256, 0, stream>>>(y, BdT, out);
}

// Round 14
// 294.600 us; speedup vs baseline: 1.1234x; 1.0236x over previous
//
#include <hip/hip_runtime.h>
#include <math.h>

// Problem dims
constexpr int T0n = 2048;   // tokens
constexpr int Dn  = 2048;   // hidden
constexpr int En  = 256;    // experts
constexpr int Gn  = 8;      // groups
constexpr int EGn = 32;     // experts per group
constexpr int Rn  = 64;     // tucker rank
constexpr int In  = 1408;   // intermediate

constexpr int NROWS = T0n * 8;    // 16384 dispatched rows
constexpr int SEGCAP = NROWS;     // per-group segment capacity in rseg
constexpr int KS_R = 6;           // router split-K (i32 exact, uneven split OK)
constexpr int NTILE2_MAX = NROWS / 256 + Gn;   // 72: bound on sum ceil(ng/256)

typedef __attribute__((ext_vector_type(8))) short s8v;    // 8 bf16
typedef __attribute__((ext_vector_type(4))) float f4v;    // 4 fp32
typedef __attribute__((ext_vector_type(4))) int i4v;      // 16 i8 operand / 4 i32 acc
#define MFMA16(a, b, c) __builtin_amdgcn_mfma_f32_16x16x32_bf16(a, b, c, 0, 0, 0)
#define MFMAI8(a, b, c) __builtin_amdgcn_mfma_i32_16x16x64_i8(a, b, c, 0, 0, 0)

__device__ __forceinline__ unsigned short f2bf(float x) {
  unsigned int u = __float_as_uint(x);
  unsigned int r = (u + 0x7FFFu + ((u >> 16) & 1u)) >> 16;
  return (unsigned short)r;
}

// ---------------------------------------------------------------------------
// Fused batched transpose+convert for 9 weight tensors:
// src f32 [batch][rows][cols] -> dst bf16 [batch][cols][rows].
// ---------------------------------------------------------------------------
struct TD { const float* src; unsigned short* dst; int rows, cols, nbx, per_batch, base; };
struct TD9 { TD t[9]; };

__global__ __launch_bounds__(256) void k_tcvt9(TD9 D) {
  __shared__ float tbuf[32][33];
  int id = blockIdx.x;
  int ti = 0;
#pragma unroll
  for (int i = 1; i < 9; ++i) ti = (id >= D.t[i].base) ? i : ti;
  TD d = D.t[ti];
  int local = id - d.base;
  int bz = local / d.per_batch;
  int rem = local - bz * d.per_batch;
  int by = rem / d.nbx;
  int bx = rem - by * d.nbx;

  size_t boff = (size_t)bz * d.rows * d.cols;
  const float* src = d.src + boff;
  unsigned short* dst = d.dst + boff;
  int c0 = bx * 32, r0 = by * 32;
  int tx = threadIdx.x & 31, ty = threadIdx.x >> 5;   // ty 0..7
  for (int i = ty; i < 32; i += 8)
    tbuf[i][tx] = src[(size_t)(r0 + i) * d.cols + c0 + tx];
  __syncthreads();
  for (int i = ty; i < 32; i += 8)
    dst[(size_t)(c0 + i) * d.rows + r0 + tx] = f2bf(tbuf[tx][i]);
}

// ---------------------------------------------------------------------------
// H f32 -> bf16 once. Halves H traffic in k_h1_mfma.
// ---------------------------------------------------------------------------
__global__ __launch_bounds__(256) void k_hcvt(
    const float* __restrict__ H, unsigned short* __restrict__ Hbf) {
  size_t i = ((size_t)blockIdx.x * 256 + threadIdx.x) * 8;
  float4 v0 = *(const float4*)&H[i];
  float4 v1 = *(const float4*)&H[i + 4];
  ushort4 o0, o1;
  o0.x = f2bf(v0.x); o0.y = f2bf(v0.y); o0.z = f2bf(v0.z); o0.w = f2bf(v0.w);
  o1.x = f2bf(v1.x); o1.y = f2bf(v1.y); o1.z = f2bf(v1.z); o1.w = f2bf(v1.w);
  *(ushort4*)&Hbf[i] = o0;
  *(ushort4*)&Hbf[i + 4] = o1;
}

// ---------------------------------------------------------------------------
// ROUTER, fixed-point limb path. Pairs k+l>=3 (10 MFMA). s=3 is NOT
// droppable (~2.6e-6 rms vs token-min top-8 gap ~1.5e-5); s=2 drop verified
// byte-identical absmax (R12 data).
// ---------------------------------------------------------------------------
__device__ __forceinline__ int4 limbs4(float v, double sc) {
  double d = (double)v * sc;           // exact in double
  d = fmin(fmax(d, -2.0e9), 2.0e9);    // clamp (unreachable for this data)
  int x = __double2int_rn(d);
  int l0 = (int)(signed char)(x & 0xff); x = (x - l0) >> 8;   // exact
  int l1 = (int)(signed char)(x & 0xff); x = (x - l1) >> 8;
  int l2 = (int)(signed char)(x & 0xff); x = (x - l2) >> 8;
  return make_int4(l0, l1, l2, x);     // x fits i8
}

// hidden [2048][2048] f32 -> hq planes [4][2048][2048] i8 (limb-major).
__global__ __launch_bounds__(256) void k_quant_h(
    const float* __restrict__ H, char* __restrict__ hq) {
  const size_t PL = (size_t)T0n * Dn;
  size_t i = (size_t)blockIdx.x * 256 + threadIdx.x;   // group of 4 elements
  float4 v = *(const float4*)&H[i * 4];
  int4 a = limbs4(v.x, 268435456.0);   // 2^28
  int4 b = limbs4(v.y, 268435456.0);
  int4 c = limbs4(v.z, 268435456.0);
  int4 d = limbs4(v.w, 268435456.0);
  unsigned int p0 = (a.x & 0xff) | ((b.x & 0xff) << 8) | ((c.x & 0xff) << 16) | ((unsigned)(d.x & 0xff) << 24);
  unsigned int p1 = (a.y & 0xff) | ((b.y & 0xff) << 8) | ((c.y & 0xff) << 16) | ((unsigned)(d.y & 0xff) << 24);
  unsigned int p2 = (a.z & 0xff) | ((b.z & 0xff) << 8) | ((c.z & 0xff) << 16) | ((unsigned)(d.z & 0xff) << 24);
  unsigned int p3 = (a.w & 0xff) | ((b.w & 0xff) << 8) | ((c.w & 0xff) << 16) | ((unsigned)(d.w & 0xff) << 24);
  *(unsigned int*)&hq[0 * PL + i * 4] = p0;
  *(unsigned int*)&hq[1 * PL + i * 4] = p1;
  *(unsigned int*)&hq[2 * PL + i * 4] = p2;
  *(unsigned int*)&hq[3 * PL + i * 4] = p3;
}

// w_gate [2048][256] f32 -> wqT planes [4][256][2048] i8 (transposed, limb-major).
__global__ __launch_bounds__(256) void k_quant_wT(
    const float* __restrict__ W, char* __restrict__ wqT) {
  __shared__ float tb[32][33];
  const size_t PL = (size_t)En * Dn;
  int kb = blockIdx.x * 32, nb = blockIdx.y * 32;
  int tx = threadIdx.x & 31, ty = threadIdx.x >> 5;
  for (int i = ty; i < 32; i += 8)
    tb[i][tx] = W[(size_t)(kb + i) * En + nb + tx];
  __syncthreads();
  for (int i = ty; i < 32; i += 8) {
    int4 l = limbs4(tb[tx][i], 8589934592.0);   // 2^33
    size_t off = (size_t)(nb + i) * Dn + kb + tx;
    wqT[0 * PL + off] = (char)l.x;
    wqT[1 * PL + off] = (char)l.y;
    wqT[2 * PL + off] = (char)l.z;
    wqT[3 * PL + off] = (char)l.w;
  }
}

// i8 MFMA router GEMM. 10 MFMA/step (s>=3), KS_R=6 (uneven split).
// grid (En/64, T0n/64, KS_R).
__global__ __launch_bounds__(256) void k_router_i8(
    const char* __restrict__ hq, const char* __restrict__ wqT,
    float* __restrict__ part) {
  __shared__ __align__(16) char Asl[4][64][80];   // [limb][m-row][k]
  __shared__ __align__(16) char Bsl[4][64][80];   // [limb][n-row][k]
  const int n0 = blockIdx.x * 64, m0 = blockIdx.y * 64;
  const int kc = blockIdx.z;
  const int tid = threadIdx.x;
  const int w = tid >> 6, ln = tid & 63;
  const int quad = ln >> 4, lane16 = ln & 15;

  const char* ha = hq + ((size_t)w * T0n + m0 + ln) * Dn;   // plane w, row m0+ln
  const char* ba = wqT + ((size_t)w * En + n0 + ln) * Dn;   // plane w, row n0+ln

  i4v acc[4][4] = {};   // [m-tile][s-group s=k+l-3, s in 3..6]

  // Uneven K-split over 32 steps of 64: kc gets steps [kc*32/6,(kc+1)*32/6).
  const int kbeg = ((kc * 32) / KS_R) * 64;
  const int kend = (((kc + 1) * 32) / KS_R) * 64;
  for (int k0 = kbeg; k0 < kend; k0 += 64) {
#pragma unroll
    for (int q = 0; q < 4; ++q) {
      *(uint4*)&Asl[w][ln][q * 16] = *(const uint4*)&ha[k0 + q * 16];
      *(uint4*)&Bsl[w][ln][q * 16] = *(const uint4*)&ba[k0 + q * 16];
    }
    __syncthreads();
    i4v b0 = *(const i4v*)&Bsl[0][w * 16 + lane16][quad * 16];
    i4v b1 = *(const i4v*)&Bsl[1][w * 16 + lane16][quad * 16];
    i4v b2 = *(const i4v*)&Bsl[2][w * 16 + lane16][quad * 16];
    i4v b3 = *(const i4v*)&Bsl[3][w * 16 + lane16][quad * 16];
#pragma unroll
    for (int mt = 0; mt < 4; ++mt) {
      i4v a0 = *(const i4v*)&Asl[0][mt * 16 + lane16][quad * 16];
      i4v a1 = *(const i4v*)&Asl[1][mt * 16 + lane16][quad * 16];
      i4v a2 = *(const i4v*)&Asl[2][mt * 16 + lane16][quad * 16];
      i4v a3 = *(const i4v*)&Asl[3][mt * 16 + lane16][quad * 16];
      // s = 3
      acc[mt][0] = MFMAI8(a0, b3, acc[mt][0]);
      acc[mt][0] = MFMAI8(a1, b2, acc[mt][0]);
      acc[mt][0] = MFMAI8(a2, b1, acc[mt][0]);
      acc[mt][0] = MFMAI8(a3, b0, acc[mt][0]);
      // s = 4
      acc[mt][1] = MFMAI8(a1, b3, acc[mt][1]);
      acc[mt][1] = MFMAI8(a2, b2, acc[mt][1]);
      acc[mt][1] = MFMAI8(a3, b1, acc[mt][1]);
      // s = 5
      acc[mt][2] = MFMAI8(a2, b3, acc[mt][2]);
      acc[mt][2] = MFMAI8(a3, b2, acc[mt][2]);
      // s = 6
      acc[mt][3] = MFMAI8(a3, b3, acc[mt][3]);
    }
    __syncthreads();
  }

  // Combine 4 exact i32 sums at scales 2^(8s-61), s=3..6.
  float* prow = part + (size_t)kc * T0n * En;
#pragma unroll
  for (int mt = 0; mt < 4; ++mt)
#pragma unroll
    for (int r = 0; r < 4; ++r) {
      int row = m0 + mt * 16 + quad * 4 + r;
      int col = n0 + w * 16 + lane16;
      double v = (double)acc[mt][0][r] * 0x1p-37 +
                 (double)acc[mt][1][r] * 0x1p-29 +
                 (double)acc[mt][2][r] * 0x1p-21 +
                 (double)acc[mt][3][r] * 0x1p-13;
      prow[(size_t)row * En + col] = (float)v;
    }
}

// ---------------------------------------------------------------------------
// Top-8: one wave per token, shuffle butterfly. Sums KS_R fp32 partials in fp64.
// ---------------------------------------------------------------------------
__global__ __launch_bounds__(256) void k_topk(
    const float* __restrict__ part, int* __restrict__ sel,
    float* __restrict__ rw, int* __restrict__ cnt_e) {
  const int wid = threadIdx.x >> 6, ln = threadIdx.x & 63;
  const int t = blockIdx.x * 4 + wid;

  double v[4];
#pragma unroll
  for (int j = 0; j < 4; ++j) {
    double s = 0.0;
#pragma unroll
    for (int kc = 0; kc < KS_R; ++kc)
      s += (double)part[((size_t)kc * T0n + t) * En + ln + 64 * j];
    v[j] = s;
  }

  float topv[8];
  int topi[8];
#pragma unroll
  for (int k = 0; k < 8; ++k) {
    double bv = v[0]; int bi = ln;
#pragma unroll
    for (int j = 1; j < 4; ++j) {
      int cand = ln + 64 * j;
      if (v[j] > bv || (v[j] == bv && cand < bi)) { bv = v[j]; bi = cand; }
    }
#pragma unroll
    for (int off = 32; off > 0; off >>= 1) {
      double ov = __shfl_xor(bv, off);
      int oi = __shfl_xor(bi, off);
      if (ov > bv || (ov == bv && oi < bi)) { bv = ov; bi = oi; }
    }
    topv[k] = (float)bv; topi[k] = bi;
    if ((bi & 63) == ln) v[bi >> 6] = -1e300;
  }

  if (ln < 8) {
    float m = topv[0];
    float ssum = 0.f;
#pragma unroll
    for (int k = 0; k < 8; ++k) ssum += expf(topv[k] - m);
    rw[t * 8 + ln] = expf(topv[ln] - m) / ssum;
    sel[t * 8 + ln] = topi[ln];
    atomicAdd(&cnt_e[topi[ln]], 1);
  }
}

// Parallel per-group prefix over 256 experts.
__global__ __launch_bounds__(256) void k_scan(
    const int* __restrict__ cnt_e, int* __restrict__ off_e,
    int* __restrict__ cur_e, int* __restrict__ grp_n) {
  __shared__ int c[256];
  int tid = threadIdx.x;
  c[tid] = cnt_e[tid];
  __syncthreads();
  int g = tid >> 5, ei = tid & 31;
  int run = 0;
  for (int i = 0; i < ei; ++i) run += c[(g << 5) + i];
  off_e[tid] = g * SEGCAP + run;
  cur_e[tid] = g * SEGCAP + run;
  if (ei == 31) grp_n[g] = run + c[tid];
}

__global__ void k_scatter(const int* __restrict__ sel, int* __restrict__ cur_e,
                          int* __restrict__ rseg) {
  int i = blockIdx.x * 256 + threadIdx.x;
  int e = sel[i];
  int pos = atomicAdd(&cur_e[e], 1);
  rseg[pos] = i;
}

// ---------------------------------------------------------------------------
// h1 = H @ A_fac[g]. bf16 H (k_hcvt); single uint4 staging load per thread.
// 512 threads: waves 0-3 gate, 4-7 up. grid (T0/64, G).
// ---------------------------------------------------------------------------
__global__ __launch_bounds__(512) void k_h1_mfma(
    const unsigned short* __restrict__ Hbf,
    const unsigned short* __restrict__ AgT, const unsigned short* __restrict__ AuT,
    unsigned short* __restrict__ h1gb, unsigned short* __restrict__ h1ub) {
  const int t0 = blockIdx.x * 64;
  const int g = blockIdx.y;
  const unsigned short* Wg = AgT + (size_t)g * Rn * Dn;
  const unsigned short* Wu = AuT + (size_t)g * Rn * Dn;

  __shared__ unsigned short As[64 * 72];
  __shared__ unsigned short Bg_l[64 * 72];
  __shared__ unsigned short Bu_l[64 * 72];
  const int tid = threadIdx.x;
  const int w = tid >> 6, ln = tid & 63;
  const int path = w >> 2, ws = w & 3;
  const int quad = ln >> 4, lane16 = ln & 15;
  const int j = tid >> 3, q = (tid & 7) * 8;   // 64 rows x 8 chunks

  f4v S[4] = {};

  for (int k0 = 0; k0 < Dn; k0 += 64) {
    {
      *(uint4*)&As[j * 72 + q] = *(const uint4*)&Hbf[(size_t)(t0 + j) * Dn + k0 + q];
      *(uint4*)&Bg_l[j * 72 + q] = *(const uint4*)&Wg[(size_t)j * Dn + k0 + q];
      *(uint4*)&Bu_l[j * 72 + q] = *(const uint4*)&Wu[(size_t)j * Dn + k0 + q];
    }
    __syncthreads();
    const unsigned short* Bl = path ? Bu_l : Bg_l;
#pragma unroll
    for (int kk = 0; kk < 2; ++kk) {
      s8v a = *(const s8v*)&As[(ws * 16 + lane16) * 72 + kk * 32 + quad * 8];
#pragma unroll
      for (int nt = 0; nt < 4; ++nt) {
        s8v b = *(const s8v*)&Bl[(nt * 16 + lane16) * 72 + kk * 32 + quad * 8];
        S[nt] = MFMA16(a, b, S[nt]);
      }
    }
    __syncthreads();
  }
  unsigned short* out = path ? h1ub : h1gb;
#pragma unroll
  for (int nt = 0; nt < 4; ++nt)
#pragma unroll
    for (int r = 0; r < 4; ++r) {
      int row = t0 + ws * 16 + quad * 4 + r;
      int col = g * 64 + nt * 16 + lane16;
      out[(size_t)row * (Gn * Rn) + col] = f2bf(S[nt][r]);
    }
}

// ---------------------------------------------------------------------------
// Per-expert core (gate/up) via MFMA. 512 threads: waves 0-3 gate, 4-7 up.
// ---------------------------------------------------------------------------
__global__ __launch_bounds__(512) void k_core_gu(
    const unsigned short* __restrict__ h1gb, const unsigned short* __restrict__ h1ub,
    const unsigned short* __restrict__ CgT, const unsigned short* __restrict__ CuT,
    const int* __restrict__ rseg, const int* __restrict__ off_e,
    const int* __restrict__ cnt_e,
    unsigned short* __restrict__ h2gb, unsigned short* __restrict__ h2ub) {
  const int e = blockIdx.x;
  const int ne = cnt_e[e];
  if (ne == 0) return;
  const int g = e >> 5;
  const int base = off_e[e];
  __shared__ unsigned short Cg_l[64 * 72];
  __shared__ unsigned short Cu_l[64 * 72];
  __shared__ unsigned short Ags[64 * 72];
  __shared__ unsigned short Aus[64 * 72];
  __shared__ int rids[64];
  const int tid = threadIdx.x;
  const int w = tid >> 6, ln = tid & 63;
  const int path = w >> 2, ws = w & 3;
  const int quad = ln >> 4, lane16 = ln & 15;
  const int j = tid >> 3, q = (tid & 7) * 8;
  {
    const unsigned short* cg = CgT + (size_t)e * (Rn * Rn);
    const unsigned short* cu = CuT + (size_t)e * (Rn * Rn);
    *(uint4*)&Cg_l[j * 72 + q] = *(const uint4*)&cg[j * 64 + q];
    *(uint4*)&Cu_l[j * 72 + q] = *(const uint4*)&cu[j * 64 + q];
  }
  const int ntile = (ne + 63) >> 6;
  for (int it = 0; it < ntile; ++it) {
    int mi = it * 64 + j;
    int rid = (mi < ne) ? rseg[base + mi] : -1;
    if ((tid & 7) == 0) rids[j] = rid;
    uint4 zg = {0, 0, 0, 0}, zu = {0, 0, 0, 0};
    if (rid >= 0) {
      zg = *(const uint4*)&h1gb[(size_t)(rid >> 3) * (Gn * Rn) + g * 64 + q];
      zu = *(const uint4*)&h1ub[(size_t)(rid >> 3) * (Gn * Rn) + g * 64 + q];
    }
    *(uint4*)&Ags[j * 72 + q] = zg;
    *(uint4*)&Aus[j * 72 + q] = zu;
    __syncthreads();
    const unsigned short* Al = path ? Aus : Ags;
    const unsigned short* Cl = path ? Cu_l : Cg_l;
    f4v S[4] = {};
#pragma unroll
    for (int kk = 0; kk < 2; ++kk) {
      s8v a = *(const s8v*)&Al[(ws * 16 + lane16) * 72 + kk * 32 + quad * 8];
#pragma unroll
      for (int nt = 0; nt < 4; ++nt) {
        s8v b = *(const s8v*)&Cl[(nt * 16 + lane16) * 72 + kk * 32 + quad * 8];
        S[nt] = MFMA16(a, b, S[nt]);
      }
    }
    unsigned short* out = path ? h2ub : h2gb;
#pragma unroll
    for (int nt = 0; nt < 4; ++nt)
#pragma unroll
      for (int r = 0; r < 4; ++r) {
        int rid2 = rids[ws * 16 + quad * 4 + r];
        if (rid2 >= 0)
          out[(size_t)rid2 * 64 + nt * 16 + lane16] = f2bf(S[nt][r]);
      }
    __syncthreads();
  }
}

// ---------------------------------------------------------------------------
// Fused expand + down-A via MFMA. R17 8-wave/256-row form (44us, VGPR 84) +
// R18: T14 register prefetch RETRY — the R11 failure was the 128-VGPR
// occupancy cliff (112+24=136 -> 3 waves/SIMD), not the mechanism. At 84
// VGPR, +12 staging regs = ~96-100, stays 4 waves/SIMD. Loads for chunk c+1
// issue right after the barrier that publishes chunk c; their vmcnt wait
// lands at the next iteration's ds_write, after ~1200cy of MFMA+silu+PV.
// ---------------------------------------------------------------------------
__global__ __launch_bounds__(512) void k_expand_mfma(
    const unsigned short* __restrict__ h2gb, const unsigned short* __restrict__ h2ub,
    const unsigned short* __restrict__ BgT, const unsigned short* __restrict__ BuT,
    const unsigned short* __restrict__ AdT,
    const int* __restrict__ rseg, const int* __restrict__ grp_n,
    float* __restrict__ h1d) {
  // Decode flat 256-row tile id -> (g, m0) via prefix over per-group counts.
  int t = blockIdx.x;
  int g = -1, m0 = 0, ng = 0;
  {
    int pre = 0;
#pragma unroll
    for (int gg = 0; gg < Gn; ++gg) {
      int n = grp_n[gg];
      int nt = (n + 255) >> 8;
      if (g < 0 && t < pre + nt) { g = gg; m0 = (t - pre) << 8; ng = n; }
      pre += nt;
    }
  }
  if (g < 0) return;
  const int c_beg = blockIdx.y * 6;
  const int c_end = min(22, c_beg + 6);

  __shared__ unsigned short Bg_l[64 * 72];
  __shared__ unsigned short Bu_l[64 * 72];
  __shared__ unsigned short Ad_l[64 * 72];
  __shared__ unsigned short inter_l[8][32 * 72];   // per-wave private
  __shared__ int rids[256];

  const int tid = threadIdx.x;
  const int w = tid >> 6, ln = tid & 63;   // w in 0..7
  const int quad = ln >> 4, lane16 = ln & 15;

  if (tid < 256) rids[tid] = (m0 + tid < ng) ? rseg[g * SEGCAP + m0 + tid] : -1;
  __syncthreads();

  // H gate/up fragments in registers: wave w owns rows w*32..w*32+31.
  s8v ag[2][2], au[2][2];
#pragma unroll
  for (int mt = 0; mt < 2; ++mt) {
    int rid = rids[w * 32 + mt * 16 + lane16];
#pragma unroll
    for (int kk = 0; kk < 2; ++kk) {
      s8v zg = {}, zu = {};
      if (rid >= 0) {
        zg = *(const s8v*)&h2gb[(size_t)rid * 64 + kk * 32 + quad * 8];
        zu = *(const s8v*)&h2ub[(size_t)rid * 64 + kk * 32 + quad * 8];
      }
      ag[mt][kk] = zg;
      au[mt][kk] = zu;
    }
  }

  const unsigned short* Bg_base = BgT + (size_t)g * In * Rn;
  const unsigned short* Bu_base = BuT + (size_t)g * In * Rn;
  const unsigned short* Ad_base = AdT + (size_t)g * Rn * In;

  unsigned short* ib = &inter_l[w][0];
  f4v P[2][4] = {};
  const int srow = tid >> 3, sco = (tid & 7) * 8;   // 512 thr: 64 rows x 8 cols

  // T14 prologue: stage first chunk into registers.
  uint4 sg, su, sd;
  {
    const int i0 = c_beg * 64;
    sg = *(const uint4*)&Bg_base[(size_t)(i0 + srow) * Rn + sco];
    su = *(const uint4*)&Bu_base[(size_t)(i0 + srow) * Rn + sco];
    sd = *(const uint4*)&Ad_base[(size_t)srow * In + i0 + sco];
  }

  for (int c = c_beg; c < c_end; ++c) {
    // Publish staged tiles (implicit vmcnt wait lands here, covered by the
    // previous iteration's compute).
    *(uint4*)&Bg_l[srow * 72 + sco] = sg;
    *(uint4*)&Bu_l[srow * 72 + sco] = su;
    *(uint4*)&Ad_l[srow * 72 + sco] = sd;
    __syncthreads();   // B tiles ready

    // Issue next chunk's loads; latency hides under the compute below.
    if (c + 1 < c_end) {
      const int i1 = (c + 1) * 64;
      sg = *(const uint4*)&Bg_base[(size_t)(i1 + srow) * Rn + sco];
      su = *(const uint4*)&Bu_base[(size_t)(i1 + srow) * Rn + sco];
      sd = *(const uint4*)&Ad_base[(size_t)srow * In + i1 + sco];
    }

    f4v Sg[2][4] = {}, Su[2][4] = {};
#pragma unroll
    for (int kk = 0; kk < 2; ++kk) {
      s8v bg[4], bu[4];
#pragma unroll
      for (int nt = 0; nt < 4; ++nt) {
        bg[nt] = *(const s8v*)&Bg_l[(nt * 16 + lane16) * 72 + kk * 32 + quad * 8];
        bu[nt] = *(const s8v*)&Bu_l[(nt * 16 + lane16) * 72 + kk * 32 + quad * 8];
      }
#pragma unroll
      for (int mt = 0; mt < 2; ++mt)
#pragma unroll
        for (int nt = 0; nt < 4; ++nt) {
          Sg[mt][nt] = MFMA16(ag[mt][kk], bg[nt], Sg[mt][nt]);
          Su[mt][nt] = MFMA16(au[mt][kk], bu[nt], Su[mt][nt]);
        }
    }

    // silu(gate)*up -> per-wave inter region. No barrier: wave-local W->R.
#pragma unroll
    for (int mt = 0; mt < 2; ++mt)
#pragma unroll
      for (int nt = 0; nt < 4; ++nt)
#pragma unroll
        for (int r = 0; r < 4; ++r) {
          float sg2 = Sg[mt][nt][r];
          float v = sg2 / (1.f + __expf(-sg2)) * Su[mt][nt][r];
          ib[(mt * 16 + quad * 4 + r) * 72 + nt * 16 + lane16] = f2bf(v);
        }
    asm volatile("s_waitcnt lgkmcnt(0)" ::: "memory");   // wave-local W->R order

#pragma unroll
    for (int kk = 0; kk < 2; ++kk) {
      s8v ai[2], bd[4];
#pragma unroll
      for (int mt = 0; mt < 2; ++mt)
        ai[mt] = *(const s8v*)&ib[(mt * 16 + lane16) * 72 + kk * 32 + quad * 8];
#pragma unroll
      for (int nt = 0; nt < 4; ++nt)
        bd[nt] = *(const s8v*)&Ad_l[(nt * 16 + lane16) * 72 + kk * 32 + quad * 8];
#pragma unroll
      for (int mt = 0; mt < 2; ++mt)
#pragma unroll
        for (int nt = 0; nt < 4; ++nt)
          P[mt][nt] = MFMA16(ai[mt], bd[nt], P[mt][nt]);
    }
    __syncthreads();   // B tiles consumed; safe to overwrite next iteration
  }

#pragma unroll
  for (int mt = 0; mt < 2; ++mt)
#pragma unroll
    for (int nt = 0; nt < 4; ++nt)
#pragma unroll
      for (int r = 0; r < 4; ++r) {
        int lrow = w * 32 + mt * 16 + quad * 4 + r;
        int rid = rids[lrow];
        if (rid >= 0)
          atomicAdd(&h1d[(size_t)rid * 64 + nt * 16 + lane16], P[mt][nt][r]);
      }
}

// ---------------------------------------------------------------------------
// Per-expert down core via MFMA + routing weight, reduce to y[t,g,64].
// 512 threads: 128 rows/iter.
// ---------------------------------------------------------------------------
__global__ __launch_bounds__(512) void k_core_down(
    const float* __restrict__ h1d, const unsigned short* __restrict__ CdT,
    const float* __restrict__ rw,
    const int* __restrict__ rseg, const int* __restrict__ off_e,
    const int* __restrict__ cnt_e,
    float* __restrict__ y) {
  const int e = blockIdx.x;
  const int ne = cnt_e[e];
  if (ne == 0) return;
  const int g = e >> 5;
  const int base = off_e[e];
  __shared__ unsigned short Bd_l[64 * 72];
  __shared__ unsigned short Ad_l[128 * 72];
  __shared__ int rids[128];
  const int tid = threadIdx.x;
  const int w = tid >> 6, ln = tid & 63;
  const int quad = ln >> 4, lane16 = ln & 15;
  {
    int j = tid >> 3, q = (tid & 7) * 8;
    const unsigned short* cd = CdT + (size_t)e * (Rn * Rn);
    *(uint4*)&Bd_l[j * 72 + q] = *(const uint4*)&cd[j * 64 + q];
  }
  const int gj = tid >> 2, gq = (tid & 3) * 16;   // 128 rows x 4 chunks of 16
  const int ntile = (ne + 127) >> 7;
  for (int it = 0; it < ntile; ++it) {
    int mi = it * 128 + gj;
    int rid = (mi < ne) ? rseg[base + mi] : -1;
    if ((tid & 3) == 0) rids[gj] = rid;
#pragma unroll
    for (int i = 0; i < 4; ++i) {
      int kb = gq + i * 4;
      float4 vd = {0.f, 0.f, 0.f, 0.f};
      if (rid >= 0) vd = *(const float4*)&h1d[(size_t)rid * 64 + kb];
      ushort4 od;
      od.x = f2bf(vd.x); od.y = f2bf(vd.y); od.z = f2bf(vd.z); od.w = f2bf(vd.w);
      *(ushort4*)&Ad_l[gj * 72 + kb] = od;
    }
    __syncthreads();
    f4v Sd[4] = {};
#pragma unroll
    for (int kk = 0; kk < 2; ++kk) {
      s8v ad = *(const s8v*)&Ad_l[(w * 16 + lane16) * 72 + kk * 32 + quad * 8];
#pragma unroll
      for (int nt = 0; nt < 4; ++nt) {
        s8v bd = *(const s8v*)&Bd_l[(nt * 16 + lane16) * 72 + kk * 32 + quad * 8];
        Sd[nt] = MFMA16(ad, bd, Sd[nt]);
      }
    }
#pragma unroll
    for (int nt = 0; nt < 4; ++nt)
#pragma unroll
      for (int r = 0; r < 4; ++r) {
        int rid2 = rids[w * 16 + quad * 4 + r];
        if (rid2 >= 0) {
          float wgt = rw[rid2];
          atomicAdd(&y[(size_t)(rid2 >> 3) * (Gn * Rn) + g * 64 + nt * 16 + lane16],
                    wgt * Sd[nt][r]);
        }
      }
    __syncthreads();
  }
}

// ---------------------------------------------------------------------------
// Combine: out[2048,2048] = y[2048,512] @ B_down-as-[512,2048], MFMA bf16.
// ---------------------------------------------------------------------------
__global__ __launch_bounds__(256) void k_combine(
    const float* __restrict__ y, const unsigned short* __restrict__ BdT,
    float* __restrict__ outp) {
  const int t0 = blockIdx.y * 128, n0 = blockIdx.x * 128;
  __shared__ unsigned short As[128 * 72];
  __shared__ unsigned short Bs[128 * 72];
  const int tid = threadIdx.x;
  const int w = tid >> 6, ln = tid & 63;
  const int quad = ln >> 4, lane16 = ln & 15;
  const int mbase = (w >> 1) * 64, nbase = (w & 1) * 64;

  f4v acc[4][4] = {};

  for (int k0 = 0; k0 < Gn * Rn; k0 += 64) {
#pragma unroll
    for (int i = 0; i < 8; ++i) {
      int c = tid + i * 256;
      int row = c >> 4, cc = (c & 15) * 4;
      float4 v = *(const float4*)&y[(size_t)(t0 + row) * (Gn * Rn) + k0 + cc];
      ushort4 o;
      o.x = f2bf(v.x); o.y = f2bf(v.y); o.z = f2bf(v.z); o.w = f2bf(v.w);
      *(ushort4*)&As[row * 72 + cc] = o;
    }
#pragma unroll
    for (int i = 0; i < 4; ++i) {
      int c = tid + i * 256;
      int row = c >> 3, cc = (c & 7) * 8;
      *(uint4*)&Bs[row * 72 + cc] = *(const uint4*)&BdT[(size_t)(n0 + row) * (Gn * Rn) + k0 + cc];
    }
    __syncthreads();
#pragma unroll
    for (int kk = 0; kk < 2; ++kk) {
      s8v a[4], b[4];
#pragma unroll
      for (int mt = 0; mt < 4; ++mt)
        a[mt] = *(const s8v*)&As[(mbase + mt * 16 + lane16) * 72 + kk * 32 + quad * 8];
#pragma unroll
      for (int nt = 0; nt < 4; ++nt)
        b[nt] = *(const s8v*)&Bs[(nbase + nt * 16 + lane16) * 72 + kk * 32 + quad * 8];
#pragma unroll
      for (int mt = 0; mt < 4; ++mt)
#pragma unroll
        for (int nt = 0; nt < 4; ++nt)
          acc[mt][nt] = MFMA16(a[mt], b[nt], acc[mt][nt]);
    }
    __syncthreads();
  }
#pragma unroll
  for (int mt = 0; mt < 4; ++mt)
#pragma unroll
    for (int nt = 0; nt < 4; ++nt)
#pragma unroll
      for (int r = 0; r < 4; ++r)
        outp[(size_t)(t0 + mbase + mt * 16 + quad * 4 + r) * Dn +
             n0 + nbase + nt * 16 + lane16] = acc[mt][nt][r];
}

// ---------------------------------------------------------------------------
extern "C" void kernel_launch(void* const* d_in, const int* in_sizes, int n_in,
                              void* d_out, int out_size, void* d_ws, size_t ws_size,
                              hipStream_t stream) {
  const float* hidden = (const float*)d_in[0];
  const float* w_gate = (const float*)d_in[1];
  const float* A_gate = (const float*)d_in[2];
  const float* C_gate = (const float*)d_in[3];
  const float* B_gate = (const float*)d_in[4];
  const float* A_up   = (const float*)d_in[5];
  const float* C_up   = (const float*)d_in[6];
  const float* B_up   = (const float*)d_in[7];
  const float* A_down = (const float*)d_in[8];
  const float* C_down = (const float*)d_in[9];
  const float* B_down = (const float*)d_in[10];
  float* out = (float*)d_out;

  // Workspace layout (peak unchanged, 34.34 MB). Router-stage {part 12.6MB
  // (KS_R=6), hq 16.8MB, wqT 2.1MB} = 31.5MB overlay [0, 31.5MB), all dead
  // after k_topk and below the persistent smalls at 33.69MB. Hbf aliases
  // h1d+y (written after router stage, dead before h1d/y memsets).
  char* base = (char*)d_ws;
  size_t o = 0;
  unsigned short* h2gb = (unsigned short*)(base + o); o += (size_t)NROWS * Rn * 2;
  unsigned short* h2ub = (unsigned short*)(base + o); o += (size_t)NROWS * Rn * 2;
  unsigned short* AgT  = (unsigned short*)(base + o); o += (size_t)Gn * Rn * Dn * 2;
  unsigned short* AuT  = (unsigned short*)(base + o); o += (size_t)Gn * Rn * Dn * 2;
  unsigned short* BgT  = (unsigned short*)(base + o); o += (size_t)Gn * In * Rn * 2;
  unsigned short* BuT  = (unsigned short*)(base + o); o += (size_t)Gn * In * Rn * 2;
  unsigned short* AdT  = (unsigned short*)(base + o); o += (size_t)Gn * Rn * In * 2;
  unsigned short* BdT  = (unsigned short*)(base + o); o += (size_t)Dn * Gn * Rn * 2;
  unsigned short* CgT  = (unsigned short*)(base + o); o += (size_t)En * Rn * Rn * 2;
  unsigned short* CuT  = (unsigned short*)(base + o); o += (size_t)En * Rn * Rn * 2;
  unsigned short* CdT  = (unsigned short*)(base + o); o += (size_t)En * Rn * Rn * 2;
  unsigned short* h1gb = (unsigned short*)(base + o); o += (size_t)T0n * Gn * Rn * 2;
  unsigned short* h1ub = (unsigned short*)(base + o); o += (size_t)T0n * Gn * Rn * 2;
  float* h1d = (float*)(base + o); o += (size_t)NROWS * Rn * 4;
  float* y   = (float*)(base + o); o += (size_t)T0n * Gn * Rn * 4;
  // ---- persistent smalls ----
  float* rwp = (float*)(base + o); o += (size_t)NROWS * 4;
  int* sel   = (int*)(base + o); o += (size_t)NROWS * 4;
  int* rseg  = (int*)(base + o); o += (size_t)Gn * SEGCAP * 4;
  int* cnt_e = (int*)(base + o); o += En * 4;
  int* off_e = (int*)(base + o); o += En * 4;
  int* cur_e = (int*)(base + o); o += En * 4;
  int* grp_n = (int*)(base + o); o += Gn * 4;
  // ---- router-stage aliases (dead after k_topk), inside [0, 31.5MB) ----
  float* part = (float*)base;                              // 6*2048*256*4 = 12,582,912
  char* hq  = base + (size_t)KS_R * T0n * En * 4;          // +16,777,216 (4 i8 planes)
  char* wqT = hq + (size_t)4 * T0n * Dn;                   // +2,097,152  (4 i8 planes, T)
  // ---- Hbf alias: h1d (4.19MB) + y (4.19MB) = exactly T0n*Dn*2 bytes ----
  unsigned short* Hbf = (unsigned short*)h1d;

  hipMemsetAsync(cnt_e, 0, En * sizeof(int), stream);

  // 1) quantize inputs to exact 4x-i8 fixed-point limbs
  k_quant_h<<<T0n * Dn / 1024, 256, 0, stream>>>(hidden, hq);
  k_quant_wT<<<dim3(Dn / 32, En / 32), 256, 0, stream>>>(w_gate, wqT);
  // 2) router logits via i32-MFMA limb GEMM (s>=3 pairs, split-K=6)
  k_router_i8<<<dim3(En / 64, T0n / 64, KS_R), 256, 0, stream>>>(hq, wqT, part);
  // 3) top-8 + renorm + expert counts
  k_topk<<<T0n / 4, 256, 0, stream>>>(part, sel, rwp, cnt_e);
  // 4) offsets (parallel prefix) + scatter rows by expert
  k_scan<<<1, 256, 0, stream>>>(cnt_e, off_e, cur_e, grp_n);
  k_scatter<<<NROWS / 256, 256, 0, stream>>>(sel, cur_e, rseg);

  // part/hq/wqT now dead. Convert H to bf16 once (into the h1d+y alias).
  k_hcvt<<<T0n * Dn / 2048, 256, 0, stream>>>(hidden, Hbf);

  // 5) transpose+convert all 9 weight tensors to bf16 operand layouts
  {
    TD9 D;
    D.t[0] = {A_gate, AgT, Dn, Rn, Rn / 32, (Rn / 32) * (Dn / 32), 0};
    D.t[1] = {A_up,   AuT, Dn, Rn, Rn / 32, (Rn / 32) * (Dn / 32), 1024};
    D.t[2] = {B_gate, BgT, Rn, In, In / 32, (In / 32) * (Rn / 32), 2048};
    D.t[3] = {B_up,   BuT, Rn, In, In / 32, (In / 32) * (Rn / 32), 2752};
    D.t[4] = {A_down, AdT, In, Rn, Rn / 32, (Rn / 32) * (In / 32), 3456};
    D.t[5] = {B_down, BdT, Gn * Rn, Dn, Dn / 32, (Dn / 32) * (Gn * Rn / 32), 4160};
    D.t[6] = {C_gate, CgT, Rn, Rn, 2, 4, 5184};
    D.t[7] = {C_up,   CuT, Rn, Rn, 2, 4, 6208};
    D.t[8] = {C_down, CdT, Rn, Rn, 2, 4, 7232};
    k_tcvt9<<<8256, 256, 0, stream>>>(D);
  }

  // 6) dense in-factor projections (bf16 H from Hbf)
  k_h1_mfma<<<dim3(T0n / 64, Gn), 512, 0, stream>>>(Hbf, AgT, AuT, h1gb, h1ub);

  // Hbf dead; reclaim h1d + y.
  hipMemsetAsync(h1d, 0, (size_t)NROWS * Rn * sizeof(float), stream);
  hipMemsetAsync(y,   0, (size_t)T0n * Gn * Rn * sizeof(float), stream);

  // 7) per-expert core (gate/up) via MFMA (512 thr path-split)
  k_core_gu<<<En, 512, 0, stream>>>(h1gb, h1ub, CgT, CuT,
                                    rseg, off_e, cnt_e, h2gb, h2ub);
  // 8) fused expand + down-A (8-wave/256-row + T14 register prefetch)
  k_expand_mfma<<<dim3(NTILE2_MAX, 4), 512, 0, stream>>>(
      h2gb, h2ub, BgT, BuT, AdT, rseg, grp_n, h1d);
  // 9) per-expert down core via MFMA + rw (512 thr, 128 rows/iter)
  k_core_down<<<En, 512, 0, stream>>>(h1d, CdT, rwp,
                                      rseg, off_e, cnt_e, y);
  // 10) combine (MFMA bf16)
  k_combine<<<dim3(Dn / 128, T0n / 128), 256, 0, stream>>>(y, BdT, out);
}

// Round 15
// 290.046 us; speedup vs baseline: 1.1411x; 1.0157x over previous
//
#include <hip/hip_runtime.h>
#include <math.h>

// Problem dims
constexpr int T0n = 2048;   // tokens
constexpr int Dn  = 2048;   // hidden
constexpr int En  = 256;    // experts
constexpr int Gn  = 8;      // groups
constexpr int EGn = 32;     // experts per group
constexpr int Rn  = 64;     // tucker rank
constexpr int In  = 1408;   // intermediate

constexpr int NROWS = T0n * 8;    // 16384 dispatched rows
constexpr int SEGCAP = NROWS;     // per-group segment capacity in rseg
constexpr int KS_R = 6;           // router split-K (i32 exact, uneven split OK)
constexpr int NTILE2_MAX = NROWS / 256 + Gn;   // 72: bound on sum ceil(ng/256)

typedef __attribute__((ext_vector_type(8))) short s8v;    // 8 bf16
typedef __attribute__((ext_vector_type(4))) float f4v;    // 4 fp32
typedef __attribute__((ext_vector_type(4))) int i4v;      // 16 i8 operand / 4 i32 acc
#define MFMA16(a, b, c) __builtin_amdgcn_mfma_f32_16x16x32_bf16(a, b, c, 0, 0, 0)
#define MFMAI8(a, b, c) __builtin_amdgcn_mfma_i32_16x16x64_i8(a, b, c, 0, 0, 0)

__device__ __forceinline__ unsigned short f2bf(float x) {
  unsigned int u = __float_as_uint(x);
  unsigned int r = (u + 0x7FFFu + ((u >> 16) & 1u)) >> 16;
  return (unsigned short)r;
}

// ---------------------------------------------------------------------------
// Fused batched transpose+convert for 9 weight tensors:
// src f32 [batch][rows][cols] -> dst bf16 [batch][cols][rows].
// ---------------------------------------------------------------------------
struct TD { const float* src; unsigned short* dst; int rows, cols, nbx, per_batch, base; };
struct TD9 { TD t[9]; };

__global__ __launch_bounds__(256) void k_tcvt9(TD9 D) {
  __shared__ float tbuf[32][33];
  int id = blockIdx.x;
  int ti = 0;
#pragma unroll
  for (int i = 1; i < 9; ++i) ti = (id >= D.t[i].base) ? i : ti;
  TD d = D.t[ti];
  int local = id - d.base;
  int bz = local / d.per_batch;
  int rem = local - bz * d.per_batch;
  int by = rem / d.nbx;
  int bx = rem - by * d.nbx;

  size_t boff = (size_t)bz * d.rows * d.cols;
  const float* src = d.src + boff;
  unsigned short* dst = d.dst + boff;
  int c0 = bx * 32, r0 = by * 32;
  int tx = threadIdx.x & 31, ty = threadIdx.x >> 5;   // ty 0..7
  for (int i = ty; i < 32; i += 8)
    tbuf[i][tx] = src[(size_t)(r0 + i) * d.cols + c0 + tx];
  __syncthreads();
  for (int i = ty; i < 32; i += 8)
    dst[(size_t)(c0 + i) * d.rows + r0 + tx] = f2bf(tbuf[tx][i]);
}

// ---------------------------------------------------------------------------
// H f32 -> bf16 once. Halves H traffic in k_h1_mfma.
// ---------------------------------------------------------------------------
__global__ __launch_bounds__(256) void k_hcvt(
    const float* __restrict__ H, unsigned short* __restrict__ Hbf) {
  size_t i = ((size_t)blockIdx.x * 256 + threadIdx.x) * 8;
  float4 v0 = *(const float4*)&H[i];
  float4 v1 = *(const float4*)&H[i + 4];
  ushort4 o0, o1;
  o0.x = f2bf(v0.x); o0.y = f2bf(v0.y); o0.z = f2bf(v0.z); o0.w = f2bf(v0.w);
  o1.x = f2bf(v1.x); o1.y = f2bf(v1.y); o1.z = f2bf(v1.z); o1.w = f2bf(v1.w);
  *(ushort4*)&Hbf[i] = o0;
  *(ushort4*)&Hbf[i + 4] = o1;
}

// ---------------------------------------------------------------------------
// ROUTER, fixed-point limb path. Pairs k+l>=3 (10 MFMA). s=3 is NOT
// droppable (~2.6e-6 rms vs token-min top-8 gap ~1.5e-5); s=2 drop verified
// byte-identical absmax (R12 data).
// ---------------------------------------------------------------------------
__device__ __forceinline__ int4 limbs4(float v, double sc) {
  double d = (double)v * sc;           // exact in double
  d = fmin(fmax(d, -2.0e9), 2.0e9);    // clamp (unreachable for this data)
  int x = __double2int_rn(d);
  int l0 = (int)(signed char)(x & 0xff); x = (x - l0) >> 8;   // exact
  int l1 = (int)(signed char)(x & 0xff); x = (x - l1) >> 8;
  int l2 = (int)(signed char)(x & 0xff); x = (x - l2) >> 8;
  return make_int4(l0, l1, l2, x);     // x fits i8
}

// hidden [2048][2048] f32 -> hq planes [4][2048][2048] i8 (limb-major).
__global__ __launch_bounds__(256) void k_quant_h(
    const float* __restrict__ H, char* __restrict__ hq) {
  const size_t PL = (size_t)T0n * Dn;
  size_t i = (size_t)blockIdx.x * 256 + threadIdx.x;   // group of 4 elements
  float4 v = *(const float4*)&H[i * 4];
  int4 a = limbs4(v.x, 268435456.0);   // 2^28
  int4 b = limbs4(v.y, 268435456.0);
  int4 c = limbs4(v.z, 268435456.0);
  int4 d = limbs4(v.w, 268435456.0);
  unsigned int p0 = (a.x & 0xff) | ((b.x & 0xff) << 8) | ((c.x & 0xff) << 16) | ((unsigned)(d.x & 0xff) << 24);
  unsigned int p1 = (a.y & 0xff) | ((b.y & 0xff) << 8) | ((c.y & 0xff) << 16) | ((unsigned)(d.y & 0xff) << 24);
  unsigned int p2 = (a.z & 0xff) | ((b.z & 0xff) << 8) | ((c.z & 0xff) << 16) | ((unsigned)(d.z & 0xff) << 24);
  unsigned int p3 = (a.w & 0xff) | ((b.w & 0xff) << 8) | ((c.w & 0xff) << 16) | ((unsigned)(d.w & 0xff) << 24);
  *(unsigned int*)&hq[0 * PL + i * 4] = p0;
  *(unsigned int*)&hq[1 * PL + i * 4] = p1;
  *(unsigned int*)&hq[2 * PL + i * 4] = p2;
  *(unsigned int*)&hq[3 * PL + i * 4] = p3;
}

// w_gate [2048][256] f32 -> wqT planes [4][256][2048] i8 (transposed, limb-major).
__global__ __launch_bounds__(256) void k_quant_wT(
    const float* __restrict__ W, char* __restrict__ wqT) {
  __shared__ float tb[32][33];
  const size_t PL = (size_t)En * Dn;
  int kb = blockIdx.x * 32, nb = blockIdx.y * 32;
  int tx = threadIdx.x & 31, ty = threadIdx.x >> 5;
  for (int i = ty; i < 32; i += 8)
    tb[i][tx] = W[(size_t)(kb + i) * En + nb + tx];
  __syncthreads();
  for (int i = ty; i < 32; i += 8) {
    int4 l = limbs4(tb[tx][i], 8589934592.0);   // 2^33
    size_t off = (size_t)(nb + i) * Dn + kb + tx;
    wqT[0 * PL + off] = (char)l.x;
    wqT[1 * PL + off] = (char)l.y;
    wqT[2 * PL + off] = (char)l.z;
    wqT[3 * PL + off] = (char)l.w;
  }
}

// i8 MFMA router GEMM. 10 MFMA/step (s>=3), KS_R=6 (uneven split).
// grid (En/64, T0n/64, KS_R).
__global__ __launch_bounds__(256) void k_router_i8(
    const char* __restrict__ hq, const char* __restrict__ wqT,
    float* __restrict__ part) {
  __shared__ __align__(16) char Asl[4][64][80];   // [limb][m-row][k]
  __shared__ __align__(16) char Bsl[4][64][80];   // [limb][n-row][k]
  const int n0 = blockIdx.x * 64, m0 = blockIdx.y * 64;
  const int kc = blockIdx.z;
  const int tid = threadIdx.x;
  const int w = tid >> 6, ln = tid & 63;
  const int quad = ln >> 4, lane16 = ln & 15;

  const char* ha = hq + ((size_t)w * T0n + m0 + ln) * Dn;   // plane w, row m0+ln
  const char* ba = wqT + ((size_t)w * En + n0 + ln) * Dn;   // plane w, row n0+ln

  i4v acc[4][4] = {};   // [m-tile][s-group s=k+l-3, s in 3..6]

  // Uneven K-split over 32 steps of 64: kc gets steps [kc*32/6,(kc+1)*32/6).
  const int kbeg = ((kc * 32) / KS_R) * 64;
  const int kend = (((kc + 1) * 32) / KS_R) * 64;
  for (int k0 = kbeg; k0 < kend; k0 += 64) {
#pragma unroll
    for (int q = 0; q < 4; ++q) {
      *(uint4*)&Asl[w][ln][q * 16] = *(const uint4*)&ha[k0 + q * 16];
      *(uint4*)&Bsl[w][ln][q * 16] = *(const uint4*)&ba[k0 + q * 16];
    }
    __syncthreads();
    i4v b0 = *(const i4v*)&Bsl[0][w * 16 + lane16][quad * 16];
    i4v b1 = *(const i4v*)&Bsl[1][w * 16 + lane16][quad * 16];
    i4v b2 = *(const i4v*)&Bsl[2][w * 16 + lane16][quad * 16];
    i4v b3 = *(const i4v*)&Bsl[3][w * 16 + lane16][quad * 16];
#pragma unroll
    for (int mt = 0; mt < 4; ++mt) {
      i4v a0 = *(const i4v*)&Asl[0][mt * 16 + lane16][quad * 16];
      i4v a1 = *(const i4v*)&Asl[1][mt * 16 + lane16][quad * 16];
      i4v a2 = *(const i4v*)&Asl[2][mt * 16 + lane16][quad * 16];
      i4v a3 = *(const i4v*)&Asl[3][mt * 16 + lane16][quad * 16];
      // s = 3
      acc[mt][0] = MFMAI8(a0, b3, acc[mt][0]);
      acc[mt][0] = MFMAI8(a1, b2, acc[mt][0]);
      acc[mt][0] = MFMAI8(a2, b1, acc[mt][0]);
      acc[mt][0] = MFMAI8(a3, b0, acc[mt][0]);
      // s = 4
      acc[mt][1] = MFMAI8(a1, b3, acc[mt][1]);
      acc[mt][1] = MFMAI8(a2, b2, acc[mt][1]);
      acc[mt][1] = MFMAI8(a3, b1, acc[mt][1]);
      // s = 5
      acc[mt][2] = MFMAI8(a2, b3, acc[mt][2]);
      acc[mt][2] = MFMAI8(a3, b2, acc[mt][2]);
      // s = 6
      acc[mt][3] = MFMAI8(a3, b3, acc[mt][3]);
    }
    __syncthreads();
  }

  // Combine 4 exact i32 sums at scales 2^(8s-61), s=3..6.
  float* prow = part + (size_t)kc * T0n * En;
#pragma unroll
  for (int mt = 0; mt < 4; ++mt)
#pragma unroll
    for (int r = 0; r < 4; ++r) {
      int row = m0 + mt * 16 + quad * 4 + r;
      int col = n0 + w * 16 + lane16;
      double v = (double)acc[mt][0][r] * 0x1p-37 +
                 (double)acc[mt][1][r] * 0x1p-29 +
                 (double)acc[mt][2][r] * 0x1p-21 +
                 (double)acc[mt][3][r] * 0x1p-13;
      prow[(size_t)row * En + col] = (float)v;
    }
}

// ---------------------------------------------------------------------------
// Top-8: one wave per token, shuffle butterfly. Sums KS_R fp32 partials in fp64.
// ---------------------------------------------------------------------------
__global__ __launch_bounds__(256) void k_topk(
    const float* __restrict__ part, int* __restrict__ sel,
    float* __restrict__ rw, int* __restrict__ cnt_e) {
  const int wid = threadIdx.x >> 6, ln = threadIdx.x & 63;
  const int t = blockIdx.x * 4 + wid;

  double v[4];
#pragma unroll
  for (int j = 0; j < 4; ++j) {
    double s = 0.0;
#pragma unroll
    for (int kc = 0; kc < KS_R; ++kc)
      s += (double)part[((size_t)kc * T0n + t) * En + ln + 64 * j];
    v[j] = s;
  }

  float topv[8];
  int topi[8];
#pragma unroll
  for (int k = 0; k < 8; ++k) {
    double bv = v[0]; int bi = ln;
#pragma unroll
    for (int j = 1; j < 4; ++j) {
      int cand = ln + 64 * j;
      if (v[j] > bv || (v[j] == bv && cand < bi)) { bv = v[j]; bi = cand; }
    }
#pragma unroll
    for (int off = 32; off > 0; off >>= 1) {
      double ov = __shfl_xor(bv, off);
      int oi = __shfl_xor(bi, off);
      if (ov > bv || (ov == bv && oi < bi)) { bv = ov; bi = oi; }
    }
    topv[k] = (float)bv; topi[k] = bi;
    if ((bi & 63) == ln) v[bi >> 6] = -1e300;
  }

  if (ln < 8) {
    float m = topv[0];
    float ssum = 0.f;
#pragma unroll
    for (int k = 0; k < 8; ++k) ssum += expf(topv[k] - m);
    rw[t * 8 + ln] = expf(topv[ln] - m) / ssum;
    sel[t * 8 + ln] = topi[ln];
    atomicAdd(&cnt_e[topi[ln]], 1);
  }
}

// Parallel per-group prefix over 256 experts.
__global__ __launch_bounds__(256) void k_scan(
    const int* __restrict__ cnt_e, int* __restrict__ off_e,
    int* __restrict__ cur_e, int* __restrict__ grp_n) {
  __shared__ int c[256];
  int tid = threadIdx.x;
  c[tid] = cnt_e[tid];
  __syncthreads();
  int g = tid >> 5, ei = tid & 31;
  int run = 0;
  for (int i = 0; i < ei; ++i) run += c[(g << 5) + i];
  off_e[tid] = g * SEGCAP + run;
  cur_e[tid] = g * SEGCAP + run;
  if (ei == 31) grp_n[g] = run + c[tid];
}

__global__ void k_scatter(const int* __restrict__ sel, int* __restrict__ cur_e,
                          int* __restrict__ rseg) {
  int i = blockIdx.x * 256 + threadIdx.x;
  int e = sel[i];
  int pos = atomicAdd(&cur_e[e], 1);
  rseg[pos] = i;
}

// ---------------------------------------------------------------------------
// h1 = H @ A_fac[g]. bf16 H (k_hcvt). R19: T14 register prefetch applied to
// the 32-step K-loop (same twice-verified transform as expand R18): publish
// staged regs -> LDS, barrier, issue k0+64 loads, MFMA, barrier. +12 VGPR,
// far from the 128 cliff. 512 threads: waves 0-3 gate, 4-7 up. grid (T0/64,G).
// ---------------------------------------------------------------------------
__global__ __launch_bounds__(512) void k_h1_mfma(
    const unsigned short* __restrict__ Hbf,
    const unsigned short* __restrict__ AgT, const unsigned short* __restrict__ AuT,
    unsigned short* __restrict__ h1gb, unsigned short* __restrict__ h1ub) {
  const int t0 = blockIdx.x * 64;
  const int g = blockIdx.y;
  const unsigned short* Wg = AgT + (size_t)g * Rn * Dn;
  const unsigned short* Wu = AuT + (size_t)g * Rn * Dn;

  __shared__ unsigned short As[64 * 72];
  __shared__ unsigned short Bg_l[64 * 72];
  __shared__ unsigned short Bu_l[64 * 72];
  const int tid = threadIdx.x;
  const int w = tid >> 6, ln = tid & 63;
  const int path = w >> 2, ws = w & 3;
  const int quad = ln >> 4, lane16 = ln & 15;
  const int j = tid >> 3, q = (tid & 7) * 8;   // 64 rows x 8 chunks

  f4v S[4] = {};

  // T14 prologue: stage k0=0 into registers.
  uint4 sH, sG, sU;
  {
    sH = *(const uint4*)&Hbf[(size_t)(t0 + j) * Dn + q];
    sG = *(const uint4*)&Wg[(size_t)j * Dn + q];
    sU = *(const uint4*)&Wu[(size_t)j * Dn + q];
  }

  for (int k0 = 0; k0 < Dn; k0 += 64) {
    // Publish staged tile (vmcnt wait covered by previous iter's compute).
    *(uint4*)&As[j * 72 + q] = sH;
    *(uint4*)&Bg_l[j * 72 + q] = sG;
    *(uint4*)&Bu_l[j * 72 + q] = sU;
    __syncthreads();

    // Issue next K-step's loads; latency hides under the MFMAs below.
    if (k0 + 64 < Dn) {
      sH = *(const uint4*)&Hbf[(size_t)(t0 + j) * Dn + k0 + 64 + q];
      sG = *(const uint4*)&Wg[(size_t)j * Dn + k0 + 64 + q];
      sU = *(const uint4*)&Wu[(size_t)j * Dn + k0 + 64 + q];
    }

    const unsigned short* Bl = path ? Bu_l : Bg_l;
#pragma unroll
    for (int kk = 0; kk < 2; ++kk) {
      s8v a = *(const s8v*)&As[(ws * 16 + lane16) * 72 + kk * 32 + quad * 8];
#pragma unroll
      for (int nt = 0; nt < 4; ++nt) {
        s8v b = *(const s8v*)&Bl[(nt * 16 + lane16) * 72 + kk * 32 + quad * 8];
        S[nt] = MFMA16(a, b, S[nt]);
      }
    }
    __syncthreads();
  }
  unsigned short* out = path ? h1ub : h1gb;
#pragma unroll
  for (int nt = 0; nt < 4; ++nt)
#pragma unroll
    for (int r = 0; r < 4; ++r) {
      int row = t0 + ws * 16 + quad * 4 + r;
      int col = g * 64 + nt * 16 + lane16;
      out[(size_t)row * (Gn * Rn) + col] = f2bf(S[nt][r]);
    }
}

// ---------------------------------------------------------------------------
// Per-expert core (gate/up) via MFMA. 512 threads: waves 0-3 gate, 4-7 up.
// ---------------------------------------------------------------------------
__global__ __launch_bounds__(512) void k_core_gu(
    const unsigned short* __restrict__ h1gb, const unsigned short* __restrict__ h1ub,
    const unsigned short* __restrict__ CgT, const unsigned short* __restrict__ CuT,
    const int* __restrict__ rseg, const int* __restrict__ off_e,
    const int* __restrict__ cnt_e,
    unsigned short* __restrict__ h2gb, unsigned short* __restrict__ h2ub) {
  const int e = blockIdx.x;
  const int ne = cnt_e[e];
  if (ne == 0) return;
  const int g = e >> 5;
  const int base = off_e[e];
  __shared__ unsigned short Cg_l[64 * 72];
  __shared__ unsigned short Cu_l[64 * 72];
  __shared__ unsigned short Ags[64 * 72];
  __shared__ unsigned short Aus[64 * 72];
  __shared__ int rids[64];
  const int tid = threadIdx.x;
  const int w = tid >> 6, ln = tid & 63;
  const int path = w >> 2, ws = w & 3;
  const int quad = ln >> 4, lane16 = ln & 15;
  const int j = tid >> 3, q = (tid & 7) * 8;
  {
    const unsigned short* cg = CgT + (size_t)e * (Rn * Rn);
    const unsigned short* cu = CuT + (size_t)e * (Rn * Rn);
    *(uint4*)&Cg_l[j * 72 + q] = *(const uint4*)&cg[j * 64 + q];
    *(uint4*)&Cu_l[j * 72 + q] = *(const uint4*)&cu[j * 64 + q];
  }
  const int ntile = (ne + 63) >> 6;
  for (int it = 0; it < ntile; ++it) {
    int mi = it * 64 + j;
    int rid = (mi < ne) ? rseg[base + mi] : -1;
    if ((tid & 7) == 0) rids[j] = rid;
    uint4 zg = {0, 0, 0, 0}, zu = {0, 0, 0, 0};
    if (rid >= 0) {
      zg = *(const uint4*)&h1gb[(size_t)(rid >> 3) * (Gn * Rn) + g * 64 + q];
      zu = *(const uint4*)&h1ub[(size_t)(rid >> 3) * (Gn * Rn) + g * 64 + q];
    }
    *(uint4*)&Ags[j * 72 + q] = zg;
    *(uint4*)&Aus[j * 72 + q] = zu;
    __syncthreads();
    const unsigned short* Al = path ? Aus : Ags;
    const unsigned short* Cl = path ? Cu_l : Cg_l;
    f4v S[4] = {};
#pragma unroll
    for (int kk = 0; kk < 2; ++kk) {
      s8v a = *(const s8v*)&Al[(ws * 16 + lane16) * 72 + kk * 32 + quad * 8];
#pragma unroll
      for (int nt = 0; nt < 4; ++nt) {
        s8v b = *(const s8v*)&Cl[(nt * 16 + lane16) * 72 + kk * 32 + quad * 8];
        S[nt] = MFMA16(a, b, S[nt]);
      }
    }
    unsigned short* out = path ? h2ub : h2gb;
#pragma unroll
    for (int nt = 0; nt < 4; ++nt)
#pragma unroll
      for (int r = 0; r < 4; ++r) {
        int rid2 = rids[ws * 16 + quad * 4 + r];
        if (rid2 >= 0)
          out[(size_t)rid2 * 64 + nt * 16 + lane16] = f2bf(S[nt][r]);
      }
    __syncthreads();
  }
}

// ---------------------------------------------------------------------------
// Fused expand + down-A via MFMA. 8-wave/256-row (R17) + T14 register
// prefetch (R18, verified: 44 -> <42us). VGPR ~96-100, 4 waves/SIMD.
// ---------------------------------------------------------------------------
__global__ __launch_bounds__(512) void k_expand_mfma(
    const unsigned short* __restrict__ h2gb, const unsigned short* __restrict__ h2ub,
    const unsigned short* __restrict__ BgT, const unsigned short* __restrict__ BuT,
    const unsigned short* __restrict__ AdT,
    const int* __restrict__ rseg, const int* __restrict__ grp_n,
    float* __restrict__ h1d) {
  // Decode flat 256-row tile id -> (g, m0) via prefix over per-group counts.
  int t = blockIdx.x;
  int g = -1, m0 = 0, ng = 0;
  {
    int pre = 0;
#pragma unroll
    for (int gg = 0; gg < Gn; ++gg) {
      int n = grp_n[gg];
      int nt = (n + 255) >> 8;
      if (g < 0 && t < pre + nt) { g = gg; m0 = (t - pre) << 8; ng = n; }
      pre += nt;
    }
  }
  if (g < 0) return;
  const int c_beg = blockIdx.y * 6;
  const int c_end = min(22, c_beg + 6);

  __shared__ unsigned short Bg_l[64 * 72];
  __shared__ unsigned short Bu_l[64 * 72];
  __shared__ unsigned short Ad_l[64 * 72];
  __shared__ unsigned short inter_l[8][32 * 72];   // per-wave private
  __shared__ int rids[256];

  const int tid = threadIdx.x;
  const int w = tid >> 6, ln = tid & 63;   // w in 0..7
  const int quad = ln >> 4, lane16 = ln & 15;

  if (tid < 256) rids[tid] = (m0 + tid < ng) ? rseg[g * SEGCAP + m0 + tid] : -1;
  __syncthreads();

  // H gate/up fragments in registers: wave w owns rows w*32..w*32+31.
  s8v ag[2][2], au[2][2];
#pragma unroll
  for (int mt = 0; mt < 2; ++mt) {
    int rid = rids[w * 32 + mt * 16 + lane16];
#pragma unroll
    for (int kk = 0; kk < 2; ++kk) {
      s8v zg = {}, zu = {};
      if (rid >= 0) {
        zg = *(const s8v*)&h2gb[(size_t)rid * 64 + kk * 32 + quad * 8];
        zu = *(const s8v*)&h2ub[(size_t)rid * 64 + kk * 32 + quad * 8];
      }
      ag[mt][kk] = zg;
      au[mt][kk] = zu;
    }
  }

  const unsigned short* Bg_base = BgT + (size_t)g * In * Rn;
  const unsigned short* Bu_base = BuT + (size_t)g * In * Rn;
  const unsigned short* Ad_base = AdT + (size_t)g * Rn * In;

  unsigned short* ib = &inter_l[w][0];
  f4v P[2][4] = {};
  const int srow = tid >> 3, sco = (tid & 7) * 8;   // 512 thr: 64 rows x 8 cols

  // T14 prologue: stage first chunk into registers.
  uint4 sg, su, sd;
  {
    const int i0 = c_beg * 64;
    sg = *(const uint4*)&Bg_base[(size_t)(i0 + srow) * Rn + sco];
    su = *(const uint4*)&Bu_base[(size_t)(i0 + srow) * Rn + sco];
    sd = *(const uint4*)&Ad_base[(size_t)srow * In + i0 + sco];
  }

  for (int c = c_beg; c < c_end; ++c) {
    // Publish staged tiles (implicit vmcnt wait lands here, covered by the
    // previous iteration's compute).
    *(uint4*)&Bg_l[srow * 72 + sco] = sg;
    *(uint4*)&Bu_l[srow * 72 + sco] = su;
    *(uint4*)&Ad_l[srow * 72 + sco] = sd;
    __syncthreads();   // B tiles ready

    // Issue next chunk's loads; latency hides under the compute below.
    if (c + 1 < c_end) {
      const int i1 = (c + 1) * 64;
      sg = *(const uint4*)&Bg_base[(size_t)(i1 + srow) * Rn + sco];
      su = *(const uint4*)&Bu_base[(size_t)(i1 + srow) * Rn + sco];
      sd = *(const uint4*)&Ad_base[(size_t)srow * In + i1 + sco];
    }

    f4v Sg[2][4] = {}, Su[2][4] = {};
#pragma unroll
    for (int kk = 0; kk < 2; ++kk) {
      s8v bg[4], bu[4];
#pragma unroll
      for (int nt = 0; nt < 4; ++nt) {
        bg[nt] = *(const s8v*)&Bg_l[(nt * 16 + lane16) * 72 + kk * 32 + quad * 8];
        bu[nt] = *(const s8v*)&Bu_l[(nt * 16 + lane16) * 72 + kk * 32 + quad * 8];
      }
#pragma unroll
      for (int mt = 0; mt < 2; ++mt)
#pragma unroll
        for (int nt = 0; nt < 4; ++nt) {
          Sg[mt][nt] = MFMA16(ag[mt][kk], bg[nt], Sg[mt][nt]);
          Su[mt][nt] = MFMA16(au[mt][kk], bu[nt], Su[mt][nt]);
        }
    }

    // silu(gate)*up -> per-wave inter region. No barrier: wave-local W->R.
#pragma unroll
    for (int mt = 0; mt < 2; ++mt)
#pragma unroll
      for (int nt = 0; nt < 4; ++nt)
#pragma unroll
        for (int r = 0; r < 4; ++r) {
          float sg2 = Sg[mt][nt][r];
          float v = sg2 / (1.f + __expf(-sg2)) * Su[mt][nt][r];
          ib[(mt * 16 + quad * 4 + r) * 72 + nt * 16 + lane16] = f2bf(v);
        }
    asm volatile("s_waitcnt lgkmcnt(0)" ::: "memory");   // wave-local W->R order

#pragma unroll
    for (int kk = 0; kk < 2; ++kk) {
      s8v ai[2], bd[4];
#pragma unroll
      for (int mt = 0; mt < 2; ++mt)
        ai[mt] = *(const s8v*)&ib[(mt * 16 + lane16) * 72 + kk * 32 + quad * 8];
#pragma unroll
      for (int nt = 0; nt < 4; ++nt)
        bd[nt] = *(const s8v*)&Ad_l[(nt * 16 + lane16) * 72 + kk * 32 + quad * 8];
#pragma unroll
      for (int mt = 0; mt < 2; ++mt)
#pragma unroll
        for (int nt = 0; nt < 4; ++nt)
          P[mt][nt] = MFMA16(ai[mt], bd[nt], P[mt][nt]);
    }
    __syncthreads();   // B tiles consumed; safe to overwrite next iteration
  }

#pragma unroll
  for (int mt = 0; mt < 2; ++mt)
#pragma unroll
    for (int nt = 0; nt < 4; ++nt)
#pragma unroll
      for (int r = 0; r < 4; ++r) {
        int lrow = w * 32 + mt * 16 + quad * 4 + r;
        int rid = rids[lrow];
        if (rid >= 0)
          atomicAdd(&h1d[(size_t)rid * 64 + nt * 16 + lane16], P[mt][nt][r]);
      }
}

// ---------------------------------------------------------------------------
// Per-expert down core via MFMA + routing weight, reduce to y[t,g,64].
// 512 threads: 128 rows/iter.
// ---------------------------------------------------------------------------
__global__ __launch_bounds__(512) void k_core_down(
    const float* __restrict__ h1d, const unsigned short* __restrict__ CdT,
    const float* __restrict__ rw,
    const int* __restrict__ rseg, const int* __restrict__ off_e,
    const int* __restrict__ cnt_e,
    float* __restrict__ y) {
  const int e = blockIdx.x;
  const int ne = cnt_e[e];
  if (ne == 0) return;
  const int g = e >> 5;
  const int base = off_e[e];
  __shared__ unsigned short Bd_l[64 * 72];
  __shared__ unsigned short Ad_l[128 * 72];
  __shared__ int rids[128];
  const int tid = threadIdx.x;
  const int w = tid >> 6, ln = tid & 63;
  const int quad = ln >> 4, lane16 = ln & 15;
  {
    int j = tid >> 3, q = (tid & 7) * 8;
    const unsigned short* cd = CdT + (size_t)e * (Rn * Rn);
    *(uint4*)&Bd_l[j * 72 + q] = *(const uint4*)&cd[j * 64 + q];
  }
  const int gj = tid >> 2, gq = (tid & 3) * 16;   // 128 rows x 4 chunks of 16
  const int ntile = (ne + 127) >> 7;
  for (int it = 0; it < ntile; ++it) {
    int mi = it * 128 + gj;
    int rid = (mi < ne) ? rseg[base + mi] : -1;
    if ((tid & 3) == 0) rids[gj] = rid;
#pragma unroll
    for (int i = 0; i < 4; ++i) {
      int kb = gq + i * 4;
      float4 vd = {0.f, 0.f, 0.f, 0.f};
      if (rid >= 0) vd = *(const float4*)&h1d[(size_t)rid * 64 + kb];
      ushort4 od;
      od.x = f2bf(vd.x); od.y = f2bf(vd.y); od.z = f2bf(vd.z); od.w = f2bf(vd.w);
      *(ushort4*)&Ad_l[gj * 72 + kb] = od;
    }
    __syncthreads();
    f4v Sd[4] = {};
#pragma unroll
    for (int kk = 0; kk < 2; ++kk) {
      s8v ad = *(const s8v*)&Ad_l[(w * 16 + lane16) * 72 + kk * 32 + quad * 8];
#pragma unroll
      for (int nt = 0; nt < 4; ++nt) {
        s8v bd = *(const s8v*)&Bd_l[(nt * 16 + lane16) * 72 + kk * 32 + quad * 8];
        Sd[nt] = MFMA16(ad, bd, Sd[nt]);
      }
    }
#pragma unroll
    for (int nt = 0; nt < 4; ++nt)
#pragma unroll
      for (int r = 0; r < 4; ++r) {
        int rid2 = rids[w * 16 + quad * 4 + r];
        if (rid2 >= 0) {
          float wgt = rw[rid2];
          atomicAdd(&y[(size_t)(rid2 >> 3) * (Gn * Rn) + g * 64 + nt * 16 + lane16],
                    wgt * Sd[nt][r]);
        }
      }
    __syncthreads();
  }
}

// ---------------------------------------------------------------------------
// Combine: out[2048,2048] = y[2048,512] @ B_down-as-[512,2048], MFMA bf16.
// ---------------------------------------------------------------------------
__global__ __launch_bounds__(256) void k_combine(
    const float* __restrict__ y, const unsigned short* __restrict__ BdT,
    float* __restrict__ outp) {
  const int t0 = blockIdx.y * 128, n0 = blockIdx.x * 128;
  __shared__ unsigned short As[128 * 72];
  __shared__ unsigned short Bs[128 * 72];
  const int tid = threadIdx.x;
  const int w = tid >> 6, ln = tid & 63;
  const int quad = ln >> 4, lane16 = ln & 15;
  const int mbase = (w >> 1) * 64, nbase = (w & 1) * 64;

  f4v acc[4][4] = {};

  for (int k0 = 0; k0 < Gn * Rn; k0 += 64) {
#pragma unroll
    for (int i = 0; i < 8; ++i) {
      int c = tid + i * 256;
      int row = c >> 4, cc = (c & 15) * 4;
      float4 v = *(const float4*)&y[(size_t)(t0 + row) * (Gn * Rn) + k0 + cc];
      ushort4 o;
      o.x = f2bf(v.x); o.y = f2bf(v.y); o.z = f2bf(v.z); o.w = f2bf(v.w);
      *(ushort4*)&As[row * 72 + cc] = o;
    }
#pragma unroll
    for (int i = 0; i < 4; ++i) {
      int c = tid + i * 256;
      int row = c >> 3, cc = (c & 7) * 8;
      *(uint4*)&Bs[row * 72 + cc] = *(const uint4*)&BdT[(size_t)(n0 + row) * (Gn * Rn) + k0 + cc];
    }
    __syncthreads();
#pragma unroll
    for (int kk = 0; kk < 2; ++kk) {
      s8v a[4], b[4];
#pragma unroll
      for (int mt = 0; mt < 4; ++mt)
        a[mt] = *(const s8v*)&As[(mbase + mt * 16 + lane16) * 72 + kk * 32 + quad * 8];
#pragma unroll
      for (int nt = 0; nt < 4; ++nt)
        b[nt] = *(const s8v*)&Bs[(nbase + nt * 16 + lane16) * 72 + kk * 32 + quad * 8];
#pragma unroll
      for (int mt = 0; mt < 4; ++mt)
#pragma unroll
        for (int nt = 0; nt < 4; ++nt)
          acc[mt][nt] = MFMA16(a[mt], b[nt], acc[mt][nt]);
    }
    __syncthreads();
  }
#pragma unroll
  for (int mt = 0; mt < 4; ++mt)
#pragma unroll
    for (int nt = 0; nt < 4; ++nt)
#pragma unroll
      for (int r = 0; r < 4; ++r)
        outp[(size_t)(t0 + mbase + mt * 16 + quad * 4 + r) * Dn +
             n0 + nbase + nt * 16 + lane16] = acc[mt][nt][r];
}

// ---------------------------------------------------------------------------
extern "C" void kernel_launch(void* const* d_in, const int* in_sizes, int n_in,
                              void* d_out, int out_size, void* d_ws, size_t ws_size,
                              hipStream_t stream) {
  const float* hidden = (const float*)d_in[0];
  const float* w_gate = (const float*)d_in[1];
  const float* A_gate = (const float*)d_in[2];
  const float* C_gate = (const float*)d_in[3];
  const float* B_gate = (const float*)d_in[4];
  const float* A_up   = (const float*)d_in[5];
  const float* C_up   = (const float*)d_in[6];
  const float* B_up   = (const float*)d_in[7];
  const float* A_down = (const float*)d_in[8];
  const float* C_down = (const float*)d_in[9];
  const float* B_down = (const float*)d_in[10];
  float* out = (float*)d_out;

  // Workspace layout (peak unchanged, 34.34 MB). Router-stage {part 12.6MB
  // (KS_R=6), hq 16.8MB, wqT 2.1MB} = 31.5MB overlay [0, 31.5MB), all dead
  // after k_topk and below the persistent smalls at 33.69MB. Hbf aliases
  // h1d+y (written after router stage, dead before h1d/y memsets).
  char* base = (char*)d_ws;
  size_t o = 0;
  unsigned short* h2gb = (unsigned short*)(base + o); o += (size_t)NROWS * Rn * 2;
  unsigned short* h2ub = (unsigned short*)(base + o); o += (size_t)NROWS * Rn * 2;
  unsigned short* AgT  = (unsigned short*)(base + o); o += (size_t)Gn * Rn * Dn * 2;
  unsigned short* AuT  = (unsigned short*)(base + o); o += (size_t)Gn * Rn * Dn * 2;
  unsigned short* BgT  = (unsigned short*)(base + o); o += (size_t)Gn * In * Rn * 2;
  unsigned short* BuT  = (unsigned short*)(base + o); o += (size_t)Gn * In * Rn * 2;
  unsigned short* AdT  = (unsigned short*)(base + o); o += (size_t)Gn * Rn * In * 2;
  unsigned short* BdT  = (unsigned short*)(base + o); o += (size_t)Dn * Gn * Rn * 2;
  unsigned short* CgT  = (unsigned short*)(base + o); o += (size_t)En * Rn * Rn * 2;
  unsigned short* CuT  = (unsigned short*)(base + o); o += (size_t)En * Rn * Rn * 2;
  unsigned short* CdT  = (unsigned short*)(base + o); o += (size_t)En * Rn * Rn * 2;
  unsigned short* h1gb = (unsigned short*)(base + o); o += (size_t)T0n * Gn * Rn * 2;
  unsigned short* h1ub = (unsigned short*)(base + o); o += (size_t)T0n * Gn * Rn * 2;
  float* h1d = (float*)(base + o); o += (size_t)NROWS * Rn * 4;
  float* y   = (float*)(base + o); o += (size_t)T0n * Gn * Rn * 4;
  // ---- persistent smalls ----
  float* rwp = (float*)(base + o); o += (size_t)NROWS * 4;
  int* sel   = (int*)(base + o); o += (size_t)NROWS * 4;
  int* rseg  = (int*)(base + o); o += (size_t)Gn * SEGCAP * 4;
  int* cnt_e = (int*)(base + o); o += En * 4;
  int* off_e = (int*)(base + o); o += En * 4;
  int* cur_e = (int*)(base + o); o += En * 4;
  int* grp_n = (int*)(base + o); o += Gn * 4;
  // ---- router-stage aliases (dead after k_topk), inside [0, 31.5MB) ----
  float* part = (float*)base;                              // 6*2048*256*4 = 12,582,912
  char* hq  = base + (size_t)KS_R * T0n * En * 4;          // +16,777,216 (4 i8 planes)
  char* wqT = hq + (size_t)4 * T0n * Dn;                   // +2,097,152  (4 i8 planes, T)
  // ---- Hbf alias: h1d (4.19MB) + y (4.19MB) = exactly T0n*Dn*2 bytes ----
  unsigned short* Hbf = (unsigned short*)h1d;

  hipMemsetAsync(cnt_e, 0, En * sizeof(int), stream);

  // 1) quantize inputs to exact 4x-i8 fixed-point limbs
  k_quant_h<<<T0n * Dn / 1024, 256, 0, stream>>>(hidden, hq);
  k_quant_wT<<<dim3(Dn / 32, En / 32), 256, 0, stream>>>(w_gate, wqT);
  // 2) router logits via i32-MFMA limb GEMM (s>=3 pairs, split-K=6)
  k_router_i8<<<dim3(En / 64, T0n / 64, KS_R), 256, 0, stream>>>(hq, wqT, part);
  // 3) top-8 + renorm + expert counts
  k_topk<<<T0n / 4, 256, 0, stream>>>(part, sel, rwp, cnt_e);
  // 4) offsets (parallel prefix) + scatter rows by expert
  k_scan<<<1, 256, 0, stream>>>(cnt_e, off_e, cur_e, grp_n);
  k_scatter<<<NROWS / 256, 256, 0, stream>>>(sel, cur_e, rseg);

  // part/hq/wqT now dead. Convert H to bf16 once (into the h1d+y alias).
  k_hcvt<<<T0n * Dn / 2048, 256, 0, stream>>>(hidden, Hbf);

  // 5) transpose+convert all 9 weight tensors to bf16 operand layouts
  {
    TD9 D;
    D.t[0] = {A_gate, AgT, Dn, Rn, Rn / 32, (Rn / 32) * (Dn / 32), 0};
    D.t[1] = {A_up,   AuT, Dn, Rn, Rn / 32, (Rn / 32) * (Dn / 32), 1024};
    D.t[2] = {B_gate, BgT, Rn, In, In / 32, (In / 32) * (Rn / 32), 2048};
    D.t[3] = {B_up,   BuT, Rn, In, In / 32, (In / 32) * (Rn / 32), 2752};
    D.t[4] = {A_down, AdT, In, Rn, Rn / 32, (Rn / 32) * (In / 32), 3456};
    D.t[5] = {B_down, BdT, Gn * Rn, Dn, Dn / 32, (Dn / 32) * (Gn * Rn / 32), 4160};
    D.t[6] = {C_gate, CgT, Rn, Rn, 2, 4, 5184};
    D.t[7] = {C_up,   CuT, Rn, Rn, 2, 4, 6208};
    D.t[8] = {C_down, CdT, Rn, Rn, 2, 4, 7232};
    k_tcvt9<<<8256, 256, 0, stream>>>(D);
  }

  // 6) dense in-factor projections (bf16 H + T14 K-loop prefetch)
  k_h1_mfma<<<dim3(T0n / 64, Gn), 512, 0, stream>>>(Hbf, AgT, AuT, h1gb, h1ub);

  // Hbf dead; reclaim h1d + y.
  hipMemsetAsync(h1d, 0, (size_t)NROWS * Rn * sizeof(float), stream);
  hipMemsetAsync(y,   0, (size_t)T0n * Gn * Rn * sizeof(float), stream);

  // 7) per-expert core (gate/up) via MFMA (512 thr path-split)
  k_core_gu<<<En, 512, 0, stream>>>(h1gb, h1ub, CgT, CuT,
                                    rseg, off_e, cnt_e, h2gb, h2ub);
  // 8) fused expand + down-A (8-wave/256-row + T14 register prefetch)
  k_expand_mfma<<<dim3(NTILE2_MAX, 4), 512, 0, stream>>>(
      h2gb, h2ub, BgT, BuT, AdT, rseg, grp_n, h1d);
  // 9) per-expert down core via MFMA + rw (512 thr, 128 rows/iter)
  k_core_down<<<En, 512, 0, stream>>>(h1d, CdT, rwp,
                                      rseg, off_e, cnt_e, y);
  // 10) combine (MFMA bf16)
  k_combine<<<dim3(Dn / 128, T0n / 128), 256, 0, stream>>>(y, BdT, out);
}

// Round 16
// 288.410 us; speedup vs baseline: 1.1475x; 1.0057x over previous
//
#include <hip/hip_runtime.h>
#include <math.h>

// Problem dims
constexpr int T0n = 2048;   // tokens
constexpr int Dn  = 2048;   // hidden
constexpr int En  = 256;    // experts
constexpr int Gn  = 8;      // groups
constexpr int EGn = 32;     // experts per group
constexpr int Rn  = 64;     // tucker rank
constexpr int In  = 1408;   // intermediate

constexpr int NROWS = T0n * 8;    // 16384 dispatched rows
constexpr int SEGCAP = NROWS;     // per-group segment capacity in rseg
constexpr int KS_R = 6;           // router split-K (i32 exact, uneven split OK)
constexpr int NTILE2_MAX = NROWS / 256 + Gn;   // 72: bound on sum ceil(ng/256)

typedef __attribute__((ext_vector_type(8))) short s8v;    // 8 bf16
typedef __attribute__((ext_vector_type(4))) float f4v;    // 4 fp32
typedef __attribute__((ext_vector_type(4))) int i4v;      // 16 i8 operand / 4 i32 acc
#define MFMA16(a, b, c) __builtin_amdgcn_mfma_f32_16x16x32_bf16(a, b, c, 0, 0, 0)
#define MFMAI8(a, b, c) __builtin_amdgcn_mfma_i32_16x16x64_i8(a, b, c, 0, 0, 0)

__device__ __forceinline__ unsigned short f2bf(float x) {
  unsigned int u = __float_as_uint(x);
  unsigned int r = (u + 0x7FFFu + ((u >> 16) & 1u)) >> 16;
  return (unsigned short)r;
}

// ---------------------------------------------------------------------------
// Fused batched transpose+convert for 9 weight tensors:
// src f32 [batch][rows][cols] -> dst bf16 [batch][cols][rows].
// ---------------------------------------------------------------------------
struct TD { const float* src; unsigned short* dst; int rows, cols, nbx, per_batch, base; };
struct TD9 { TD t[9]; };

__global__ __launch_bounds__(256) void k_tcvt9(TD9 D) {
  __shared__ float tbuf[32][33];
  int id = blockIdx.x;
  int ti = 0;
#pragma unroll
  for (int i = 1; i < 9; ++i) ti = (id >= D.t[i].base) ? i : ti;
  TD d = D.t[ti];
  int local = id - d.base;
  int bz = local / d.per_batch;
  int rem = local - bz * d.per_batch;
  int by = rem / d.nbx;
  int bx = rem - by * d.nbx;

  size_t boff = (size_t)bz * d.rows * d.cols;
  const float* src = d.src + boff;
  unsigned short* dst = d.dst + boff;
  int c0 = bx * 32, r0 = by * 32;
  int tx = threadIdx.x & 31, ty = threadIdx.x >> 5;   // ty 0..7
  for (int i = ty; i < 32; i += 8)
    tbuf[i][tx] = src[(size_t)(r0 + i) * d.cols + c0 + tx];
  __syncthreads();
  for (int i = ty; i < 32; i += 8)
    dst[(size_t)(c0 + i) * d.rows + r0 + tx] = f2bf(tbuf[tx][i]);
}

// ---------------------------------------------------------------------------
// H f32 -> bf16 once. Halves H traffic in k_h1_mfma.
// ---------------------------------------------------------------------------
__global__ __launch_bounds__(256) void k_hcvt(
    const float* __restrict__ H, unsigned short* __restrict__ Hbf) {
  size_t i = ((size_t)blockIdx.x * 256 + threadIdx.x) * 8;
  float4 v0 = *(const float4*)&H[i];
  float4 v1 = *(const float4*)&H[i + 4];
  ushort4 o0, o1;
  o0.x = f2bf(v0.x); o0.y = f2bf(v0.y); o0.z = f2bf(v0.z); o0.w = f2bf(v0.w);
  o1.x = f2bf(v1.x); o1.y = f2bf(v1.y); o1.z = f2bf(v1.z); o1.w = f2bf(v1.w);
  *(ushort4*)&Hbf[i] = o0;
  *(ushort4*)&Hbf[i + 4] = o1;
}

// ---------------------------------------------------------------------------
// ROUTER, fixed-point limb path. Pairs k+l>=3 (10 MFMA). s=3 is NOT
// droppable (~2.6e-6 rms vs token-min top-8 gap ~1.5e-5); s=2 drop verified
// byte-identical absmax (R12 data).
// ---------------------------------------------------------------------------
__device__ __forceinline__ int4 limbs4(float v, double sc) {
  double d = (double)v * sc;           // exact in double
  d = fmin(fmax(d, -2.0e9), 2.0e9);    // clamp (unreachable for this data)
  int x = __double2int_rn(d);
  int l0 = (int)(signed char)(x & 0xff); x = (x - l0) >> 8;   // exact
  int l1 = (int)(signed char)(x & 0xff); x = (x - l1) >> 8;
  int l2 = (int)(signed char)(x & 0xff); x = (x - l2) >> 8;
  return make_int4(l0, l1, l2, x);     // x fits i8
}

// R20: fused input quantization. Blocks [0,4096): hidden -> hq planes.
// Blocks [4096,4608): w_gate -> wqT planes (transposed). One dispatch.
__global__ __launch_bounds__(256) void k_quant(
    const float* __restrict__ H, const float* __restrict__ W,
    char* __restrict__ hq, char* __restrict__ wqT) {
  __shared__ float tb[32][33];
  const int id = blockIdx.x;
  if (id < 4096) {
    const size_t PL = (size_t)T0n * Dn;
    size_t i = (size_t)id * 256 + threadIdx.x;   // group of 4 elements
    float4 v = *(const float4*)&H[i * 4];
    int4 a = limbs4(v.x, 268435456.0);   // 2^28
    int4 b = limbs4(v.y, 268435456.0);
    int4 c = limbs4(v.z, 268435456.0);
    int4 d = limbs4(v.w, 268435456.0);
    unsigned int p0 = (a.x & 0xff) | ((b.x & 0xff) << 8) | ((c.x & 0xff) << 16) | ((unsigned)(d.x & 0xff) << 24);
    unsigned int p1 = (a.y & 0xff) | ((b.y & 0xff) << 8) | ((c.y & 0xff) << 16) | ((unsigned)(d.y & 0xff) << 24);
    unsigned int p2 = (a.z & 0xff) | ((b.z & 0xff) << 8) | ((c.z & 0xff) << 16) | ((unsigned)(d.z & 0xff) << 24);
    unsigned int p3 = (a.w & 0xff) | ((b.w & 0xff) << 8) | ((c.w & 0xff) << 16) | ((unsigned)(d.w & 0xff) << 24);
    *(unsigned int*)&hq[0 * PL + i * 4] = p0;
    *(unsigned int*)&hq[1 * PL + i * 4] = p1;
    *(unsigned int*)&hq[2 * PL + i * 4] = p2;
    *(unsigned int*)&hq[3 * PL + i * 4] = p3;
  } else {
    const size_t PL = (size_t)En * Dn;
    int local = id - 4096;                 // [0, 512): 64 kb-tiles x 8 nb-tiles
    int kb = (local & 63) * 32, nb = (local >> 6) * 32;
    int tx = threadIdx.x & 31, ty = threadIdx.x >> 5;
    for (int i = ty; i < 32; i += 8)
      tb[i][tx] = W[(size_t)(kb + i) * En + nb + tx];
    __syncthreads();
    for (int i = ty; i < 32; i += 8) {
      int4 l = limbs4(tb[tx][i], 8589934592.0);   // 2^33
      size_t off = (size_t)(nb + i) * Dn + kb + tx;
      wqT[0 * PL + off] = (char)l.x;
      wqT[1 * PL + off] = (char)l.y;
      wqT[2 * PL + off] = (char)l.z;
      wqT[3 * PL + off] = (char)l.w;
    }
  }
}

// i8 MFMA router GEMM. 10 MFMA/step (s>=3), KS_R=6 (uneven split).
// grid (En/64, T0n/64, KS_R).
__global__ __launch_bounds__(256) void k_router_i8(
    const char* __restrict__ hq, const char* __restrict__ wqT,
    float* __restrict__ part) {
  __shared__ __align__(16) char Asl[4][64][80];   // [limb][m-row][k]
  __shared__ __align__(16) char Bsl[4][64][80];   // [limb][n-row][k]
  const int n0 = blockIdx.x * 64, m0 = blockIdx.y * 64;
  const int kc = blockIdx.z;
  const int tid = threadIdx.x;
  const int w = tid >> 6, ln = tid & 63;
  const int quad = ln >> 4, lane16 = ln & 15;

  const char* ha = hq + ((size_t)w * T0n + m0 + ln) * Dn;   // plane w, row m0+ln
  const char* ba = wqT + ((size_t)w * En + n0 + ln) * Dn;   // plane w, row n0+ln

  i4v acc[4][4] = {};   // [m-tile][s-group s=k+l-3, s in 3..6]

  // Uneven K-split over 32 steps of 64: kc gets steps [kc*32/6,(kc+1)*32/6).
  const int kbeg = ((kc * 32) / KS_R) * 64;
  const int kend = (((kc + 1) * 32) / KS_R) * 64;
  for (int k0 = kbeg; k0 < kend; k0 += 64) {
#pragma unroll
    for (int q = 0; q < 4; ++q) {
      *(uint4*)&Asl[w][ln][q * 16] = *(const uint4*)&ha[k0 + q * 16];
      *(uint4*)&Bsl[w][ln][q * 16] = *(const uint4*)&ba[k0 + q * 16];
    }
    __syncthreads();
    i4v b0 = *(const i4v*)&Bsl[0][w * 16 + lane16][quad * 16];
    i4v b1 = *(const i4v*)&Bsl[1][w * 16 + lane16][quad * 16];
    i4v b2 = *(const i4v*)&Bsl[2][w * 16 + lane16][quad * 16];
    i4v b3 = *(const i4v*)&Bsl[3][w * 16 + lane16][quad * 16];
#pragma unroll
    for (int mt = 0; mt < 4; ++mt) {
      i4v a0 = *(const i4v*)&Asl[0][mt * 16 + lane16][quad * 16];
      i4v a1 = *(const i4v*)&Asl[1][mt * 16 + lane16][quad * 16];
      i4v a2 = *(const i4v*)&Asl[2][mt * 16 + lane16][quad * 16];
      i4v a3 = *(const i4v*)&Asl[3][mt * 16 + lane16][quad * 16];
      // s = 3
      acc[mt][0] = MFMAI8(a0, b3, acc[mt][0]);
      acc[mt][0] = MFMAI8(a1, b2, acc[mt][0]);
      acc[mt][0] = MFMAI8(a2, b1, acc[mt][0]);
      acc[mt][0] = MFMAI8(a3, b0, acc[mt][0]);
      // s = 4
      acc[mt][1] = MFMAI8(a1, b3, acc[mt][1]);
      acc[mt][1] = MFMAI8(a2, b2, acc[mt][1]);
      acc[mt][1] = MFMAI8(a3, b1, acc[mt][1]);
      // s = 5
      acc[mt][2] = MFMAI8(a2, b3, acc[mt][2]);
      acc[mt][2] = MFMAI8(a3, b2, acc[mt][2]);
      // s = 6
      acc[mt][3] = MFMAI8(a3, b3, acc[mt][3]);
    }
    __syncthreads();
  }

  // Combine 4 exact i32 sums at scales 2^(8s-61), s=3..6.
  float* prow = part + (size_t)kc * T0n * En;
#pragma unroll
  for (int mt = 0; mt < 4; ++mt)
#pragma unroll
    for (int r = 0; r < 4; ++r) {
      int row = m0 + mt * 16 + quad * 4 + r;
      int col = n0 + w * 16 + lane16;
      double v = (double)acc[mt][0][r] * 0x1p-37 +
                 (double)acc[mt][1][r] * 0x1p-29 +
                 (double)acc[mt][2][r] * 0x1p-21 +
                 (double)acc[mt][3][r] * 0x1p-13;
      prow[(size_t)row * En + col] = (float)v;
    }
}

// ---------------------------------------------------------------------------
// Top-8: one wave per token, shuffle butterfly. Sums KS_R fp32 partials in fp64.
// ---------------------------------------------------------------------------
__global__ __launch_bounds__(256) void k_topk(
    const float* __restrict__ part, int* __restrict__ sel,
    float* __restrict__ rw, int* __restrict__ cnt_e) {
  const int wid = threadIdx.x >> 6, ln = threadIdx.x & 63;
  const int t = blockIdx.x * 4 + wid;

  double v[4];
#pragma unroll
  for (int j = 0; j < 4; ++j) {
    double s = 0.0;
#pragma unroll
    for (int kc = 0; kc < KS_R; ++kc)
      s += (double)part[((size_t)kc * T0n + t) * En + ln + 64 * j];
    v[j] = s;
  }

  float topv[8];
  int topi[8];
#pragma unroll
  for (int k = 0; k < 8; ++k) {
    double bv = v[0]; int bi = ln;
#pragma unroll
    for (int j = 1; j < 4; ++j) {
      int cand = ln + 64 * j;
      if (v[j] > bv || (v[j] == bv && cand < bi)) { bv = v[j]; bi = cand; }
    }
#pragma unroll
    for (int off = 32; off > 0; off >>= 1) {
      double ov = __shfl_xor(bv, off);
      int oi = __shfl_xor(bi, off);
      if (ov > bv || (ov == bv && oi < bi)) { bv = ov; bi = oi; }
    }
    topv[k] = (float)bv; topi[k] = bi;
    if ((bi & 63) == ln) v[bi >> 6] = -1e300;
  }

  if (ln < 8) {
    float m = topv[0];
    float ssum = 0.f;
#pragma unroll
    for (int k = 0; k < 8; ++k) ssum += expf(topv[k] - m);
    rw[t * 8 + ln] = expf(topv[ln] - m) / ssum;
    sel[t * 8 + ln] = topi[ln];
    atomicAdd(&cnt_e[topi[ln]], 1);
  }
}

// Parallel per-group prefix over 256 experts.
__global__ __launch_bounds__(256) void k_scan(
    const int* __restrict__ cnt_e, int* __restrict__ off_e,
    int* __restrict__ cur_e, int* __restrict__ grp_n) {
  __shared__ int c[256];
  int tid = threadIdx.x;
  c[tid] = cnt_e[tid];
  __syncthreads();
  int g = tid >> 5, ei = tid & 31;
  int run = 0;
  for (int i = 0; i < ei; ++i) run += c[(g << 5) + i];
  off_e[tid] = g * SEGCAP + run;
  cur_e[tid] = g * SEGCAP + run;
  if (ei == 31) grp_n[g] = run + c[tid];
}

__global__ void k_scatter(const int* __restrict__ sel, int* __restrict__ cur_e,
                          int* __restrict__ rseg) {
  int i = blockIdx.x * 256 + threadIdx.x;
  int e = sel[i];
  int pos = atomicAdd(&cur_e[e], 1);
  rseg[pos] = i;
}

// ---------------------------------------------------------------------------
// h1 = H @ A_fac[g]. bf16 H (k_hcvt) + T14 K-loop prefetch (R19, verified).
// 512 threads: waves 0-3 gate, 4-7 up. grid (T0/64, G).
// ---------------------------------------------------------------------------
__global__ __launch_bounds__(512) void k_h1_mfma(
    const unsigned short* __restrict__ Hbf,
    const unsigned short* __restrict__ AgT, const unsigned short* __restrict__ AuT,
    unsigned short* __restrict__ h1gb, unsigned short* __restrict__ h1ub) {
  const int t0 = blockIdx.x * 64;
  const int g = blockIdx.y;
  const unsigned short* Wg = AgT + (size_t)g * Rn * Dn;
  const unsigned short* Wu = AuT + (size_t)g * Rn * Dn;

  __shared__ unsigned short As[64 * 72];
  __shared__ unsigned short Bg_l[64 * 72];
  __shared__ unsigned short Bu_l[64 * 72];
  const int tid = threadIdx.x;
  const int w = tid >> 6, ln = tid & 63;
  const int path = w >> 2, ws = w & 3;
  const int quad = ln >> 4, lane16 = ln & 15;
  const int j = tid >> 3, q = (tid & 7) * 8;   // 64 rows x 8 chunks

  f4v S[4] = {};

  // T14 prologue: stage k0=0 into registers.
  uint4 sH, sG, sU;
  {
    sH = *(const uint4*)&Hbf[(size_t)(t0 + j) * Dn + q];
    sG = *(const uint4*)&Wg[(size_t)j * Dn + q];
    sU = *(const uint4*)&Wu[(size_t)j * Dn + q];
  }

  for (int k0 = 0; k0 < Dn; k0 += 64) {
    // Publish staged tile (vmcnt wait covered by previous iter's compute).
    *(uint4*)&As[j * 72 + q] = sH;
    *(uint4*)&Bg_l[j * 72 + q] = sG;
    *(uint4*)&Bu_l[j * 72 + q] = sU;
    __syncthreads();

    // Issue next K-step's loads; latency hides under the MFMAs below.
    if (k0 + 64 < Dn) {
      sH = *(const uint4*)&Hbf[(size_t)(t0 + j) * Dn + k0 + 64 + q];
      sG = *(const uint4*)&Wg[(size_t)j * Dn + k0 + 64 + q];
      sU = *(const uint4*)&Wu[(size_t)j * Dn + k0 + 64 + q];
    }

    const unsigned short* Bl = path ? Bu_l : Bg_l;
#pragma unroll
    for (int kk = 0; kk < 2; ++kk) {
      s8v a = *(const s8v*)&As[(ws * 16 + lane16) * 72 + kk * 32 + quad * 8];
#pragma unroll
      for (int nt = 0; nt < 4; ++nt) {
        s8v b = *(const s8v*)&Bl[(nt * 16 + lane16) * 72 + kk * 32 + quad * 8];
        S[nt] = MFMA16(a, b, S[nt]);
      }
    }
    __syncthreads();
  }
  unsigned short* out = path ? h1ub : h1gb;
#pragma unroll
  for (int nt = 0; nt < 4; ++nt)
#pragma unroll
    for (int r = 0; r < 4; ++r) {
      int row = t0 + ws * 16 + quad * 4 + r;
      int col = g * 64 + nt * 16 + lane16;
      out[(size_t)row * (Gn * Rn) + col] = f2bf(S[nt][r]);
    }
}

// ---------------------------------------------------------------------------
// Per-expert core (gate/up) via MFMA. 512 threads: waves 0-3 gate, 4-7 up.
// ---------------------------------------------------------------------------
__global__ __launch_bounds__(512) void k_core_gu(
    const unsigned short* __restrict__ h1gb, const unsigned short* __restrict__ h1ub,
    const unsigned short* __restrict__ CgT, const unsigned short* __restrict__ CuT,
    const int* __restrict__ rseg, const int* __restrict__ off_e,
    const int* __restrict__ cnt_e,
    unsigned short* __restrict__ h2gb, unsigned short* __restrict__ h2ub) {
  const int e = blockIdx.x;
  const int ne = cnt_e[e];
  if (ne == 0) return;
  const int g = e >> 5;
  const int base = off_e[e];
  __shared__ unsigned short Cg_l[64 * 72];
  __shared__ unsigned short Cu_l[64 * 72];
  __shared__ unsigned short Ags[64 * 72];
  __shared__ unsigned short Aus[64 * 72];
  __shared__ int rids[64];
  const int tid = threadIdx.x;
  const int w = tid >> 6, ln = tid & 63;
  const int path = w >> 2, ws = w & 3;
  const int quad = ln >> 4, lane16 = ln & 15;
  const int j = tid >> 3, q = (tid & 7) * 8;
  {
    const unsigned short* cg = CgT + (size_t)e * (Rn * Rn);
    const unsigned short* cu = CuT + (size_t)e * (Rn * Rn);
    *(uint4*)&Cg_l[j * 72 + q] = *(const uint4*)&cg[j * 64 + q];
    *(uint4*)&Cu_l[j * 72 + q] = *(const uint4*)&cu[j * 64 + q];
  }
  const int ntile = (ne + 63) >> 6;
  for (int it = 0; it < ntile; ++it) {
    int mi = it * 64 + j;
    int rid = (mi < ne) ? rseg[base + mi] : -1;
    if ((tid & 7) == 0) rids[j] = rid;
    uint4 zg = {0, 0, 0, 0}, zu = {0, 0, 0, 0};
    if (rid >= 0) {
      zg = *(const uint4*)&h1gb[(size_t)(rid >> 3) * (Gn * Rn) + g * 64 + q];
      zu = *(const uint4*)&h1ub[(size_t)(rid >> 3) * (Gn * Rn) + g * 64 + q];
    }
    *(uint4*)&Ags[j * 72 + q] = zg;
    *(uint4*)&Aus[j * 72 + q] = zu;
    __syncthreads();
    const unsigned short* Al = path ? Aus : Ags;
    const unsigned short* Cl = path ? Cu_l : Cg_l;
    f4v S[4] = {};
#pragma unroll
    for (int kk = 0; kk < 2; ++kk) {
      s8v a = *(const s8v*)&Al[(ws * 16 + lane16) * 72 + kk * 32 + quad * 8];
#pragma unroll
      for (int nt = 0; nt < 4; ++nt) {
        s8v b = *(const s8v*)&Cl[(nt * 16 + lane16) * 72 + kk * 32 + quad * 8];
        S[nt] = MFMA16(a, b, S[nt]);
      }
    }
    unsigned short* out = path ? h2ub : h2gb;
#pragma unroll
    for (int nt = 0; nt < 4; ++nt)
#pragma unroll
      for (int r = 0; r < 4; ++r) {
        int rid2 = rids[ws * 16 + quad * 4 + r];
        if (rid2 >= 0)
          out[(size_t)rid2 * 64 + nt * 16 + lane16] = f2bf(S[nt][r]);
      }
    __syncthreads();
  }
}

// ---------------------------------------------------------------------------
// Fused expand + down-A via MFMA. 8-wave/256-row (R17) + T14 register
// prefetch (R18, verified). VGPR ~96-100, 4 waves/SIMD.
// ---------------------------------------------------------------------------
__global__ __launch_bounds__(512) void k_expand_mfma(
    const unsigned short* __restrict__ h2gb, const unsigned short* __restrict__ h2ub,
    const unsigned short* __restrict__ BgT, const unsigned short* __restrict__ BuT,
    const unsigned short* __restrict__ AdT,
    const int* __restrict__ rseg, const int* __restrict__ grp_n,
    float* __restrict__ h1d) {
  // Decode flat 256-row tile id -> (g, m0) via prefix over per-group counts.
  int t = blockIdx.x;
  int g = -1, m0 = 0, ng = 0;
  {
    int pre = 0;
#pragma unroll
    for (int gg = 0; gg < Gn; ++gg) {
      int n = grp_n[gg];
      int nt = (n + 255) >> 8;
      if (g < 0 && t < pre + nt) { g = gg; m0 = (t - pre) << 8; ng = n; }
      pre += nt;
    }
  }
  if (g < 0) return;
  const int c_beg = blockIdx.y * 6;
  const int c_end = min(22, c_beg + 6);

  __shared__ unsigned short Bg_l[64 * 72];
  __shared__ unsigned short Bu_l[64 * 72];
  __shared__ unsigned short Ad_l[64 * 72];
  __shared__ unsigned short inter_l[8][32 * 72];   // per-wave private
  __shared__ int rids[256];

  const int tid = threadIdx.x;
  const int w = tid >> 6, ln = tid & 63;   // w in 0..7
  const int quad = ln >> 4, lane16 = ln & 15;

  if (tid < 256) rids[tid] = (m0 + tid < ng) ? rseg[g * SEGCAP + m0 + tid] : -1;
  __syncthreads();

  // H gate/up fragments in registers: wave w owns rows w*32..w*32+31.
  s8v ag[2][2], au[2][2];
#pragma unroll
  for (int mt = 0; mt < 2; ++mt) {
    int rid = rids[w * 32 + mt * 16 + lane16];
#pragma unroll
    for (int kk = 0; kk < 2; ++kk) {
      s8v zg = {}, zu = {};
      if (rid >= 0) {
        zg = *(const s8v*)&h2gb[(size_t)rid * 64 + kk * 32 + quad * 8];
        zu = *(const s8v*)&h2ub[(size_t)rid * 64 + kk * 32 + quad * 8];
      }
      ag[mt][kk] = zg;
      au[mt][kk] = zu;
    }
  }

  const unsigned short* Bg_base = BgT + (size_t)g * In * Rn;
  const unsigned short* Bu_base = BuT + (size_t)g * In * Rn;
  const unsigned short* Ad_base = AdT + (size_t)g * Rn * In;

  unsigned short* ib = &inter_l[w][0];
  f4v P[2][4] = {};
  const int srow = tid >> 3, sco = (tid & 7) * 8;   // 512 thr: 64 rows x 8 cols

  // T14 prologue: stage first chunk into registers.
  uint4 sg, su, sd;
  {
    const int i0 = c_beg * 64;
    sg = *(const uint4*)&Bg_base[(size_t)(i0 + srow) * Rn + sco];
    su = *(const uint4*)&Bu_base[(size_t)(i0 + srow) * Rn + sco];
    sd = *(const uint4*)&Ad_base[(size_t)srow * In + i0 + sco];
  }

  for (int c = c_beg; c < c_end; ++c) {
    // Publish staged tiles (implicit vmcnt wait lands here, covered by the
    // previous iteration's compute).
    *(uint4*)&Bg_l[srow * 72 + sco] = sg;
    *(uint4*)&Bu_l[srow * 72 + sco] = su;
    *(uint4*)&Ad_l[srow * 72 + sco] = sd;
    __syncthreads();   // B tiles ready

    // Issue next chunk's loads; latency hides under the compute below.
    if (c + 1 < c_end) {
      const int i1 = (c + 1) * 64;
      sg = *(const uint4*)&Bg_base[(size_t)(i1 + srow) * Rn + sco];
      su = *(const uint4*)&Bu_base[(size_t)(i1 + srow) * Rn + sco];
      sd = *(const uint4*)&Ad_base[(size_t)srow * In + i1 + sco];
    }

    f4v Sg[2][4] = {}, Su[2][4] = {};
#pragma unroll
    for (int kk = 0; kk < 2; ++kk) {
      s8v bg[4], bu[4];
#pragma unroll
      for (int nt = 0; nt < 4; ++nt) {
        bg[nt] = *(const s8v*)&Bg_l[(nt * 16 + lane16) * 72 + kk * 32 + quad * 8];
        bu[nt] = *(const s8v*)&Bu_l[(nt * 16 + lane16) * 72 + kk * 32 + quad * 8];
      }
#pragma unroll
      for (int mt = 0; mt < 2; ++mt)
#pragma unroll
        for (int nt = 0; nt < 4; ++nt) {
          Sg[mt][nt] = MFMA16(ag[mt][kk], bg[nt], Sg[mt][nt]);
          Su[mt][nt] = MFMA16(au[mt][kk], bu[nt], Su[mt][nt]);
        }
    }

    // silu(gate)*up -> per-wave inter region. No barrier: wave-local W->R.
#pragma unroll
    for (int mt = 0; mt < 2; ++mt)
#pragma unroll
      for (int nt = 0; nt < 4; ++nt)
#pragma unroll
        for (int r = 0; r < 4; ++r) {
          float sg2 = Sg[mt][nt][r];
          float v = sg2 / (1.f + __expf(-sg2)) * Su[mt][nt][r];
          ib[(mt * 16 + quad * 4 + r) * 72 + nt * 16 + lane16] = f2bf(v);
        }
    asm volatile("s_waitcnt lgkmcnt(0)" ::: "memory");   // wave-local W->R order

#pragma unroll
    for (int kk = 0; kk < 2; ++kk) {
      s8v ai[2], bd[4];
#pragma unroll
      for (int mt = 0; mt < 2; ++mt)
        ai[mt] = *(const s8v*)&ib[(mt * 16 + lane16) * 72 + kk * 32 + quad * 8];
#pragma unroll
      for (int nt = 0; nt < 4; ++nt)
        bd[nt] = *(const s8v*)&Ad_l[(nt * 16 + lane16) * 72 + kk * 32 + quad * 8];
#pragma unroll
      for (int mt = 0; mt < 2; ++mt)
#pragma unroll
        for (int nt = 0; nt < 4; ++nt)
          P[mt][nt] = MFMA16(ai[mt], bd[nt], P[mt][nt]);
    }
    __syncthreads();   // B tiles consumed; safe to overwrite next iteration
  }

#pragma unroll
  for (int mt = 0; mt < 2; ++mt)
#pragma unroll
    for (int nt = 0; nt < 4; ++nt)
#pragma unroll
      for (int r = 0; r < 4; ++r) {
        int lrow = w * 32 + mt * 16 + quad * 4 + r;
        int rid = rids[lrow];
        if (rid >= 0)
          atomicAdd(&h1d[(size_t)rid * 64 + nt * 16 + lane16], P[mt][nt][r]);
      }
}

// ---------------------------------------------------------------------------
// Per-expert down core via MFMA + routing weight, reduce to y[t,g,64].
// 512 threads: 128 rows/iter.
// ---------------------------------------------------------------------------
__global__ __launch_bounds__(512) void k_core_down(
    const float* __restrict__ h1d, const unsigned short* __restrict__ CdT,
    const float* __restrict__ rw,
    const int* __restrict__ rseg, const int* __restrict__ off_e,
    const int* __restrict__ cnt_e,
    float* __restrict__ y) {
  const int e = blockIdx.x;
  const int ne = cnt_e[e];
  if (ne == 0) return;
  const int g = e >> 5;
  const int base = off_e[e];
  __shared__ unsigned short Bd_l[64 * 72];
  __shared__ unsigned short Ad_l[128 * 72];
  __shared__ int rids[128];
  const int tid = threadIdx.x;
  const int w = tid >> 6, ln = tid & 63;
  const int quad = ln >> 4, lane16 = ln & 15;
  {
    int j = tid >> 3, q = (tid & 7) * 8;
    const unsigned short* cd = CdT + (size_t)e * (Rn * Rn);
    *(uint4*)&Bd_l[j * 72 + q] = *(const uint4*)&cd[j * 64 + q];
  }
  const int gj = tid >> 2, gq = (tid & 3) * 16;   // 128 rows x 4 chunks of 16
  const int ntile = (ne + 127) >> 7;
  for (int it = 0; it < ntile; ++it) {
    int mi = it * 128 + gj;
    int rid = (mi < ne) ? rseg[base + mi] : -1;
    if ((tid & 3) == 0) rids[gj] = rid;
#pragma unroll
    for (int i = 0; i < 4; ++i) {
      int kb = gq + i * 4;
      float4 vd = {0.f, 0.f, 0.f, 0.f};
      if (rid >= 0) vd = *(const float4*)&h1d[(size_t)rid * 64 + kb];
      ushort4 od;
      od.x = f2bf(vd.x); od.y = f2bf(vd.y); od.z = f2bf(vd.z); od.w = f2bf(vd.w);
      *(ushort4*)&Ad_l[gj * 72 + kb] = od;
    }
    __syncthreads();
    f4v Sd[4] = {};
#pragma unroll
    for (int kk = 0; kk < 2; ++kk) {
      s8v ad = *(const s8v*)&Ad_l[(w * 16 + lane16) * 72 + kk * 32 + quad * 8];
#pragma unroll
      for (int nt = 0; nt < 4; ++nt) {
        s8v bd = *(const s8v*)&Bd_l[(nt * 16 + lane16) * 72 + kk * 32 + quad * 8];
        Sd[nt] = MFMA16(ad, bd, Sd[nt]);
      }
    }
#pragma unroll
    for (int nt = 0; nt < 4; ++nt)
#pragma unroll
      for (int r = 0; r < 4; ++r) {
        int rid2 = rids[w * 16 + quad * 4 + r];
        if (rid2 >= 0) {
          float wgt = rw[rid2];
          atomicAdd(&y[(size_t)(rid2 >> 3) * (Gn * Rn) + g * 64 + nt * 16 + lane16],
                    wgt * Sd[nt][r]);
        }
      }
    __syncthreads();
  }
}

// ---------------------------------------------------------------------------
// Combine: out[2048,2048] = y[2048,512] @ B_down-as-[512,2048], MFMA bf16.
// R20: 512 thr / 8 waves (per-wave 64x32, acc[4][2]) + T14 prefetch of both
// staging tiles — same levers that won on expand (R17/R18) and h1 (R19).
// grid (Dn/128, T0n/128).
// ---------------------------------------------------------------------------
__global__ __launch_bounds__(512) void k_combine(
    const float* __restrict__ y, const unsigned short* __restrict__ BdT,
    float* __restrict__ outp) {
  const int t0 = blockIdx.y * 128, n0 = blockIdx.x * 128;
  __shared__ unsigned short As[128 * 72];
  __shared__ unsigned short Bs[128 * 72];
  const int tid = threadIdx.x;
  const int w = tid >> 6, ln = tid & 63;   // w in 0..7
  const int quad = ln >> 4, lane16 = ln & 15;
  const int mbase = (w >> 2) * 64, nbase = (w & 3) * 32;

  f4v acc[4][2] = {};

  // Staging geometry (512 thr): y 128x64 f32 -> 4 float4/thr; B 128x64 bf16
  // -> 2 uint4/thr.
  // T14 prologue: stage k0=0.
  float4 sy[4];
  uint4 sb[2];
#pragma unroll
  for (int i = 0; i < 4; ++i) {
    int c = tid + i * 512;
    int row = c >> 4, cc = (c & 15) * 4;
    sy[i] = *(const float4*)&y[(size_t)(t0 + row) * (Gn * Rn) + cc];
  }
#pragma unroll
  for (int i = 0; i < 2; ++i) {
    int c = tid + i * 512;
    int row = c >> 3, cc = (c & 7) * 8;
    sb[i] = *(const uint4*)&BdT[(size_t)(n0 + row) * (Gn * Rn) + cc];
  }

  for (int k0 = 0; k0 < Gn * Rn; k0 += 64) {
    // Publish staged tiles.
#pragma unroll
    for (int i = 0; i < 4; ++i) {
      int c = tid + i * 512;
      int row = c >> 4, cc = (c & 15) * 4;
      ushort4 o;
      o.x = f2bf(sy[i].x); o.y = f2bf(sy[i].y);
      o.z = f2bf(sy[i].z); o.w = f2bf(sy[i].w);
      *(ushort4*)&As[row * 72 + cc] = o;
    }
#pragma unroll
    for (int i = 0; i < 2; ++i) {
      int c = tid + i * 512;
      int row = c >> 3, cc = (c & 7) * 8;
      *(uint4*)&Bs[row * 72 + cc] = sb[i];
    }
    __syncthreads();

    // Issue next K-step's loads.
    if (k0 + 64 < Gn * Rn) {
#pragma unroll
      for (int i = 0; i < 4; ++i) {
        int c = tid + i * 512;
        int row = c >> 4, cc = (c & 15) * 4;
        sy[i] = *(const float4*)&y[(size_t)(t0 + row) * (Gn * Rn) + k0 + 64 + cc];
      }
#pragma unroll
      for (int i = 0; i < 2; ++i) {
        int c = tid + i * 512;
        int row = c >> 3, cc = (c & 7) * 8;
        sb[i] = *(const uint4*)&BdT[(size_t)(n0 + row) * (Gn * Rn) + k0 + 64 + cc];
      }
    }

#pragma unroll
    for (int kk = 0; kk < 2; ++kk) {
      s8v a[4], b[2];
#pragma unroll
      for (int mt = 0; mt < 4; ++mt)
        a[mt] = *(const s8v*)&As[(mbase + mt * 16 + lane16) * 72 + kk * 32 + quad * 8];
#pragma unroll
      for (int nt = 0; nt < 2; ++nt)
        b[nt] = *(const s8v*)&Bs[(nbase + nt * 16 + lane16) * 72 + kk * 32 + quad * 8];
#pragma unroll
      for (int mt = 0; mt < 4; ++mt)
#pragma unroll
        for (int nt = 0; nt < 2; ++nt)
          acc[mt][nt] = MFMA16(a[mt], b[nt], acc[mt][nt]);
    }
    __syncthreads();
  }
#pragma unroll
  for (int mt = 0; mt < 4; ++mt)
#pragma unroll
    for (int nt = 0; nt < 2; ++nt)
#pragma unroll
      for (int r = 0; r < 4; ++r)
        outp[(size_t)(t0 + mbase + mt * 16 + quad * 4 + r) * Dn +
             n0 + nbase + nt * 16 + lane16] = acc[mt][nt][r];
}

// ---------------------------------------------------------------------------
extern "C" void kernel_launch(void* const* d_in, const int* in_sizes, int n_in,
                              void* d_out, int out_size, void* d_ws, size_t ws_size,
                              hipStream_t stream) {
  const float* hidden = (const float*)d_in[0];
  const float* w_gate = (const float*)d_in[1];
  const float* A_gate = (const float*)d_in[2];
  const float* C_gate = (const float*)d_in[3];
  const float* B_gate = (const float*)d_in[4];
  const float* A_up   = (const float*)d_in[5];
  const float* C_up   = (const float*)d_in[6];
  const float* B_up   = (const float*)d_in[7];
  const float* A_down = (const float*)d_in[8];
  const float* C_down = (const float*)d_in[9];
  const float* B_down = (const float*)d_in[10];
  float* out = (float*)d_out;

  // Workspace layout (peak unchanged, 34.34 MB). Router-stage {part 12.6MB
  // (KS_R=6), hq 16.8MB, wqT 2.1MB} = 31.5MB overlay [0, 31.5MB), all dead
  // after k_topk and below the persistent smalls at 33.69MB. Hbf aliases
  // h1d+y (written after router stage, dead before the merged h1d+y memset).
  char* base = (char*)d_ws;
  size_t o = 0;
  unsigned short* h2gb = (unsigned short*)(base + o); o += (size_t)NROWS * Rn * 2;
  unsigned short* h2ub = (unsigned short*)(base + o); o += (size_t)NROWS * Rn * 2;
  unsigned short* AgT  = (unsigned short*)(base + o); o += (size_t)Gn * Rn * Dn * 2;
  unsigned short* AuT  = (unsigned short*)(base + o); o += (size_t)Gn * Rn * Dn * 2;
  unsigned short* BgT  = (unsigned short*)(base + o); o += (size_t)Gn * In * Rn * 2;
  unsigned short* BuT  = (unsigned short*)(base + o); o += (size_t)Gn * In * Rn * 2;
  unsigned short* AdT  = (unsigned short*)(base + o); o += (size_t)Gn * Rn * In * 2;
  unsigned short* BdT  = (unsigned short*)(base + o); o += (size_t)Dn * Gn * Rn * 2;
  unsigned short* CgT  = (unsigned short*)(base + o); o += (size_t)En * Rn * Rn * 2;
  unsigned short* CuT  = (unsigned short*)(base + o); o += (size_t)En * Rn * Rn * 2;
  unsigned short* CdT  = (unsigned short*)(base + o); o += (size_t)En * Rn * Rn * 2;
  unsigned short* h1gb = (unsigned short*)(base + o); o += (size_t)T0n * Gn * Rn * 2;
  unsigned short* h1ub = (unsigned short*)(base + o); o += (size_t)T0n * Gn * Rn * 2;
  float* h1d = (float*)(base + o); o += (size_t)NROWS * Rn * 4;
  float* y   = (float*)(base + o); o += (size_t)T0n * Gn * Rn * 4;
  // ---- persistent smalls ----
  float* rwp = (float*)(base + o); o += (size_t)NROWS * 4;
  int* sel   = (int*)(base + o); o += (size_t)NROWS * 4;
  int* rseg  = (int*)(base + o); o += (size_t)Gn * SEGCAP * 4;
  int* cnt_e = (int*)(base + o); o += En * 4;
  int* off_e = (int*)(base + o); o += En * 4;
  int* cur_e = (int*)(base + o); o += En * 4;
  int* grp_n = (int*)(base + o); o += Gn * 4;
  // ---- router-stage aliases (dead after k_topk), inside [0, 31.5MB) ----
  float* part = (float*)base;                              // 6*2048*256*4 = 12,582,912
  char* hq  = base + (size_t)KS_R * T0n * En * 4;          // +16,777,216 (4 i8 planes)
  char* wqT = hq + (size_t)4 * T0n * Dn;                   // +2,097,152  (4 i8 planes, T)
  // ---- Hbf alias: h1d (4.19MB) + y (4.19MB) = exactly T0n*Dn*2 bytes ----
  unsigned short* Hbf = (unsigned short*)h1d;

  hipMemsetAsync(cnt_e, 0, En * sizeof(int), stream);

  // 1) quantize H and w_gate to exact i8 limbs (fused, one dispatch)
  k_quant<<<T0n * Dn / 1024 + (Dn / 32) * (En / 32), 256, 0, stream>>>(
      hidden, w_gate, hq, wqT);
  // 2) router logits via i32-MFMA limb GEMM (s>=3 pairs, split-K=6)
  k_router_i8<<<dim3(En / 64, T0n / 64, KS_R), 256, 0, stream>>>(hq, wqT, part);
  // 3) top-8 + renorm + expert counts
  k_topk<<<T0n / 4, 256, 0, stream>>>(part, sel, rwp, cnt_e);
  // 4) offsets (parallel prefix) + scatter rows by expert
  k_scan<<<1, 256, 0, stream>>>(cnt_e, off_e, cur_e, grp_n);
  k_scatter<<<NROWS / 256, 256, 0, stream>>>(sel, cur_e, rseg);

  // part/hq/wqT now dead. Convert H to bf16 once (into the h1d+y alias).
  k_hcvt<<<T0n * Dn / 2048, 256, 0, stream>>>(hidden, Hbf);

  // 5) transpose+convert all 9 weight tensors to bf16 operand layouts
  {
    TD9 D;
    D.t[0] = {A_gate, AgT, Dn, Rn, Rn / 32, (Rn / 32) * (Dn / 32), 0};
    D.t[1] = {A_up,   AuT, Dn, Rn, Rn / 32, (Rn / 32) * (Dn / 32), 1024};
    D.t[2] = {B_gate, BgT, Rn, In, In / 32, (In / 32) * (Rn / 32), 2048};
    D.t[3] = {B_up,   BuT, Rn, In, In / 32, (In / 32) * (Rn / 32), 2752};
    D.t[4] = {A_down, AdT, In, Rn, Rn / 32, (Rn / 32) * (In / 32), 3456};
    D.t[5] = {B_down, BdT, Gn * Rn, Dn, Dn / 32, (Dn / 32) * (Gn * Rn / 32), 4160};
    D.t[6] = {C_gate, CgT, Rn, Rn, 2, 4, 5184};
    D.t[7] = {C_up,   CuT, Rn, Rn, 2, 4, 6208};
    D.t[8] = {C_down, CdT, Rn, Rn, 2, 4, 7232};
    k_tcvt9<<<8256, 256, 0, stream>>>(D);
  }

  // 6) dense in-factor projections (bf16 H + T14 K-loop prefetch)
  k_h1_mfma<<<dim3(T0n / 64, Gn), 512, 0, stream>>>(Hbf, AgT, AuT, h1gb, h1ub);

  // Hbf dead; reclaim h1d + y with ONE memset (contiguous 8.39 MB).
  hipMemsetAsync(h1d, 0, (size_t)(NROWS * Rn + T0n * Gn * Rn) * sizeof(float),
                 stream);

  // 7) per-expert core (gate/up) via MFMA (512 thr path-split)
  k_core_gu<<<En, 512, 0, stream>>>(h1gb, h1ub, CgT, CuT,
                                    rseg, off_e, cnt_e, h2gb, h2ub);
  // 8) fused expand + down-A (8-wave/256-row + T14 register prefetch)
  k_expand_mfma<<<dim3(NTILE2_MAX, 4), 512, 0, stream>>>(
      h2gb, h2ub, BgT, BuT, AdT, rseg, grp_n, h1d);
  // 9) per-expert down core via MFMA + rw (512 thr, 128 rows/iter)
  k_core_down<<<En, 512, 0, stream>>>(h1d, CdT, rwp,
                                      rseg, off_e, cnt_e, y);
  // 10) combine (8-wave + T14 prefetch)
  k_combine<<<dim3(Dn / 128, T0n / 128), 512, 0, stream>>>(y, BdT, out);
}